// Round 1
// baseline (607.776 us; speedup 1.0000x reference)
//
#include <hip/hip_runtime.h>

#define N_NODES 20000
#define F_IN 64
#define HID 128
#define HEADS 4
#define E_EDGES 320000
#define ET (E_EDGES + N_NODES)   // + self loops
#define NEG_SLOPE 0.2f

// ---------------------------------------------------------------------------
// Encoder: x = relu(nf @ encW + encb)   [20000,64]@[64,128]
// block = 128 threads, 8 nodes per block
__global__ __launch_bounds__(128) void enc_gemm(const float* __restrict__ nf,
                                                const float* __restrict__ W,
                                                const float* __restrict__ b,
                                                float* __restrict__ x) {
    __shared__ float xs[8][64];
    int t = threadIdx.x;
    int n0 = blockIdx.x * 8;
    for (int i = t; i < 8 * 64; i += 128)
        xs[i >> 6][i & 63] = nf[(size_t)n0 * 64 + i];
    __syncthreads();
    float acc[8];
#pragma unroll
    for (int i = 0; i < 8; ++i) acc[i] = 0.f;
    for (int k = 0; k < 64; ++k) {
        float w = W[k * 128 + t];
#pragma unroll
        for (int i = 0; i < 8; ++i) acc[i] = fmaf(xs[i][k], w, acc[i]);
    }
    float bias = b[t];
#pragma unroll
    for (int i = 0; i < 8; ++i) {
        float v = acc[i] + bias;
        x[(size_t)(n0 + i) * 128 + t] = v > 0.f ? v : 0.f;
    }
}

// ---------------------------------------------------------------------------
// CSR build (by destination), once per call
__global__ void hist_kernel(const int* __restrict__ ei, int* __restrict__ deg) {
    int e = blockIdx.x * 256 + threadIdx.x;
    if (e >= ET) return;
    int d = (e < E_EDGES) ? ei[E_EDGES + e] : (e - E_EDGES);
    atomicAdd(&deg[d], 1);
}

__global__ __launch_bounds__(1024) void scan_kernel(const int* __restrict__ deg,
                                                    int* __restrict__ off) {
    // single block, 1024 threads, 20 elems each (20480 >= 20000)
    __shared__ int sums[1024];
    int t = threadIdx.x;
    int base = t * 20;
    int tmp[20];
    int s = 0;
#pragma unroll
    for (int i = 0; i < 20; ++i) {
        int idx = base + i;
        int v = (idx < N_NODES) ? deg[idx] : 0;
        tmp[i] = s;
        s += v;
    }
    sums[t] = s;
    __syncthreads();
    for (int st = 1; st < 1024; st <<= 1) {
        int v = (t >= st) ? sums[t - st] : 0;
        __syncthreads();
        sums[t] += v;
        __syncthreads();
    }
    int bsum = (t == 0) ? 0 : sums[t - 1];
#pragma unroll
    for (int i = 0; i < 20; ++i) {
        int idx = base + i;
        if (idx < N_NODES) off[idx] = bsum + tmp[i];
    }
    if (t == 1023) off[N_NODES] = sums[1023];
}

__global__ void scatter_kernel(const int* __restrict__ ei, const int* __restrict__ off,
                               int* __restrict__ cursor, int* __restrict__ csr) {
    int e = blockIdx.x * 256 + threadIdx.x;
    if (e >= ET) return;
    int s, d;
    if (e < E_EDGES) { s = ei[e]; d = ei[E_EDGES + e]; }
    else             { s = d = e - E_EDGES; }
    int pos = atomicAdd(&cursor[d], 1);
    csr[off[d] + pos] = s;
}

// ---------------------------------------------------------------------------
// Per-layer: h = x @ linW  [20000,128]@[128,512]; a_src/a_dst per-head dots.
// block = 512 threads, 8 nodes per block
__global__ __launch_bounds__(512) void gat_h(const float* __restrict__ x,
                                             const float* __restrict__ linW,
                                             const float* __restrict__ attS,
                                             const float* __restrict__ attD,
                                             float* __restrict__ h,
                                             float* __restrict__ aS,
                                             float* __restrict__ aD) {
    __shared__ float xs[8][128];
    __shared__ float lss[8], lsd[8];
    int t = threadIdx.x;
    int n0 = blockIdx.x * 8;
    for (int i = t; i < 8 * 128; i += 512)
        xs[i >> 7][i & 127] = x[(size_t)n0 * 128 + i];
    __syncthreads();
    float acc[8];
#pragma unroll
    for (int i = 0; i < 8; ++i) acc[i] = 0.f;
    for (int k = 0; k < 128; ++k) {
        float w = linW[k * 512 + t];
#pragma unroll
        for (int i = 0; i < 8; ++i) acc[i] = fmaf(xs[i][k], w, acc[i]);
    }
    int head = t >> 7, dim = t & 127;
    float vs = attS[head * 128 + dim];
    float vd = attD[head * 128 + dim];
    int wave = t >> 6, lane = t & 63;
#pragma unroll
    for (int i = 0; i < 8; ++i)
        h[(size_t)(n0 + i) * 512 + t] = acc[i];
    for (int i = 0; i < 8; ++i) {
        float ps = acc[i] * vs, pd = acc[i] * vd;
#pragma unroll
        for (int s = 32; s; s >>= 1) {
            ps += __shfl_down(ps, s);
            pd += __shfl_down(pd, s);
        }
        if (lane == 0) { lss[wave] = ps; lsd[wave] = pd; }
        __syncthreads();
        if (t < 4) {
            aS[(n0 + i) * 4 + t] = lss[2 * t] + lss[2 * t + 1];
            aD[(n0 + i) * 4 + t] = lsd[2 * t] + lsd[2 * t + 1];
        }
        __syncthreads();
    }
}

// ---------------------------------------------------------------------------
// Aggregation: per dst node, softmax over incoming edges, weighted sum of
// h[src], head-mean + bias + relu + residual (x updated in place).
// block = 256 threads, 1 node per block
#define CH 64
__global__ __launch_bounds__(256) void gat_agg(const float* __restrict__ h,
                                               const float* __restrict__ aS,
                                               const float* __restrict__ aD,
                                               const int* __restrict__ off,
                                               const int* __restrict__ csr,
                                               const float* __restrict__ bias,
                                               float* __restrict__ x) {
    int n = blockIdx.x;
    int t = threadIdx.x;
    int lane = t & 63, wave = t >> 6;
    int beg = off[n];
    int deg = off[n + 1] - beg;

    __shared__ float adn[4], m[4], zv[4];
    __shared__ float lm[4][4];
    __shared__ int srcs[CH];
    __shared__ float wch[CH][4];
    __shared__ float red[256];
    __shared__ float outs[512];

    if (t < 4) adn[t] = aD[n * 4 + t];
    __syncthreads();

    // pass 1: per-head max of leaky_relu(a_src[s]+a_dst[n])
    float mx0 = -1e30f, mx1 = -1e30f, mx2 = -1e30f, mx3 = -1e30f;
    for (int i = t; i < deg; i += 256) {
        int s = csr[beg + i];
        float e;
        e = aS[s * 4 + 0] + adn[0]; e = e > 0.f ? e : NEG_SLOPE * e; mx0 = fmaxf(mx0, e);
        e = aS[s * 4 + 1] + adn[1]; e = e > 0.f ? e : NEG_SLOPE * e; mx1 = fmaxf(mx1, e);
        e = aS[s * 4 + 2] + adn[2]; e = e > 0.f ? e : NEG_SLOPE * e; mx2 = fmaxf(mx2, e);
        e = aS[s * 4 + 3] + adn[3]; e = e > 0.f ? e : NEG_SLOPE * e; mx3 = fmaxf(mx3, e);
    }
#pragma unroll
    for (int s = 32; s; s >>= 1) {
        mx0 = fmaxf(mx0, __shfl_down(mx0, s));
        mx1 = fmaxf(mx1, __shfl_down(mx1, s));
        mx2 = fmaxf(mx2, __shfl_down(mx2, s));
        mx3 = fmaxf(mx3, __shfl_down(mx3, s));
    }
    if (lane == 0) { lm[wave][0] = mx0; lm[wave][1] = mx1; lm[wave][2] = mx2; lm[wave][3] = mx3; }
    __syncthreads();
    if (t < 4) m[t] = fmaxf(fmaxf(lm[0][t], lm[1][t]), fmaxf(lm[2][t], lm[3][t]));
    __syncthreads();

    // pass 2: chunks of CH edges; compute w, accumulate w*h[src]
    float zp = 0.f, acc0 = 0.f, acc1 = 0.f;
    int head1 = t >> 7;          // 0/1; second dim is head1+2
    int hh = t & 3;
    int eidx = t >> 2;
    for (int c0 = 0; c0 < deg; c0 += CH) {
        int ce = min(CH, deg - c0);
        if (eidx < ce) {
            int s = csr[beg + c0 + eidx];
            if (hh == 0) srcs[eidx] = s;
            float e = aS[s * 4 + hh] + adn[hh];
            e = e > 0.f ? e : NEG_SLOPE * e;
            float w = __expf(e - m[hh]);
            wch[eidx][hh] = w;
            zp += w;
        }
        __syncthreads();
        for (int j = 0; j < ce; ++j) {
            int s = srcs[j];
            float w1 = wch[j][head1];
            float w2 = wch[j][head1 + 2];
            acc0 = fmaf(w1, h[(size_t)s * 512 + t], acc0);
            acc1 = fmaf(w2, h[(size_t)s * 512 + 256 + t], acc1);
        }
        __syncthreads();
    }

    // z per head: strided tree keeps (t&3) classes
    red[t] = zp;
    __syncthreads();
    for (int s = 128; s >= 4; s >>= 1) {
        if (t < s) red[t] += red[t + s];
        __syncthreads();
    }
    if (t < 4) zv[t] = red[t];
    __syncthreads();

    outs[t] = acc0 / zv[head1];
    outs[256 + t] = acc1 / zv[head1 + 2];
    __syncthreads();
    if (t < 128) {
        float v = 0.25f * (outs[t] + outs[128 + t] + outs[256 + t] + outs[384 + t]) + bias[t];
        v = v > 0.f ? v : 0.f;
        x[(size_t)n * 128 + t] += v;
    }
}

// ---------------------------------------------------------------------------
// Prediction heads: h1 = relu(x@W1+b1); attack = sigmoid(h1@W2+b2);
// vuln = sigmoid(x@vW+vb). One node per 128-thread block.
__global__ __launch_bounds__(128) void pred_kernel(const float* __restrict__ x,
                                                   const float* __restrict__ W1,
                                                   const float* __restrict__ b1,
                                                   const float* __restrict__ W2,
                                                   const float* __restrict__ b2,
                                                   const float* __restrict__ vW,
                                                   const float* __restrict__ vb,
                                                   float* __restrict__ out) {
    int n = blockIdx.x, t = threadIdx.x;
    __shared__ float xr[128];
    __shared__ float h1[64];
    __shared__ float part[2];
    xr[t] = x[(size_t)n * 128 + t];
    __syncthreads();
    if (t < 64) {
        float a = b1[t];
        for (int k = 0; k < 128; ++k) a = fmaf(xr[k], W1[k * 64 + t], a);
        h1[t] = a > 0.f ? a : 0.f;
    }
    __syncthreads();
    float p = (t < 64) ? h1[t] * W2[t] : 0.f;
    float q = xr[t] * vW[t];
#pragma unroll
    for (int s = 32; s; s >>= 1) {
        p += __shfl_down(p, s);
        q += __shfl_down(q, s);
    }
    int lane = t & 63, wave = t >> 6;
    if (lane == 0) part[wave] = q;
    __syncthreads();
    if (t == 0) {
        out[n] = 1.f / (1.f + __expf(-(p + b2[0])));
        out[N_NODES + n] = 1.f / (1.f + __expf(-(part[0] + part[1] + vb[0])));
    }
}

// ---------------------------------------------------------------------------
extern "C" void kernel_launch(void* const* d_in, const int* in_sizes, int n_in,
                              void* d_out, int out_size, void* d_ws, size_t ws_size,
                              hipStream_t stream) {
    const float* nf    = (const float*)d_in[0];
    const int*   ei    = (const int*)d_in[1];
    const float* encW  = (const float*)d_in[2];
    const float* encb  = (const float*)d_in[3];
    const float* lin   = (const float*)d_in[4];
    const float* attS  = (const float*)d_in[5];
    const float* attD  = (const float*)d_in[6];
    const float* gbias = (const float*)d_in[7];
    const float* W1    = (const float*)d_in[8];
    const float* b1    = (const float*)d_in[9];
    const float* W2    = (const float*)d_in[10];
    const float* b2    = (const float*)d_in[11];
    const float* vW    = (const float*)d_in[12];
    const float* vb    = (const float*)d_in[13];
    float* out = (float*)d_out;

    char* ws = (char*)d_ws;
    size_t o = 0;
    auto alloc = [&](size_t bytes) {
        void* p = ws + o;
        o += (bytes + 255) & ~(size_t)255;
        return p;
    };
    float* x    = (float*)alloc((size_t)N_NODES * 128 * 4);
    float* h    = (float*)alloc((size_t)N_NODES * 512 * 4);
    float* aS   = (float*)alloc((size_t)N_NODES * 4 * 4);
    float* aD   = (float*)alloc((size_t)N_NODES * 4 * 4);
    int* deg    = (int*)alloc((size_t)N_NODES * 4);
    int* cursor = (int*)alloc((size_t)N_NODES * 4);
    int* offs   = (int*)alloc((size_t)(N_NODES + 1) * 4);
    int* csr    = (int*)alloc((size_t)ET * 4);

    hipMemsetAsync(deg, 0, (size_t)N_NODES * 4, stream);
    hipMemsetAsync(cursor, 0, (size_t)N_NODES * 4, stream);

    enc_gemm<<<N_NODES / 8, 128, 0, stream>>>(nf, encW, encb, x);
    hist_kernel<<<(ET + 255) / 256, 256, 0, stream>>>(ei, deg);
    scan_kernel<<<1, 1024, 0, stream>>>(deg, offs);
    scatter_kernel<<<(ET + 255) / 256, 256, 0, stream>>>(ei, offs, cursor, csr);

    for (int l = 0; l < 3; ++l) {
        gat_h<<<N_NODES / 8, 512, 0, stream>>>(x, lin + (size_t)l * 128 * 512,
                                               attS + (size_t)l * HEADS * 128,
                                               attD + (size_t)l * HEADS * 128,
                                               h, aS, aD);
        gat_agg<<<N_NODES, 256, 0, stream>>>(h, aS, aD, offs, csr,
                                             gbias + (size_t)l * 128, x);
    }
    pred_kernel<<<N_NODES, 128, 0, stream>>>(x, W1, b1, W2, b2, vW, vb, out);
}

// Round 2
// 500.590 us; speedup vs baseline: 1.2141x; 1.2141x over previous
//
#include <hip/hip_runtime.h>

#define N_NODES 20000
#define F_IN 64
#define HID 128
#define HEADS 4
#define E_EDGES 320000
#define ET (E_EDGES + N_NODES)   // + self loops
#define NEG_SLOPE 0.2f

typedef unsigned short ushort_t;
typedef unsigned int uint_t;

__device__ __forceinline__ ushort_t f2bf(float f) {
    union { float f; uint_t u; } v; v.f = f;
    uint_t r = v.u + 0x7fffu + ((v.u >> 16) & 1u);   // round-to-nearest-even
    return (ushort_t)(r >> 16);
}
__device__ __forceinline__ float bf2f(ushort_t u) {
    union { uint_t u; float f; } v; v.u = ((uint_t)u) << 16; return v.f;
}
__device__ __forceinline__ float bflo(uint_t w) {   // low 16 bits -> float
    union { uint_t u; float f; } v; v.u = w << 16; return v.f;
}
__device__ __forceinline__ float bfhi(uint_t w) {   // high 16 bits -> float
    union { uint_t u; float f; } v; v.u = w & 0xffff0000u; return v.f;
}

// ---------------------------------------------------------------------------
// Encoder: x = relu(nf @ encW + encb)   [20000,64]@[64,128]
__global__ __launch_bounds__(128) void enc_gemm(const float* __restrict__ nf,
                                                const float* __restrict__ W,
                                                const float* __restrict__ b,
                                                float* __restrict__ x) {
    __shared__ float xs[8][64];
    int t = threadIdx.x;
    int n0 = blockIdx.x * 8;
    for (int i = t; i < 8 * 64; i += 128)
        xs[i >> 6][i & 63] = nf[(size_t)n0 * 64 + i];
    __syncthreads();
    float acc[8];
#pragma unroll
    for (int i = 0; i < 8; ++i) acc[i] = 0.f;
    for (int k = 0; k < 64; ++k) {
        float w = W[k * 128 + t];
#pragma unroll
        for (int i = 0; i < 8; ++i) acc[i] = fmaf(xs[i][k], w, acc[i]);
    }
    float bias = b[t];
#pragma unroll
    for (int i = 0; i < 8; ++i) {
        float v = acc[i] + bias;
        x[(size_t)(n0 + i) * 128 + t] = v > 0.f ? v : 0.f;
    }
}

// ---------------------------------------------------------------------------
// CSR build (by destination), once per call
__global__ void hist_kernel(const int* __restrict__ ei, int* __restrict__ deg) {
    int e = blockIdx.x * 256 + threadIdx.x;
    if (e >= ET) return;
    int d = (e < E_EDGES) ? ei[E_EDGES + e] : (e - E_EDGES);
    atomicAdd(&deg[d], 1);
}

__global__ __launch_bounds__(1024) void scan_kernel(const int* __restrict__ deg,
                                                    int* __restrict__ off) {
    __shared__ int sums[1024];
    int t = threadIdx.x;
    int base = t * 20;
    int tmp[20];
    int s = 0;
#pragma unroll
    for (int i = 0; i < 20; ++i) {
        int idx = base + i;
        int v = (idx < N_NODES) ? deg[idx] : 0;
        tmp[i] = s;
        s += v;
    }
    sums[t] = s;
    __syncthreads();
    for (int st = 1; st < 1024; st <<= 1) {
        int v = (t >= st) ? sums[t - st] : 0;
        __syncthreads();
        sums[t] += v;
        __syncthreads();
    }
    int bsum = (t == 0) ? 0 : sums[t - 1];
#pragma unroll
    for (int i = 0; i < 20; ++i) {
        int idx = base + i;
        if (idx < N_NODES) off[idx] = bsum + tmp[i];
    }
    if (t == 1023) off[N_NODES] = sums[1023];
}

__global__ void scatter_kernel(const int* __restrict__ ei, const int* __restrict__ off,
                               int* __restrict__ cursor, int* __restrict__ csr) {
    int e = blockIdx.x * 256 + threadIdx.x;
    if (e >= ET) return;
    int s, d;
    if (e < E_EDGES) { s = ei[e]; d = ei[E_EDGES + e]; }
    else             { s = d = e - E_EDGES; }
    int pos = atomicAdd(&cursor[d], 1);
    csr[off[d] + pos] = s;
}

// ---------------------------------------------------------------------------
// h = x @ linW  [20000,128]@[128,512], output stored bf16.
// 256 threads, 16 nodes/block, 2 output cols per thread (t, t+256).
// One ds_read_b128 (4 k-values) feeds 8 FMAs -> VALU-bound.
#define NPB 16
__global__ __launch_bounds__(256) void gat_h(const float* __restrict__ x,
                                             const float* __restrict__ linW,
                                             ushort_t* __restrict__ h) {
    __shared__ float xs[NPB][128];
    int t = threadIdx.x;
    int n0 = blockIdx.x * NPB;
    const float4* xsrc = (const float4*)(x + (size_t)n0 * 128);
    float4* xdst = (float4*)&xs[0][0];
    xdst[t] = xsrc[t];
    xdst[t + 256] = xsrc[t + 256];
    __syncthreads();
    float2 acc[NPB];
#pragma unroll
    for (int i = 0; i < NPB; ++i) acc[i] = make_float2(0.f, 0.f);
    const float* wpA = linW + t;
    const float* wpB = linW + t + 256;
    for (int k0 = 0; k0 < 128; k0 += 4) {
        float wa0 = wpA[(size_t)(k0 + 0) * 512];
        float wa1 = wpA[(size_t)(k0 + 1) * 512];
        float wa2 = wpA[(size_t)(k0 + 2) * 512];
        float wa3 = wpA[(size_t)(k0 + 3) * 512];
        float wb0 = wpB[(size_t)(k0 + 0) * 512];
        float wb1 = wpB[(size_t)(k0 + 1) * 512];
        float wb2 = wpB[(size_t)(k0 + 2) * 512];
        float wb3 = wpB[(size_t)(k0 + 3) * 512];
#pragma unroll
        for (int i = 0; i < NPB; ++i) {
            float4 xv = *(const float4*)&xs[i][k0];
            acc[i].x = fmaf(xv.x, wa0, acc[i].x);
            acc[i].x = fmaf(xv.y, wa1, acc[i].x);
            acc[i].x = fmaf(xv.z, wa2, acc[i].x);
            acc[i].x = fmaf(xv.w, wa3, acc[i].x);
            acc[i].y = fmaf(xv.x, wb0, acc[i].y);
            acc[i].y = fmaf(xv.y, wb1, acc[i].y);
            acc[i].y = fmaf(xv.z, wb2, acc[i].y);
            acc[i].y = fmaf(xv.w, wb3, acc[i].y);
        }
    }
#pragma unroll
    for (int i = 0; i < NPB; ++i) {
        h[(size_t)(n0 + i) * 512 + t] = f2bf(acc[i].x);
        h[(size_t)(n0 + i) * 512 + t + 256] = f2bf(acc[i].y);
    }
}

// ---------------------------------------------------------------------------
// a_src/a_dst per-head dots from bf16 h. One wave per node (4 nodes/block).
// lane covers dims lane*8..lane*8+7; head = lane>>4; reduce within 16 lanes.
__global__ __launch_bounds__(256) void att_dots(const ushort_t* __restrict__ h,
                                                const float* __restrict__ attS,
                                                const float* __restrict__ attD,
                                                float* __restrict__ aS,
                                                float* __restrict__ aD) {
    int t = threadIdx.x;
    int wave = t >> 6, lane = t & 63;
    int n = blockIdx.x * 4 + wave;
    uint4 v = *(const uint4*)(h + (size_t)n * 512 + lane * 8);
    int head = lane >> 4;
    int db = (lane & 15) * 8;
    float4 s0 = *(const float4*)(attS + head * 128 + db);
    float4 s1 = *(const float4*)(attS + head * 128 + db + 4);
    float4 d0 = *(const float4*)(attD + head * 128 + db);
    float4 d1 = *(const float4*)(attD + head * 128 + db + 4);
    float f0 = bflo(v.x), f1 = bfhi(v.x), f2 = bflo(v.y), f3 = bfhi(v.y);
    float f4 = bflo(v.z), f5 = bfhi(v.z), f6 = bflo(v.w), f7 = bfhi(v.w);
    float ps = f0 * s0.x + f1 * s0.y + f2 * s0.z + f3 * s0.w
             + f4 * s1.x + f5 * s1.y + f6 * s1.z + f7 * s1.w;
    float pd = f0 * d0.x + f1 * d0.y + f2 * d0.z + f3 * d0.w
             + f4 * d1.x + f5 * d1.y + f6 * d1.z + f7 * d1.w;
#pragma unroll
    for (int s = 1; s < 16; s <<= 1) {
        ps += __shfl_xor(ps, s);
        pd += __shfl_xor(pd, s);
    }
    if ((lane & 15) == 0) {
        aS[n * 4 + head] = ps;
        aD[n * 4 + head] = pd;
    }
}

// ---------------------------------------------------------------------------
// Aggregation: per dst node softmax over incoming edges, weighted sum of bf16
// h[src], head-mean + bias + relu + residual (x in place).
// Thread t covers dims (2t, 2t+1); head = t>>6.
#define CH 64
__global__ __launch_bounds__(256) void gat_agg(const ushort_t* __restrict__ h,
                                               const float* __restrict__ aS,
                                               const float* __restrict__ aD,
                                               const int* __restrict__ off,
                                               const int* __restrict__ csr,
                                               const float* __restrict__ bias,
                                               float* __restrict__ x) {
    int n = blockIdx.x;
    int t = threadIdx.x;
    int lane = t & 63, wave = t >> 6;
    int beg = off[n];
    int deg = off[n + 1] - beg;

    __shared__ float adn[4], m[4], zv[4];
    __shared__ float lm[4][4];
    __shared__ int srcs[CH];
    __shared__ float wch[CH][4];
    __shared__ float red[256];
    __shared__ float outs[512];

    if (t < 4) adn[t] = aD[n * 4 + t];
    __syncthreads();

    // pass 1: per-head max of leaky_relu(a_src[s]+a_dst[n])
    float mx0 = -1e30f, mx1 = -1e30f, mx2 = -1e30f, mx3 = -1e30f;
    for (int i = t; i < deg; i += 256) {
        int s = csr[beg + i];
        float4 a = *(const float4*)(aS + (size_t)s * 4);
        float e;
        e = a.x + adn[0]; e = e > 0.f ? e : NEG_SLOPE * e; mx0 = fmaxf(mx0, e);
        e = a.y + adn[1]; e = e > 0.f ? e : NEG_SLOPE * e; mx1 = fmaxf(mx1, e);
        e = a.z + adn[2]; e = e > 0.f ? e : NEG_SLOPE * e; mx2 = fmaxf(mx2, e);
        e = a.w + adn[3]; e = e > 0.f ? e : NEG_SLOPE * e; mx3 = fmaxf(mx3, e);
    }
#pragma unroll
    for (int s = 32; s; s >>= 1) {
        mx0 = fmaxf(mx0, __shfl_down(mx0, s));
        mx1 = fmaxf(mx1, __shfl_down(mx1, s));
        mx2 = fmaxf(mx2, __shfl_down(mx2, s));
        mx3 = fmaxf(mx3, __shfl_down(mx3, s));
    }
    if (lane == 0) { lm[wave][0] = mx0; lm[wave][1] = mx1; lm[wave][2] = mx2; lm[wave][3] = mx3; }
    __syncthreads();
    if (t < 4) m[t] = fmaxf(fmaxf(lm[0][t], lm[1][t]), fmaxf(lm[2][t], lm[3][t]));
    __syncthreads();

    // pass 2: chunks of CH edges; compute w, accumulate w*h[src] (bf16 gather)
    float zp = 0.f;
    float2 acc = make_float2(0.f, 0.f);
    int head = t >> 6;
    int hh = t & 3;
    int eidx = t >> 2;
    const uint_t* hrow = (const uint_t*)h;   // uint = 2 bf16
    for (int c0 = 0; c0 < deg; c0 += CH) {
        int ce = min(CH, deg - c0);
        if (eidx < ce) {
            int s = csr[beg + c0 + eidx];
            if (hh == 0) srcs[eidx] = s;
            float e = aS[s * 4 + hh] + adn[hh];
            e = e > 0.f ? e : NEG_SLOPE * e;
            float w = __expf(e - m[hh]);
            wch[eidx][hh] = w;
            zp += w;
        }
        __syncthreads();
#pragma unroll 4
        for (int j = 0; j < ce; ++j) {
            int s = srcs[j];
            float w = wch[j][head];
            uint_t hv = hrow[(size_t)s * 256 + t];
            acc.x = fmaf(w, bflo(hv), acc.x);
            acc.y = fmaf(w, bfhi(hv), acc.y);
        }
        __syncthreads();
    }

    // z per head: strided tree keeps (t&3) classes
    red[t] = zp;
    __syncthreads();
    for (int s = 128; s >= 4; s >>= 1) {
        if (t < s) red[t] += red[t + s];
        __syncthreads();
    }
    if (t < 4) zv[t] = red[t];
    __syncthreads();

    float invz = 1.f / zv[head];
    *(float2*)&outs[2 * t] = make_float2(acc.x * invz, acc.y * invz);
    __syncthreads();
    if (t < 128) {
        float v = 0.25f * (outs[t] + outs[128 + t] + outs[256 + t] + outs[384 + t]) + bias[t];
        v = v > 0.f ? v : 0.f;
        x[(size_t)n * 128 + t] += v;
    }
}

// ---------------------------------------------------------------------------
// Prediction heads
__global__ __launch_bounds__(128) void pred_kernel(const float* __restrict__ x,
                                                   const float* __restrict__ W1,
                                                   const float* __restrict__ b1,
                                                   const float* __restrict__ W2,
                                                   const float* __restrict__ b2,
                                                   const float* __restrict__ vW,
                                                   const float* __restrict__ vb,
                                                   float* __restrict__ out) {
    int n = blockIdx.x, t = threadIdx.x;
    __shared__ float xr[128];
    __shared__ float h1[64];
    __shared__ float part[2];
    xr[t] = x[(size_t)n * 128 + t];
    __syncthreads();
    if (t < 64) {
        float a = b1[t];
        for (int k = 0; k < 128; ++k) a = fmaf(xr[k], W1[k * 64 + t], a);
        h1[t] = a > 0.f ? a : 0.f;
    }
    __syncthreads();
    float p = (t < 64) ? h1[t] * W2[t] : 0.f;
    float q = xr[t] * vW[t];
#pragma unroll
    for (int s = 32; s; s >>= 1) {
        p += __shfl_down(p, s);
        q += __shfl_down(q, s);
    }
    int lane = t & 63, wave = t >> 6;
    if (lane == 0) part[wave] = q;
    __syncthreads();
    if (t == 0) {
        out[n] = 1.f / (1.f + __expf(-(p + b2[0])));
        out[N_NODES + n] = 1.f / (1.f + __expf(-(part[0] + part[1] + vb[0])));
    }
}

// ---------------------------------------------------------------------------
extern "C" void kernel_launch(void* const* d_in, const int* in_sizes, int n_in,
                              void* d_out, int out_size, void* d_ws, size_t ws_size,
                              hipStream_t stream) {
    const float* nf    = (const float*)d_in[0];
    const int*   ei    = (const int*)d_in[1];
    const float* encW  = (const float*)d_in[2];
    const float* encb  = (const float*)d_in[3];
    const float* lin   = (const float*)d_in[4];
    const float* attS  = (const float*)d_in[5];
    const float* attD  = (const float*)d_in[6];
    const float* gbias = (const float*)d_in[7];
    const float* W1    = (const float*)d_in[8];
    const float* b1    = (const float*)d_in[9];
    const float* W2    = (const float*)d_in[10];
    const float* b2    = (const float*)d_in[11];
    const float* vW    = (const float*)d_in[12];
    const float* vb    = (const float*)d_in[13];
    float* out = (float*)d_out;

    char* ws = (char*)d_ws;
    size_t o = 0;
    auto alloc = [&](size_t bytes) {
        void* p = ws + o;
        o += (bytes + 255) & ~(size_t)255;
        return p;
    };
    float* x      = (float*)alloc((size_t)N_NODES * 128 * 4);
    ushort_t* h   = (ushort_t*)alloc((size_t)N_NODES * 512 * 2);
    float* aS     = (float*)alloc((size_t)N_NODES * 4 * 4);
    float* aD     = (float*)alloc((size_t)N_NODES * 4 * 4);
    int* deg      = (int*)alloc((size_t)N_NODES * 4);
    int* cursor   = (int*)alloc((size_t)N_NODES * 4);
    int* offs     = (int*)alloc((size_t)(N_NODES + 1) * 4);
    int* csr      = (int*)alloc((size_t)ET * 4);

    hipMemsetAsync(deg, 0, (size_t)N_NODES * 4, stream);
    hipMemsetAsync(cursor, 0, (size_t)N_NODES * 4, stream);

    enc_gemm<<<N_NODES / 8, 128, 0, stream>>>(nf, encW, encb, x);
    hist_kernel<<<(ET + 255) / 256, 256, 0, stream>>>(ei, deg);
    scan_kernel<<<1, 1024, 0, stream>>>(deg, offs);
    scatter_kernel<<<(ET + 255) / 256, 256, 0, stream>>>(ei, offs, cursor, csr);

    for (int l = 0; l < 3; ++l) {
        gat_h<<<N_NODES / NPB, 256, 0, stream>>>(x, lin + (size_t)l * 128 * 512, h);
        att_dots<<<N_NODES / 4, 256, 0, stream>>>(h, attS + (size_t)l * HEADS * 128,
                                                  attD + (size_t)l * HEADS * 128, aS, aD);
        gat_agg<<<N_NODES, 256, 0, stream>>>(h, aS, aD, offs, csr,
                                             gbias + (size_t)l * 128, x);
    }
    pred_kernel<<<N_NODES, 128, 0, stream>>>(x, W1, b1, W2, b2, vW, vb, out);
}

// Round 3
// 375.301 us; speedup vs baseline: 1.6194x; 1.3338x over previous
//
#include <hip/hip_runtime.h>

#define N_NODES 20000
#define N_PAD 20032            // padded to multiple of 64 for MFMA tiles
#define F_IN 64
#define HID 128
#define HEADS 4
#define E_EDGES 320000
#define ET (E_EDGES + N_NODES)   // + self loops
#define NEG_SLOPE 0.2f

typedef unsigned short ushort_t;
typedef unsigned int uint_t;

using bf16x8 = __attribute__((ext_vector_type(8))) short;
using f32x4  = __attribute__((ext_vector_type(4))) float;

__device__ __forceinline__ ushort_t f2bf(float f) {
    union { float f; uint_t u; } v; v.f = f;
    uint_t r = v.u + 0x7fffu + ((v.u >> 16) & 1u);   // round-to-nearest-even
    return (ushort_t)(r >> 16);
}
__device__ __forceinline__ float bflo(uint_t w) {
    union { uint_t u; float f; } v; v.u = w << 16; return v.f;
}
__device__ __forceinline__ float bfhi(uint_t w) {
    union { uint_t u; float f; } v; v.u = w & 0xffff0000u; return v.f;
}

// ---------------------------------------------------------------------------
// Encoder: x = relu(nf @ encW + encb); writes f32 x and bf16 xb
__global__ __launch_bounds__(128) void enc_gemm(const float* __restrict__ nf,
                                                const float* __restrict__ W,
                                                const float* __restrict__ b,
                                                float* __restrict__ x,
                                                ushort_t* __restrict__ xb) {
    __shared__ float xs[8][64];
    int t = threadIdx.x;
    int n0 = blockIdx.x * 8;
    for (int i = t; i < 8 * 64; i += 128)
        xs[i >> 6][i & 63] = nf[(size_t)n0 * 64 + i];
    __syncthreads();
    float acc[8];
#pragma unroll
    for (int i = 0; i < 8; ++i) acc[i] = 0.f;
    for (int k = 0; k < 64; ++k) {
        float w = W[k * 128 + t];
#pragma unroll
        for (int i = 0; i < 8; ++i) acc[i] = fmaf(xs[i][k], w, acc[i]);
    }
    float bias = b[t];
#pragma unroll
    for (int i = 0; i < 8; ++i) {
        float v = acc[i] + bias;
        v = v > 0.f ? v : 0.f;
        x[(size_t)(n0 + i) * 128 + t] = v;
        xb[(size_t)(n0 + i) * 128 + t] = f2bf(v);
    }
}

// ---------------------------------------------------------------------------
// Weight pre-pack: lin f32 [3][128][512] -> linP bf16 [3][512][128] where
// linP[l][col][k] = lin[l][k][col]  (a lane's 8 consecutive k = one 16B load)
__global__ __launch_bounds__(256) void pack_w(const float* __restrict__ lin,
                                              ushort_t* __restrict__ linP) {
    int idx = blockIdx.x * 256 + threadIdx.x;     // 3*512*16 = 24576
    int l = idx / (512 * 16);
    int rem = idx % (512 * 16);
    int col = rem / 16, kg = rem % 16;
    const float* W = lin + (size_t)l * 128 * 512;
    ushort_t tmp[8];
#pragma unroll
    for (int j = 0; j < 8; ++j)
        tmp[j] = f2bf(W[(size_t)(kg * 8 + j) * 512 + col]);
    *(uint4*)(linP + ((size_t)l * 512 * 16 + rem) * 8) = *(const uint4*)tmp;
}

// ---------------------------------------------------------------------------
// CSR build (by destination), once per call
__global__ void hist_kernel(const int* __restrict__ ei, int* __restrict__ deg) {
    int e = blockIdx.x * 256 + threadIdx.x;
    if (e >= ET) return;
    int d = (e < E_EDGES) ? ei[E_EDGES + e] : (e - E_EDGES);
    atomicAdd(&deg[d], 1);
}

__global__ __launch_bounds__(1024) void scan_kernel(const int* __restrict__ deg,
                                                    int* __restrict__ off) {
    __shared__ int sums[1024];
    int t = threadIdx.x;
    int base = t * 20;
    int tmp[20];
    int s = 0;
#pragma unroll
    for (int i = 0; i < 20; ++i) {
        int idx = base + i;
        int v = (idx < N_NODES) ? deg[idx] : 0;
        tmp[i] = s;
        s += v;
    }
    sums[t] = s;
    __syncthreads();
    for (int st = 1; st < 1024; st <<= 1) {
        int v = (t >= st) ? sums[t - st] : 0;
        __syncthreads();
        sums[t] += v;
        __syncthreads();
    }
    int bsum = (t == 0) ? 0 : sums[t - 1];
#pragma unroll
    for (int i = 0; i < 20; ++i) {
        int idx = base + i;
        if (idx < N_NODES) off[idx] = bsum + tmp[i];
    }
    if (t == 1023) off[N_NODES] = sums[1023];
}

__global__ void scatter_kernel(const int* __restrict__ ei, const int* __restrict__ off,
                               int* __restrict__ cursor, int* __restrict__ csr) {
    int e = blockIdx.x * 256 + threadIdx.x;
    if (e >= ET) return;
    int s, d;
    if (e < E_EDGES) { s = ei[e]; d = ei[E_EDGES + e]; }
    else             { s = d = e - E_EDGES; }
    int pos = atomicAdd(&cursor[d], 1);
    csr[off[d] + pos] = s;
}

// ---------------------------------------------------------------------------
// h = xb @ linP via MFMA bf16: [20032,128]@[128,512] -> bf16 h.
// Grid (313, 4); block 256 = 4 waves (2x2); each wave: 32x64 output tile
// (2x4 frags of 16x16, K-loop 4x32). No LDS; A/B frags direct from L2.
// A: lane holds xb[row=l&15][k=8*(l>>4)+j]; B: linP[col=l&15][k] same shape.
// C/D: col=lane&15, row=(lane>>4)*4+reg   [verified m89/m91]
__global__ __launch_bounds__(256) void gat_h_mfma(const ushort_t* __restrict__ xb,
                                                  const ushort_t* __restrict__ Bp,
                                                  ushort_t* __restrict__ h) {
    int t = threadIdx.x;
    int lane = t & 63, w = t >> 6;
    int wr = w >> 1, wc = w & 1;
    int bm0 = blockIdx.x * 64 + wr * 32;
    int bn0 = blockIdx.y * 128 + wc * 64;
    int r16 = lane & 15, g = lane >> 4;

    const ushort_t* arow = xb + (size_t)(bm0 + r16) * 128 + g * 8;
    const ushort_t* bcol = Bp + (size_t)(bn0 + r16) * 128 + g * 8;

    f32x4 acc[2][4] = {};
#pragma unroll
    for (int k0 = 0; k0 < 128; k0 += 32) {
        bf16x8 a0 = *(const bf16x8*)(arow + k0);
        bf16x8 a1 = *(const bf16x8*)(arow + 16 * 128 + k0);
        bf16x8 b0 = *(const bf16x8*)(bcol + k0);
        bf16x8 b1 = *(const bf16x8*)(bcol + 16 * 128 + k0);
        bf16x8 b2 = *(const bf16x8*)(bcol + 32 * 128 + k0);
        bf16x8 b3 = *(const bf16x8*)(bcol + 48 * 128 + k0);
        acc[0][0] = __builtin_amdgcn_mfma_f32_16x16x32_bf16(a0, b0, acc[0][0], 0, 0, 0);
        acc[0][1] = __builtin_amdgcn_mfma_f32_16x16x32_bf16(a0, b1, acc[0][1], 0, 0, 0);
        acc[0][2] = __builtin_amdgcn_mfma_f32_16x16x32_bf16(a0, b2, acc[0][2], 0, 0, 0);
        acc[0][3] = __builtin_amdgcn_mfma_f32_16x16x32_bf16(a0, b3, acc[0][3], 0, 0, 0);
        acc[1][0] = __builtin_amdgcn_mfma_f32_16x16x32_bf16(a1, b0, acc[1][0], 0, 0, 0);
        acc[1][1] = __builtin_amdgcn_mfma_f32_16x16x32_bf16(a1, b1, acc[1][1], 0, 0, 0);
        acc[1][2] = __builtin_amdgcn_mfma_f32_16x16x32_bf16(a1, b2, acc[1][2], 0, 0, 0);
        acc[1][3] = __builtin_amdgcn_mfma_f32_16x16x32_bf16(a1, b3, acc[1][3], 0, 0, 0);
    }

#pragma unroll
    for (int fm = 0; fm < 2; ++fm)
#pragma unroll
        for (int fn = 0; fn < 4; ++fn)
#pragma unroll
            for (int r = 0; r < 4; ++r) {
                int row = bm0 + fm * 16 + g * 4 + r;
                int col = bn0 + fn * 16 + r16;
                h[(size_t)row * 512 + col] = f2bf(acc[fm][fn][r]);  // h is padded
            }
}

// ---------------------------------------------------------------------------
// a_src/a_dst per-head dots from bf16 h. One wave per node.
__global__ __launch_bounds__(256) void att_dots(const ushort_t* __restrict__ h,
                                                const float* __restrict__ attS,
                                                const float* __restrict__ attD,
                                                float* __restrict__ aS,
                                                float* __restrict__ aD) {
    int t = threadIdx.x;
    int wave = t >> 6, lane = t & 63;
    int n = blockIdx.x * 4 + wave;
    uint4 v = *(const uint4*)(h + (size_t)n * 512 + lane * 8);
    int head = lane >> 4;
    int db = (lane & 15) * 8;
    float4 s0 = *(const float4*)(attS + head * 128 + db);
    float4 s1 = *(const float4*)(attS + head * 128 + db + 4);
    float4 d0 = *(const float4*)(attD + head * 128 + db);
    float4 d1 = *(const float4*)(attD + head * 128 + db + 4);
    float f0 = bflo(v.x), f1 = bfhi(v.x), f2 = bflo(v.y), f3 = bfhi(v.y);
    float f4 = bflo(v.z), f5 = bfhi(v.z), f6 = bflo(v.w), f7 = bfhi(v.w);
    float ps = f0 * s0.x + f1 * s0.y + f2 * s0.z + f3 * s0.w
             + f4 * s1.x + f5 * s1.y + f6 * s1.z + f7 * s1.w;
    float pd = f0 * d0.x + f1 * d0.y + f2 * d0.z + f3 * d0.w
             + f4 * d1.x + f5 * d1.y + f6 * d1.z + f7 * d1.w;
#pragma unroll
    for (int s = 1; s < 16; s <<= 1) {
        ps += __shfl_xor(ps, s);
        pd += __shfl_xor(pd, s);
    }
    if ((lane & 15) == 0) {
        aS[n * 4 + head] = ps;
        aD[n * 4 + head] = pd;
    }
}

// ---------------------------------------------------------------------------
// Aggregation: per dst node softmax + weighted bf16 gather, head-mean + bias
// + relu + residual; updates f32 x and bf16 xb.
#define CH 64
__global__ __launch_bounds__(256) void gat_agg(const ushort_t* __restrict__ h,
                                               const float* __restrict__ aS,
                                               const float* __restrict__ aD,
                                               const int* __restrict__ off,
                                               const int* __restrict__ csr,
                                               const float* __restrict__ bias,
                                               float* __restrict__ x,
                                               ushort_t* __restrict__ xb) {
    int n = blockIdx.x;
    int t = threadIdx.x;
    int lane = t & 63, wave = t >> 6;
    int beg = off[n];
    int deg = off[n + 1] - beg;

    __shared__ float adn[4], m[4], zv[4];
    __shared__ float lm[4][4];
    __shared__ int srcs[CH];
    __shared__ float wch[CH][4];
    __shared__ float red[256];
    __shared__ float outs[512];

    if (t < 4) adn[t] = aD[n * 4 + t];
    __syncthreads();

    float mx0 = -1e30f, mx1 = -1e30f, mx2 = -1e30f, mx3 = -1e30f;
    for (int i = t; i < deg; i += 256) {
        int s = csr[beg + i];
        float4 a = *(const float4*)(aS + (size_t)s * 4);
        float e;
        e = a.x + adn[0]; e = e > 0.f ? e : NEG_SLOPE * e; mx0 = fmaxf(mx0, e);
        e = a.y + adn[1]; e = e > 0.f ? e : NEG_SLOPE * e; mx1 = fmaxf(mx1, e);
        e = a.z + adn[2]; e = e > 0.f ? e : NEG_SLOPE * e; mx2 = fmaxf(mx2, e);
        e = a.w + adn[3]; e = e > 0.f ? e : NEG_SLOPE * e; mx3 = fmaxf(mx3, e);
    }
#pragma unroll
    for (int s = 32; s; s >>= 1) {
        mx0 = fmaxf(mx0, __shfl_down(mx0, s));
        mx1 = fmaxf(mx1, __shfl_down(mx1, s));
        mx2 = fmaxf(mx2, __shfl_down(mx2, s));
        mx3 = fmaxf(mx3, __shfl_down(mx3, s));
    }
    if (lane == 0) { lm[wave][0] = mx0; lm[wave][1] = mx1; lm[wave][2] = mx2; lm[wave][3] = mx3; }
    __syncthreads();
    if (t < 4) m[t] = fmaxf(fmaxf(lm[0][t], lm[1][t]), fmaxf(lm[2][t], lm[3][t]));
    __syncthreads();

    float zp = 0.f;
    float2 acc = make_float2(0.f, 0.f);
    int head = t >> 6;
    int hh = t & 3;
    int eidx = t >> 2;
    const uint_t* hrow = (const uint_t*)h;
    for (int c0 = 0; c0 < deg; c0 += CH) {
        int ce = min(CH, deg - c0);
        if (eidx < ce) {
            int s = csr[beg + c0 + eidx];
            if (hh == 0) srcs[eidx] = s;
            float e = aS[s * 4 + hh] + adn[hh];
            e = e > 0.f ? e : NEG_SLOPE * e;
            float w = __expf(e - m[hh]);
            wch[eidx][hh] = w;
            zp += w;
        }
        __syncthreads();
#pragma unroll 4
        for (int j = 0; j < ce; ++j) {
            int s = srcs[j];
            float w = wch[j][head];
            uint_t hv = hrow[(size_t)s * 256 + t];
            acc.x = fmaf(w, bflo(hv), acc.x);
            acc.y = fmaf(w, bfhi(hv), acc.y);
        }
        __syncthreads();
    }

    red[t] = zp;
    __syncthreads();
    for (int s = 128; s >= 4; s >>= 1) {
        if (t < s) red[t] += red[t + s];
        __syncthreads();
    }
    if (t < 4) zv[t] = red[t];
    __syncthreads();

    float invz = 1.f / zv[head];
    *(float2*)&outs[2 * t] = make_float2(acc.x * invz, acc.y * invz);
    __syncthreads();
    if (t < 128) {
        float v = 0.25f * (outs[t] + outs[128 + t] + outs[256 + t] + outs[384 + t]) + bias[t];
        v = v > 0.f ? v : 0.f;
        float nx = x[(size_t)n * 128 + t] + v;
        x[(size_t)n * 128 + t] = nx;
        xb[(size_t)n * 128 + t] = f2bf(nx);
    }
}

// ---------------------------------------------------------------------------
// Prediction heads
__global__ __launch_bounds__(128) void pred_kernel(const float* __restrict__ x,
                                                   const float* __restrict__ W1,
                                                   const float* __restrict__ b1,
                                                   const float* __restrict__ W2,
                                                   const float* __restrict__ b2,
                                                   const float* __restrict__ vW,
                                                   const float* __restrict__ vb,
                                                   float* __restrict__ out) {
    int n = blockIdx.x, t = threadIdx.x;
    __shared__ float xr[128];
    __shared__ float h1[64];
    __shared__ float part[2];
    xr[t] = x[(size_t)n * 128 + t];
    __syncthreads();
    if (t < 64) {
        float a = b1[t];
        for (int k = 0; k < 128; ++k) a = fmaf(xr[k], W1[k * 64 + t], a);
        h1[t] = a > 0.f ? a : 0.f;
    }
    __syncthreads();
    float p = (t < 64) ? h1[t] * W2[t] : 0.f;
    float q = xr[t] * vW[t];
#pragma unroll
    for (int s = 32; s; s >>= 1) {
        p += __shfl_down(p, s);
        q += __shfl_down(q, s);
    }
    int lane = t & 63, wave = t >> 6;
    if (lane == 0) part[wave] = q;
    __syncthreads();
    if (t == 0) {
        out[n] = 1.f / (1.f + __expf(-(p + b2[0])));
        out[N_NODES + n] = 1.f / (1.f + __expf(-(part[0] + part[1] + vb[0])));
    }
}

// ---------------------------------------------------------------------------
extern "C" void kernel_launch(void* const* d_in, const int* in_sizes, int n_in,
                              void* d_out, int out_size, void* d_ws, size_t ws_size,
                              hipStream_t stream) {
    const float* nf    = (const float*)d_in[0];
    const int*   ei    = (const int*)d_in[1];
    const float* encW  = (const float*)d_in[2];
    const float* encb  = (const float*)d_in[3];
    const float* lin   = (const float*)d_in[4];
    const float* attS  = (const float*)d_in[5];
    const float* attD  = (const float*)d_in[6];
    const float* gbias = (const float*)d_in[7];
    const float* W1    = (const float*)d_in[8];
    const float* b1    = (const float*)d_in[9];
    const float* W2    = (const float*)d_in[10];
    const float* b2    = (const float*)d_in[11];
    const float* vW    = (const float*)d_in[12];
    const float* vb    = (const float*)d_in[13];
    float* out = (float*)d_out;

    char* ws = (char*)d_ws;
    size_t o = 0;
    auto alloc = [&](size_t bytes) {
        void* p = ws + o;
        o += (bytes + 255) & ~(size_t)255;
        return p;
    };
    float* x      = (float*)alloc((size_t)N_NODES * 128 * 4);
    ushort_t* xb  = (ushort_t*)alloc((size_t)N_PAD * 128 * 2);
    ushort_t* h   = (ushort_t*)alloc((size_t)N_PAD * 512 * 2);
    ushort_t* linP= (ushort_t*)alloc((size_t)3 * 512 * 128 * 2);
    float* aS     = (float*)alloc((size_t)N_NODES * 4 * 4);
    float* aD     = (float*)alloc((size_t)N_NODES * 4 * 4);
    int* deg      = (int*)alloc((size_t)N_NODES * 4);
    int* cursor   = (int*)alloc((size_t)N_NODES * 4);
    int* offs     = (int*)alloc((size_t)(N_NODES + 1) * 4);
    int* csr      = (int*)alloc((size_t)ET * 4);

    hipMemsetAsync(deg, 0, (size_t)N_NODES * 4, stream);
    hipMemsetAsync(cursor, 0, (size_t)N_NODES * 4, stream);
    // zero the 32 pad rows of xb so MFMA tiles read clean zeros
    hipMemsetAsync(xb + (size_t)N_NODES * 128, 0, (size_t)(N_PAD - N_NODES) * 128 * 2, stream);

    pack_w<<<96, 256, 0, stream>>>(lin, linP);
    enc_gemm<<<N_NODES / 8, 128, 0, stream>>>(nf, encW, encb, x, xb);
    hist_kernel<<<(ET + 255) / 256, 256, 0, stream>>>(ei, deg);
    scan_kernel<<<1, 1024, 0, stream>>>(deg, offs);
    scatter_kernel<<<(ET + 255) / 256, 256, 0, stream>>>(ei, offs, cursor, csr);

    dim3 ggrid(N_PAD / 64, 4);
    for (int l = 0; l < 3; ++l) {
        gat_h_mfma<<<ggrid, 256, 0, stream>>>(xb, linP + (size_t)l * 512 * 128, h);
        att_dots<<<N_NODES / 4, 256, 0, stream>>>(h, attS + (size_t)l * HEADS * 128,
                                                  attD + (size_t)l * HEADS * 128, aS, aD);
        gat_agg<<<N_NODES, 256, 0, stream>>>(h, aS, aD, offs, csr,
                                             gbias + (size_t)l * 128, x, xb);
    }
    pred_kernel<<<N_NODES, 128, 0, stream>>>(x, W1, b1, W2, b2, vW, vb, out);
}

// Round 4
// 321.910 us; speedup vs baseline: 1.8880x; 1.1659x over previous
//
#include <hip/hip_runtime.h>

#define N_NODES 20000
#define N_PAD 20032            // padded to multiple of 64 for MFMA tiles
#define F_IN 64
#define HID 128
#define HEADS 4
#define E_EDGES 320000
#define ET (E_EDGES + N_NODES)   // + self loops
#define NEG_SLOPE 0.2f

typedef unsigned short ushort_t;
typedef unsigned int uint_t;

using bf16x8 = __attribute__((ext_vector_type(8))) short;
using f32x4  = __attribute__((ext_vector_type(4))) float;

__device__ __forceinline__ ushort_t f2bf(float f) {
    union { float f; uint_t u; } v; v.f = f;
    uint_t r = v.u + 0x7fffu + ((v.u >> 16) & 1u);   // round-to-nearest-even
    return (ushort_t)(r >> 16);
}
__device__ __forceinline__ float bflo(uint_t w) {
    union { uint_t u; float f; } v; v.u = w << 16; return v.f;
}
__device__ __forceinline__ float bfhi(uint_t w) {
    union { uint_t u; float f; } v; v.u = w & 0xffff0000u; return v.f;
}
__device__ __forceinline__ float rdlane_f(float v, int j) {
    return __uint_as_float(__builtin_amdgcn_readlane(__float_as_uint(v), j));
}

// ---------------------------------------------------------------------------
// Encoder: x = relu(nf @ encW + encb); writes f32 x and bf16 xb
__global__ __launch_bounds__(128) void enc_gemm(const float* __restrict__ nf,
                                                const float* __restrict__ W,
                                                const float* __restrict__ b,
                                                float* __restrict__ x,
                                                ushort_t* __restrict__ xb) {
    __shared__ float xs[8][64];
    int t = threadIdx.x;
    int n0 = blockIdx.x * 8;
    for (int i = t; i < 8 * 64; i += 128)
        xs[i >> 6][i & 63] = nf[(size_t)n0 * 64 + i];
    __syncthreads();
    float acc[8];
#pragma unroll
    for (int i = 0; i < 8; ++i) acc[i] = 0.f;
    for (int k = 0; k < 64; ++k) {
        float w = W[k * 128 + t];
#pragma unroll
        for (int i = 0; i < 8; ++i) acc[i] = fmaf(xs[i][k], w, acc[i]);
    }
    float bias = b[t];
#pragma unroll
    for (int i = 0; i < 8; ++i) {
        float v = acc[i] + bias;
        v = v > 0.f ? v : 0.f;
        x[(size_t)(n0 + i) * 128 + t] = v;
        xb[(size_t)(n0 + i) * 128 + t] = f2bf(v);
    }
}

// ---------------------------------------------------------------------------
// Weight pre-pack: lin f32 [3][128][512] -> linP bf16 [3][512][128]
__global__ __launch_bounds__(256) void pack_w(const float* __restrict__ lin,
                                              ushort_t* __restrict__ linP) {
    int idx = blockIdx.x * 256 + threadIdx.x;     // 3*512*16 = 24576
    int l = idx / (512 * 16);
    int rem = idx % (512 * 16);
    int col = rem / 16, kg = rem % 16;
    const float* W = lin + (size_t)l * 128 * 512;
    ushort_t tmp[8];
#pragma unroll
    for (int j = 0; j < 8; ++j)
        tmp[j] = f2bf(W[(size_t)(kg * 8 + j) * 512 + col]);
    *(uint4*)(linP + ((size_t)l * 512 * 16 + rem) * 8) = *(const uint4*)tmp;
}

// ---------------------------------------------------------------------------
// CSR build (by destination), once per call
__global__ void hist_kernel(const int* __restrict__ ei, int* __restrict__ deg) {
    int e = blockIdx.x * 256 + threadIdx.x;
    if (e >= ET) return;
    int d = (e < E_EDGES) ? ei[E_EDGES + e] : (e - E_EDGES);
    atomicAdd(&deg[d], 1);
}

__global__ __launch_bounds__(1024) void scan_kernel(const int* __restrict__ deg,
                                                    int* __restrict__ off) {
    __shared__ int sums[1024];
    int t = threadIdx.x;
    int base = t * 20;
    int tmp[20];
    int s = 0;
#pragma unroll
    for (int i = 0; i < 20; ++i) {
        int idx = base + i;
        int v = (idx < N_NODES) ? deg[idx] : 0;
        tmp[i] = s;
        s += v;
    }
    sums[t] = s;
    __syncthreads();
    for (int st = 1; st < 1024; st <<= 1) {
        int v = (t >= st) ? sums[t - st] : 0;
        __syncthreads();
        sums[t] += v;
        __syncthreads();
    }
    int bsum = (t == 0) ? 0 : sums[t - 1];
#pragma unroll
    for (int i = 0; i < 20; ++i) {
        int idx = base + i;
        if (idx < N_NODES) off[idx] = bsum + tmp[i];
    }
    if (t == 1023) off[N_NODES] = sums[1023];
}

__global__ void scatter_kernel(const int* __restrict__ ei, const int* __restrict__ off,
                               int* __restrict__ cursor, int* __restrict__ csr) {
    int e = blockIdx.x * 256 + threadIdx.x;
    if (e >= ET) return;
    int s, d;
    if (e < E_EDGES) { s = ei[e]; d = ei[E_EDGES + e]; }
    else             { s = d = e - E_EDGES; }
    int pos = atomicAdd(&cursor[d], 1);
    csr[off[d] + pos] = s;
}

// ---------------------------------------------------------------------------
// h = xb @ linP via MFMA bf16, with fused a_src/a_dst per-head dots.
// Grid (313, 4): blockIdx.y = head; block covers 64 rows x 128 cols (one head).
// 4 waves (2x2): wave (wr,wc) -> rows bx*64+wr*32..+32, cols head*128+wc*64..+64
__global__ __launch_bounds__(256) void gat_h_mfma(const ushort_t* __restrict__ xb,
                                                  const ushort_t* __restrict__ Bp,
                                                  const float* __restrict__ attS,
                                                  const float* __restrict__ attD,
                                                  ushort_t* __restrict__ h,
                                                  float* __restrict__ aS,
                                                  float* __restrict__ aD) {
    int t = threadIdx.x;
    int lane = t & 63, w = t >> 6;
    int wr = w >> 1, wc = w & 1;
    int head = blockIdx.y;
    int bm0 = blockIdx.x * 64 + wr * 32;
    int bn0 = head * 128 + wc * 64;
    int r16 = lane & 15, g = lane >> 4;

    const ushort_t* arow = xb + (size_t)(bm0 + r16) * 128 + g * 8;
    const ushort_t* bcol = Bp + (size_t)(bn0 + r16) * 128 + g * 8;

    f32x4 acc[2][4] = {};
#pragma unroll
    for (int k0 = 0; k0 < 128; k0 += 32) {
        bf16x8 a0 = *(const bf16x8*)(arow + k0);
        bf16x8 a1 = *(const bf16x8*)(arow + 16 * 128 + k0);
        bf16x8 b0 = *(const bf16x8*)(bcol + k0);
        bf16x8 b1 = *(const bf16x8*)(bcol + 16 * 128 + k0);
        bf16x8 b2 = *(const bf16x8*)(bcol + 32 * 128 + k0);
        bf16x8 b3 = *(const bf16x8*)(bcol + 48 * 128 + k0);
        acc[0][0] = __builtin_amdgcn_mfma_f32_16x16x32_bf16(a0, b0, acc[0][0], 0, 0, 0);
        acc[0][1] = __builtin_amdgcn_mfma_f32_16x16x32_bf16(a0, b1, acc[0][1], 0, 0, 0);
        acc[0][2] = __builtin_amdgcn_mfma_f32_16x16x32_bf16(a0, b2, acc[0][2], 0, 0, 0);
        acc[0][3] = __builtin_amdgcn_mfma_f32_16x16x32_bf16(a0, b3, acc[0][3], 0, 0, 0);
        acc[1][0] = __builtin_amdgcn_mfma_f32_16x16x32_bf16(a1, b0, acc[1][0], 0, 0, 0);
        acc[1][1] = __builtin_amdgcn_mfma_f32_16x16x32_bf16(a1, b1, acc[1][1], 0, 0, 0);
        acc[1][2] = __builtin_amdgcn_mfma_f32_16x16x32_bf16(a1, b2, acc[1][2], 0, 0, 0);
        acc[1][3] = __builtin_amdgcn_mfma_f32_16x16x32_bf16(a1, b3, acc[1][3], 0, 0, 0);
    }

    // h store: C/D layout col=lane&15, row=(lane>>4)*4+reg  [verified]
#pragma unroll
    for (int fm = 0; fm < 2; ++fm)
#pragma unroll
        for (int fn = 0; fn < 4; ++fn)
#pragma unroll
            for (int r = 0; r < 4; ++r) {
                int row = bm0 + fm * 16 + g * 4 + r;
                int col = bn0 + fn * 16 + r16;
                h[(size_t)row * 512 + col] = f2bf(acc[fm][fn][r]);
            }

    // fused attention dots: aS[row][head] = sum_d h[row][head][d]*attS[head][d]
    float ws[4], wd[4];
#pragma unroll
    for (int fn = 0; fn < 4; ++fn) {
        int cih = wc * 64 + fn * 16 + r16;      // col within head
        ws[fn] = attS[head * 128 + cih];
        wd[fn] = attD[head * 128 + cih];
    }
    __shared__ float pS[2][64], pD[2][64];
#pragma unroll
    for (int fm = 0; fm < 2; ++fm)
#pragma unroll
        for (int r = 0; r < 4; ++r) {
            float sS = acc[fm][0][r] * ws[0] + acc[fm][1][r] * ws[1]
                     + acc[fm][2][r] * ws[2] + acc[fm][3][r] * ws[3];
            float sD = acc[fm][0][r] * wd[0] + acc[fm][1][r] * wd[1]
                     + acc[fm][2][r] * wd[2] + acc[fm][3][r] * wd[3];
#pragma unroll
            for (int st = 1; st < 16; st <<= 1) {
                sS += __shfl_xor(sS, st);
                sD += __shfl_xor(sD, st);
            }
            if (r16 == 0) {
                int lr_ = wr * 32 + fm * 16 + g * 4 + r;
                pS[wc][lr_] = sS;
                pD[wc][lr_] = sD;
            }
        }
    __syncthreads();
    if (t < 64) {
        int row = blockIdx.x * 64 + t;
        aS[(size_t)row * 4 + head] = pS[0][t] + pS[1][t];
        aD[(size_t)row * 4 + head] = pD[0][t] + pD[1][t];
    }
}

// ---------------------------------------------------------------------------
// Aggregation: ONE WAVE per dst node, no LDS, no barriers.
// Lane l owns dims 8l..8l+7 (head = l>>4). Per edge: readlane src broadcast,
// lane recomputes its head's softmax weight from aS, uint4 bf16 gather + 8 FMA.
__global__ __launch_bounds__(256) void gat_agg(const ushort_t* __restrict__ h,
                                               const float* __restrict__ aS,
                                               const float* __restrict__ aD,
                                               const int* __restrict__ off,
                                               const int* __restrict__ csr,
                                               const float* __restrict__ bias,
                                               float* __restrict__ x,
                                               ushort_t* __restrict__ xb) {
    int t = threadIdx.x;
    int w = t >> 6, l = t & 63;
    int n = blockIdx.x * 4 + w;
    int head = l >> 4;
    int beg = off[n];
    int deg = off[n + 1] - beg;

    float4 adv = *(const float4*)(aD + (size_t)n * 4);

    // phase 1: per-head max of aS over neighbors (leaky_relu is monotone:
    // max lr(aS+adn) == lr(max aS + adn))
    float4 smax = make_float4(-1e30f, -1e30f, -1e30f, -1e30f);
    for (int i = l; i < deg; i += 64) {
        int s = csr[beg + i];
        float4 a = *(const float4*)(aS + (size_t)s * 4);
        smax.x = fmaxf(smax.x, a.x);
        smax.y = fmaxf(smax.y, a.y);
        smax.z = fmaxf(smax.z, a.z);
        smax.w = fmaxf(smax.w, a.w);
    }
#pragma unroll
    for (int st = 1; st < 64; st <<= 1) {
        smax.x = fmaxf(smax.x, __shfl_xor(smax.x, st));
        smax.y = fmaxf(smax.y, __shfl_xor(smax.y, st));
        smax.z = fmaxf(smax.z, __shfl_xor(smax.z, st));
        smax.w = fmaxf(smax.w, __shfl_xor(smax.w, st));
    }
    float e;
    e = smax.x + adv.x; float m0 = e > 0.f ? e : NEG_SLOPE * e;
    e = smax.y + adv.y; float m1 = e > 0.f ? e : NEG_SLOPE * e;
    e = smax.z + adv.z; float m2 = e > 0.f ? e : NEG_SLOPE * e;
    e = smax.w + adv.w; float m3 = e > 0.f ? e : NEG_SLOPE * e;
    float mh  = head == 0 ? m0 : head == 1 ? m1 : head == 2 ? m2 : m3;
    float adh = head == 0 ? adv.x : head == 1 ? adv.y : head == 2 ? adv.z : adv.w;

    // phase 2: gather
    float z = 0.f;
    float acc[8];
#pragma unroll
    for (int i = 0; i < 8; ++i) acc[i] = 0.f;
    const float* aSh = aS + head;
    for (int c0 = 0; c0 < deg; c0 += 64) {
        int ce = min(64, deg - c0);
        int myS = (l < ce) ? csr[beg + c0 + l] : 0;
#pragma unroll 2
        for (int j = 0; j < ce; ++j) {
            int s = __builtin_amdgcn_readlane(myS, j);
            float ash = aSh[(size_t)s * 4];
            float ev = ash + adh;
            ev = ev > 0.f ? ev : NEG_SLOPE * ev;
            float wgt = __expf(ev - mh);
            z += wgt;
            uint4 hv = *(const uint4*)(h + (size_t)s * 512 + l * 8);
            acc[0] = fmaf(wgt, bflo(hv.x), acc[0]);
            acc[1] = fmaf(wgt, bfhi(hv.x), acc[1]);
            acc[2] = fmaf(wgt, bflo(hv.y), acc[2]);
            acc[3] = fmaf(wgt, bfhi(hv.y), acc[3]);
            acc[4] = fmaf(wgt, bflo(hv.z), acc[4]);
            acc[5] = fmaf(wgt, bfhi(hv.z), acc[5]);
            acc[6] = fmaf(wgt, bflo(hv.w), acc[6]);
            acc[7] = fmaf(wgt, bfhi(hv.w), acc[7]);
        }
    }

    // normalize by z (complete per lane), then mean over heads via shfl_xor
    float invz = 1.f / z;
#pragma unroll
    for (int i = 0; i < 8; ++i) acc[i] *= invz;
#pragma unroll
    for (int i = 0; i < 8; ++i) {
        acc[i] += __shfl_xor(acc[i], 16);
        acc[i] += __shfl_xor(acc[i], 32);
    }

    if (l < 16) {
        float4 xv0 = *(const float4*)(x + (size_t)n * 128 + l * 8);
        float4 xv1 = *(const float4*)(x + (size_t)n * 128 + l * 8 + 4);
        float4 b0 = *(const float4*)(bias + l * 8);
        float4 b1 = *(const float4*)(bias + l * 8 + 4);
        float o[8];
        o[0] = 0.25f * acc[0] + b0.x; o[1] = 0.25f * acc[1] + b0.y;
        o[2] = 0.25f * acc[2] + b0.z; o[3] = 0.25f * acc[3] + b0.w;
        o[4] = 0.25f * acc[4] + b1.x; o[5] = 0.25f * acc[5] + b1.y;
        o[6] = 0.25f * acc[6] + b1.z; o[7] = 0.25f * acc[7] + b1.w;
#pragma unroll
        for (int i = 0; i < 8; ++i) o[i] = o[i] > 0.f ? o[i] : 0.f;
        float nx[8];
        nx[0] = xv0.x + o[0]; nx[1] = xv0.y + o[1];
        nx[2] = xv0.z + o[2]; nx[3] = xv0.w + o[3];
        nx[4] = xv1.x + o[4]; nx[5] = xv1.y + o[5];
        nx[6] = xv1.z + o[6]; nx[7] = xv1.w + o[7];
        *(float4*)(x + (size_t)n * 128 + l * 8) = make_float4(nx[0], nx[1], nx[2], nx[3]);
        *(float4*)(x + (size_t)n * 128 + l * 8 + 4) = make_float4(nx[4], nx[5], nx[6], nx[7]);
        ushort_t ob[8];
#pragma unroll
        for (int i = 0; i < 8; ++i) ob[i] = f2bf(nx[i]);
        *(uint4*)(xb + (size_t)n * 128 + l * 8) = *(const uint4*)ob;
    }
}

// ---------------------------------------------------------------------------
// Prediction heads
__global__ __launch_bounds__(128) void pred_kernel(const float* __restrict__ x,
                                                   const float* __restrict__ W1,
                                                   const float* __restrict__ b1,
                                                   const float* __restrict__ W2,
                                                   const float* __restrict__ b2,
                                                   const float* __restrict__ vW,
                                                   const float* __restrict__ vb,
                                                   float* __restrict__ out) {
    int n = blockIdx.x, t = threadIdx.x;
    __shared__ float xr[128];
    __shared__ float h1[64];
    __shared__ float part[2];
    xr[t] = x[(size_t)n * 128 + t];
    __syncthreads();
    if (t < 64) {
        float a = b1[t];
        for (int k = 0; k < 128; ++k) a = fmaf(xr[k], W1[k * 64 + t], a);
        h1[t] = a > 0.f ? a : 0.f;
    }
    __syncthreads();
    float p = (t < 64) ? h1[t] * W2[t] : 0.f;
    float q = xr[t] * vW[t];
#pragma unroll
    for (int s = 32; s; s >>= 1) {
        p += __shfl_down(p, s);
        q += __shfl_down(q, s);
    }
    int lane = t & 63, wave = t >> 6;
    if (lane == 0) part[wave] = q;
    __syncthreads();
    if (t == 0) {
        out[n] = 1.f / (1.f + __expf(-(p + b2[0])));
        out[N_NODES + n] = 1.f / (1.f + __expf(-(part[0] + part[1] + vb[0])));
    }
}

// ---------------------------------------------------------------------------
extern "C" void kernel_launch(void* const* d_in, const int* in_sizes, int n_in,
                              void* d_out, int out_size, void* d_ws, size_t ws_size,
                              hipStream_t stream) {
    const float* nf    = (const float*)d_in[0];
    const int*   ei    = (const int*)d_in[1];
    const float* encW  = (const float*)d_in[2];
    const float* encb  = (const float*)d_in[3];
    const float* lin   = (const float*)d_in[4];
    const float* attS  = (const float*)d_in[5];
    const float* attD  = (const float*)d_in[6];
    const float* gbias = (const float*)d_in[7];
    const float* W1    = (const float*)d_in[8];
    const float* b1    = (const float*)d_in[9];
    const float* W2    = (const float*)d_in[10];
    const float* b2    = (const float*)d_in[11];
    const float* vW    = (const float*)d_in[12];
    const float* vb    = (const float*)d_in[13];
    float* out = (float*)d_out;

    char* ws = (char*)d_ws;
    size_t o = 0;
    auto alloc = [&](size_t bytes) {
        void* p = ws + o;
        o += (bytes + 255) & ~(size_t)255;
        return p;
    };
    float* x      = (float*)alloc((size_t)N_NODES * 128 * 4);
    ushort_t* xb  = (ushort_t*)alloc((size_t)N_PAD * 128 * 2);
    ushort_t* h   = (ushort_t*)alloc((size_t)N_PAD * 512 * 2);
    ushort_t* linP= (ushort_t*)alloc((size_t)3 * 512 * 128 * 2);
    float* aS     = (float*)alloc((size_t)N_PAD * 4 * 4);
    float* aD     = (float*)alloc((size_t)N_PAD * 4 * 4);
    int* deg      = (int*)alloc((size_t)N_NODES * 4);
    int* cursor   = (int*)alloc((size_t)N_NODES * 4);
    int* offs     = (int*)alloc((size_t)(N_NODES + 1) * 4);
    int* csr      = (int*)alloc((size_t)ET * 4);

    hipMemsetAsync(deg, 0, (size_t)N_NODES * 4, stream);
    hipMemsetAsync(cursor, 0, (size_t)N_NODES * 4, stream);
    hipMemsetAsync(xb + (size_t)N_NODES * 128, 0, (size_t)(N_PAD - N_NODES) * 128 * 2, stream);

    pack_w<<<96, 256, 0, stream>>>(lin, linP);
    enc_gemm<<<N_NODES / 8, 128, 0, stream>>>(nf, encW, encb, x, xb);
    hist_kernel<<<(ET + 255) / 256, 256, 0, stream>>>(ei, deg);
    scan_kernel<<<1, 1024, 0, stream>>>(deg, offs);
    scatter_kernel<<<(ET + 255) / 256, 256, 0, stream>>>(ei, offs, cursor, csr);

    dim3 ggrid(N_PAD / 64, 4);
    for (int l = 0; l < 3; ++l) {
        gat_h_mfma<<<ggrid, 256, 0, stream>>>(xb, linP + (size_t)l * 512 * 128,
                                              attS + (size_t)l * HEADS * 128,
                                              attD + (size_t)l * HEADS * 128,
                                              h, aS, aD);
        gat_agg<<<N_NODES / 4, 256, 0, stream>>>(h, aS, aD, offs, csr,
                                                 gbias + (size_t)l * 128, x, xb);
    }
    pred_kernel<<<N_NODES, 128, 0, stream>>>(x, W1, b1, W2, b2, vW, vb, out);
}

// Round 5
// 306.341 us; speedup vs baseline: 1.9840x; 1.0508x over previous
//
#include <hip/hip_runtime.h>

#define N_NODES 20000
#define N_PAD 20032            // padded to multiple of 64 for MFMA tiles
#define F_IN 64
#define HID 128
#define HEADS 4
#define E_EDGES 320000
#define ET (E_EDGES + N_NODES)   // + self loops
#define NEG_SLOPE 0.2f

typedef unsigned short ushort_t;
typedef unsigned int uint_t;

using bf16x8 = __attribute__((ext_vector_type(8))) short;
using f32x4  = __attribute__((ext_vector_type(4))) float;

__device__ __forceinline__ ushort_t f2bf(float f) {
    union { float f; uint_t u; } v; v.f = f;
    uint_t r = v.u + 0x7fffu + ((v.u >> 16) & 1u);   // round-to-nearest-even
    return (ushort_t)(r >> 16);
}
__device__ __forceinline__ float bflo(uint_t w) {
    union { uint_t u; float f; } v; v.u = w << 16; return v.f;
}
__device__ __forceinline__ float bfhi(uint_t w) {
    union { uint_t u; float f; } v; v.u = w & 0xffff0000u; return v.f;
}
__device__ __forceinline__ float rdlane_f(float v, int j) {
    return __uint_as_float(__builtin_amdgcn_readlane(__float_as_uint(v), j));
}

// ---------------------------------------------------------------------------
// Encoder: x = relu(nf @ encW + encb); writes f32 x and bf16 xb
__global__ __launch_bounds__(128) void enc_gemm(const float* __restrict__ nf,
                                                const float* __restrict__ W,
                                                const float* __restrict__ b,
                                                float* __restrict__ x,
                                                ushort_t* __restrict__ xb) {
    __shared__ float xs[8][64];
    int t = threadIdx.x;
    int n0 = blockIdx.x * 8;
    for (int i = t; i < 8 * 64; i += 128)
        xs[i >> 6][i & 63] = nf[(size_t)n0 * 64 + i];
    __syncthreads();
    float acc[8];
#pragma unroll
    for (int i = 0; i < 8; ++i) acc[i] = 0.f;
    for (int k = 0; k < 64; ++k) {
        float w = W[k * 128 + t];
#pragma unroll
        for (int i = 0; i < 8; ++i) acc[i] = fmaf(xs[i][k], w, acc[i]);
    }
    float bias = b[t];
#pragma unroll
    for (int i = 0; i < 8; ++i) {
        float v = acc[i] + bias;
        v = v > 0.f ? v : 0.f;
        x[(size_t)(n0 + i) * 128 + t] = v;
        xb[(size_t)(n0 + i) * 128 + t] = f2bf(v);
    }
}

// ---------------------------------------------------------------------------
// Pack W-bar: Bp[l][col][kk] = lin[l][ kk&127 ][ (kk>>7)*128 + col ], bf16.
// (kk = h*128 + k;  out = 0.25 * Ubar @ Wbar)
__global__ __launch_bounds__(256) void pack_bw(const float* __restrict__ lin,
                                               ushort_t* __restrict__ Bp) {
    int idx = blockIdx.x * 256 + threadIdx.x;   // 3*128*64 = 24576
    int l = idx / 8192;
    int rem = idx % 8192;
    int col = rem / 64, kg = rem % 64;
    const float* W = lin + (size_t)l * 128 * 512;
    int h = kg >> 4;
    int kbase = (kg & 15) * 8;
    ushort_t tmp[8];
#pragma unroll
    for (int j = 0; j < 8; ++j)
        tmp[j] = f2bf(W[(size_t)(kbase + j) * 512 + h * 128 + col]);
    *(uint4*)(Bp + ((size_t)(l * 128 + col)) * 512 + kg * 8) = *(const uint4*)tmp;
}

// w-tilde: wtS[l][h][k] = sum_d lin[l][k][h*128+d] * attS[l][h][d] (f32)
__global__ __launch_bounds__(256) void pack_wt(const float* __restrict__ lin,
                                               const float* __restrict__ attS,
                                               const float* __restrict__ attD,
                                               float* __restrict__ wtS,
                                               float* __restrict__ wtD) {
    int idx = blockIdx.x * 256 + threadIdx.x;   // 3*4*128 = 1536
    if (idx >= 1536) return;
    int l = idx / 512;
    int rem = idx % 512;
    int h = rem >> 7, k = rem & 127;
    const float* W = lin + (size_t)l * 128 * 512 + (size_t)k * 512 + h * 128;
    const float* as = attS + (size_t)l * 512 + h * 128;
    const float* ad = attD + (size_t)l * 512 + h * 128;
    float ss = 0.f, sd = 0.f;
    for (int d = 0; d < 128; ++d) {
        float w = W[d];
        ss = fmaf(w, as[d], ss);
        sd = fmaf(w, ad[d], sd);
    }
    wtS[idx] = ss;
    wtD[idx] = sd;
}

// W1 pack: W1p[col][k] = W1[k*64+col] bf16  (64 cols, 128 k)
__global__ __launch_bounds__(256) void pack_w1(const float* __restrict__ W1,
                                               ushort_t* __restrict__ W1p) {
    int idx = blockIdx.x * 256 + threadIdx.x;   // 64*16 = 1024
    if (idx >= 1024) return;
    int col = idx >> 4, kg = idx & 15;
    ushort_t tmp[8];
#pragma unroll
    for (int j = 0; j < 8; ++j)
        tmp[j] = f2bf(W1[(size_t)(kg * 8 + j) * 64 + col]);
    *(uint4*)(W1p + (size_t)col * 128 + kg * 8) = *(const uint4*)tmp;
}

// ---------------------------------------------------------------------------
// CSR build (by destination), once per call
__global__ void hist_kernel(const int* __restrict__ ei, int* __restrict__ deg) {
    int e = blockIdx.x * 256 + threadIdx.x;
    if (e >= ET) return;
    int d = (e < E_EDGES) ? ei[E_EDGES + e] : (e - E_EDGES);
    atomicAdd(&deg[d], 1);
}

__global__ __launch_bounds__(1024) void scan_kernel(const int* __restrict__ deg,
                                                    int* __restrict__ off) {
    __shared__ int sums[1024];
    int t = threadIdx.x;
    int base = t * 20;
    int tmp[20];
    int s = 0;
#pragma unroll
    for (int i = 0; i < 20; ++i) {
        int idx = base + i;
        int v = (idx < N_NODES) ? deg[idx] : 0;
        tmp[i] = s;
        s += v;
    }
    sums[t] = s;
    __syncthreads();
    for (int st = 1; st < 1024; st <<= 1) {
        int v = (t >= st) ? sums[t - st] : 0;
        __syncthreads();
        sums[t] += v;
        __syncthreads();
    }
    int bsum = (t == 0) ? 0 : sums[t - 1];
#pragma unroll
    for (int i = 0; i < 20; ++i) {
        int idx = base + i;
        if (idx < N_NODES) off[idx] = bsum + tmp[i];
    }
    if (t == 1023) off[N_NODES] = sums[1023];
}

__global__ void scatter_kernel(const int* __restrict__ ei, const int* __restrict__ off,
                               int* __restrict__ cursor, int* __restrict__ csr) {
    int e = blockIdx.x * 256 + threadIdx.x;
    if (e >= ET) return;
    int s, d;
    if (e < E_EDGES) { s = ei[e]; d = ei[E_EDGES + e]; }
    else             { s = d = e - E_EDGES; }
    int pos = atomicAdd(&cursor[d], 1);
    csr[off[d] + pos] = s;
}

// ---------------------------------------------------------------------------
// dots: aS[n][h] = xb[n] . wtS[l][h], aD similarly. 32 nodes/block,
// 8 threads per node (16 dims each), w-tilde staged in LDS.
__global__ __launch_bounds__(256) void dots_kernel(const ushort_t* __restrict__ xb,
                                                   const float* __restrict__ wtS,
                                                   const float* __restrict__ wtD,
                                                   float* __restrict__ aS,
                                                   float* __restrict__ aD) {
    __shared__ float ls[4][128], ld_[4][128];
    int t = threadIdx.x;
    for (int i = t; i < 512; i += 256) {
        ls[i >> 7][i & 127] = wtS[i];
        ld_[i >> 7][i & 127] = wtD[i];
    }
    __syncthreads();
    int n = blockIdx.x * 32 + (t >> 3);
    int p = t & 7;
    const uint_t* xr = (const uint_t*)xb + (size_t)n * 64 + p * 8;
    float pS[4] = {0.f, 0.f, 0.f, 0.f}, pD[4] = {0.f, 0.f, 0.f, 0.f};
#pragma unroll
    for (int j = 0; j < 8; ++j) {
        uint_t u = xr[j];
        float f0 = bflo(u), f1 = bfhi(u);
        int d = p * 16 + j * 2;
#pragma unroll
        for (int h = 0; h < 4; ++h) {
            pS[h] = fmaf(f0, ls[h][d], fmaf(f1, ls[h][d + 1], pS[h]));
            pD[h] = fmaf(f0, ld_[h][d], fmaf(f1, ld_[h][d + 1], pD[h]));
        }
    }
#pragma unroll
    for (int st = 1; st < 8; st <<= 1) {
#pragma unroll
        for (int h = 0; h < 4; ++h) {
            pS[h] += __shfl_xor(pS[h], st);
            pD[h] += __shfl_xor(pD[h], st);
        }
    }
    if (p == 0) {
        *(float4*)(aS + (size_t)n * 4) = make_float4(pS[0], pS[1], pS[2], pS[3]);
        *(float4*)(aD + (size_t)n * 4) = make_float4(pD[0], pD[1], pD[2], pD[3]);
    }
}

// ---------------------------------------------------------------------------
// Aggregation in x-space: ONE WAVE per dst node. Lane l owns dims (2l,2l+1).
// Gathers x[src] (256B/edge), accumulates 4 head-weighted sums, normalizes,
// writes Ubar[n][h*128 + 2l .. +1] bf16.
__global__ __launch_bounds__(256) void gat_agg(const uint_t* __restrict__ xb2,
                                               const float* __restrict__ aS,
                                               const float* __restrict__ aD,
                                               const int* __restrict__ off,
                                               const int* __restrict__ csr,
                                               uint_t* __restrict__ Ub2) {
    int t = threadIdx.x;
    int w = t >> 6, l = t & 63;
    int n = blockIdx.x * 4 + w;
    int beg = off[n];
    int deg = off[n + 1] - beg;

    float4 adv = *(const float4*)(aD + (size_t)n * 4);

    // phase 1: per-head max of aS over neighbors (leaky_relu monotone)
    float4 smax = make_float4(-1e30f, -1e30f, -1e30f, -1e30f);
    for (int i = l; i < deg; i += 64) {
        int s = csr[beg + i];
        float4 a = *(const float4*)(aS + (size_t)s * 4);
        smax.x = fmaxf(smax.x, a.x);
        smax.y = fmaxf(smax.y, a.y);
        smax.z = fmaxf(smax.z, a.z);
        smax.w = fmaxf(smax.w, a.w);
    }
#pragma unroll
    for (int st = 1; st < 64; st <<= 1) {
        smax.x = fmaxf(smax.x, __shfl_xor(smax.x, st));
        smax.y = fmaxf(smax.y, __shfl_xor(smax.y, st));
        smax.z = fmaxf(smax.z, __shfl_xor(smax.z, st));
        smax.w = fmaxf(smax.w, __shfl_xor(smax.w, st));
    }
    float e;
    e = smax.x + adv.x; float m0 = e > 0.f ? e : NEG_SLOPE * e;
    e = smax.y + adv.y; float m1 = e > 0.f ? e : NEG_SLOPE * e;
    e = smax.z + adv.z; float m2 = e > 0.f ? e : NEG_SLOPE * e;
    e = smax.w + adv.w; float m3 = e > 0.f ? e : NEG_SLOPE * e;

    // phase 2: chunked gather of x[src] with per-head weights
    float acc[8];
#pragma unroll
    for (int i = 0; i < 8; ++i) acc[i] = 0.f;
    float4 zac = make_float4(0.f, 0.f, 0.f, 0.f);
    for (int c0 = 0; c0 < deg; c0 += 64) {
        int ce = min(64, deg - c0);
        int sl = 0;
        float4 wv = make_float4(0.f, 0.f, 0.f, 0.f);
        if (l < ce) {
            sl = csr[beg + c0 + l];
            float4 a = *(const float4*)(aS + (size_t)sl * 4);
            e = a.x + adv.x; e = e > 0.f ? e : NEG_SLOPE * e; wv.x = __expf(e - m0);
            e = a.y + adv.y; e = e > 0.f ? e : NEG_SLOPE * e; wv.y = __expf(e - m1);
            e = a.z + adv.z; e = e > 0.f ? e : NEG_SLOPE * e; wv.z = __expf(e - m2);
            e = a.w + adv.w; e = e > 0.f ? e : NEG_SLOPE * e; wv.w = __expf(e - m3);
            zac.x += wv.x; zac.y += wv.y; zac.z += wv.z; zac.w += wv.w;
        }
#pragma unroll 2
        for (int j = 0; j < ce; ++j) {
            int s = __builtin_amdgcn_readlane(sl, j);
            float w0 = rdlane_f(wv.x, j);
            float w1 = rdlane_f(wv.y, j);
            float w2 = rdlane_f(wv.z, j);
            float w3 = rdlane_f(wv.w, j);
            uint_t xv = xb2[(size_t)s * 64 + l];
            float f0 = bflo(xv), f1 = bfhi(xv);
            acc[0] = fmaf(w0, f0, acc[0]); acc[1] = fmaf(w0, f1, acc[1]);
            acc[2] = fmaf(w1, f0, acc[2]); acc[3] = fmaf(w1, f1, acc[3]);
            acc[4] = fmaf(w2, f0, acc[4]); acc[5] = fmaf(w2, f1, acc[5]);
            acc[6] = fmaf(w3, f0, acc[6]); acc[7] = fmaf(w3, f1, acc[7]);
        }
    }

    // z: wave-sum of per-lane weight sums
#pragma unroll
    for (int st = 1; st < 64; st <<= 1) {
        zac.x += __shfl_xor(zac.x, st);
        zac.y += __shfl_xor(zac.y, st);
        zac.z += __shfl_xor(zac.z, st);
        zac.w += __shfl_xor(zac.w, st);
    }
    float iz0 = 1.f / zac.x, iz1 = 1.f / zac.y, iz2 = 1.f / zac.z, iz3 = 1.f / zac.w;
    uint_t o0 = (uint_t)f2bf(acc[0] * iz0) | ((uint_t)f2bf(acc[1] * iz0) << 16);
    uint_t o1 = (uint_t)f2bf(acc[2] * iz1) | ((uint_t)f2bf(acc[3] * iz1) << 16);
    uint_t o2 = (uint_t)f2bf(acc[4] * iz2) | ((uint_t)f2bf(acc[5] * iz2) << 16);
    uint_t o3 = (uint_t)f2bf(acc[6] * iz3) | ((uint_t)f2bf(acc[7] * iz3) << 16);
    size_t base = (size_t)n * 256;
    Ub2[base + l]       = o0;
    Ub2[base + 64 + l]  = o1;
    Ub2[base + 128 + l] = o2;
    Ub2[base + 192 + l] = o3;
}

// ---------------------------------------------------------------------------
// ugemm: x += relu(0.25 * Ubar @ Wbar + bias); update x (f32) and xb (bf16).
// [20032,512]@[512,128]; grid (313,2); 4 waves (2x2), wave = 32x32 tile.
__global__ __launch_bounds__(256) void ugemm(const ushort_t* __restrict__ Ub,
                                             const ushort_t* __restrict__ Bp,
                                             const float* __restrict__ bias,
                                             float* __restrict__ x,
                                             ushort_t* __restrict__ xb) {
    int t = threadIdx.x;
    int lane = t & 63, w = t >> 6;
    int wr = w >> 1, wc = w & 1;
    int bm0 = blockIdx.x * 64 + wr * 32;
    int bn0 = blockIdx.y * 64 + wc * 32;
    int r16 = lane & 15, g = lane >> 4;

    const ushort_t* arow = Ub + (size_t)(bm0 + r16) * 512 + g * 8;
    const ushort_t* bcol = Bp + (size_t)(bn0 + r16) * 512 + g * 8;

    f32x4 acc[2][2] = {};
#pragma unroll 4
    for (int k0 = 0; k0 < 512; k0 += 32) {
        bf16x8 a0 = *(const bf16x8*)(arow + k0);
        bf16x8 a1 = *(const bf16x8*)(arow + 16 * 512 + k0);
        bf16x8 b0 = *(const bf16x8*)(bcol + k0);
        bf16x8 b1 = *(const bf16x8*)(bcol + 16 * 512 + k0);
        acc[0][0] = __builtin_amdgcn_mfma_f32_16x16x32_bf16(a0, b0, acc[0][0], 0, 0, 0);
        acc[0][1] = __builtin_amdgcn_mfma_f32_16x16x32_bf16(a0, b1, acc[0][1], 0, 0, 0);
        acc[1][0] = __builtin_amdgcn_mfma_f32_16x16x32_bf16(a1, b0, acc[1][0], 0, 0, 0);
        acc[1][1] = __builtin_amdgcn_mfma_f32_16x16x32_bf16(a1, b1, acc[1][1], 0, 0, 0);
    }

    float bia[2] = {bias[bn0 + r16], bias[bn0 + 16 + r16]};
#pragma unroll
    for (int fm = 0; fm < 2; ++fm)
#pragma unroll
        for (int fn = 0; fn < 2; ++fn) {
            int col = bn0 + fn * 16 + r16;
#pragma unroll
            for (int r = 0; r < 4; ++r) {
                int row = bm0 + fm * 16 + g * 4 + r;
                if (row < N_NODES) {
                    float v = 0.25f * acc[fm][fn][r] + bia[fn];
                    v = v > 0.f ? v : 0.f;
                    float nx = x[(size_t)row * 128 + col] + v;
                    x[(size_t)row * 128 + col] = nx;
                    xb[(size_t)row * 128 + col] = f2bf(nx);
                }
            }
        }
}

// ---------------------------------------------------------------------------
// Prediction: MFMA for h1 = relu(xb@W1p + b1); attack = sigmoid(h1.W2 + b2);
// vuln = sigmoid(x.vW + vb). Block = 64 rows, 4 waves (2x2), cols 64.
__global__ __launch_bounds__(256) void pred_kernel(const float* __restrict__ x,
                                                   const ushort_t* __restrict__ xb,
                                                   const ushort_t* __restrict__ W1p,
                                                   const float* __restrict__ b1,
                                                   const float* __restrict__ W2,
                                                   const float* __restrict__ b2,
                                                   const float* __restrict__ vW,
                                                   const float* __restrict__ vb,
                                                   float* __restrict__ out) {
    int t = threadIdx.x;
    int lane = t & 63, w = t >> 6;
    int wr = w >> 1, wc = w & 1;
    int bm0 = blockIdx.x * 64 + wr * 32;
    int bn0 = wc * 32;
    int r16 = lane & 15, g = lane >> 4;

    const ushort_t* arow = xb + (size_t)(bm0 + r16) * 128 + g * 8;
    const ushort_t* bcol = W1p + (size_t)(bn0 + r16) * 128 + g * 8;

    f32x4 acc[2][2] = {};
#pragma unroll
    for (int k0 = 0; k0 < 128; k0 += 32) {
        bf16x8 a0 = *(const bf16x8*)(arow + k0);
        bf16x8 a1 = *(const bf16x8*)(arow + 16 * 128 + k0);
        bf16x8 b0 = *(const bf16x8*)(bcol + k0);
        bf16x8 b1 = *(const bf16x8*)(bcol + 16 * 128 + k0);
        acc[0][0] = __builtin_amdgcn_mfma_f32_16x16x32_bf16(a0, b0, acc[0][0], 0, 0, 0);
        acc[0][1] = __builtin_amdgcn_mfma_f32_16x16x32_bf16(a0, b1, acc[0][1], 0, 0, 0);
        acc[1][0] = __builtin_amdgcn_mfma_f32_16x16x32_bf16(a1, b0, acc[1][0], 0, 0, 0);
        acc[1][1] = __builtin_amdgcn_mfma_f32_16x16x32_bf16(a1, b1, acc[1][1], 0, 0, 0);
    }

    __shared__ float pa[2][64];
    float b1c[2] = {b1[bn0 + r16], b1[bn0 + 16 + r16]};
    float w2c[2] = {W2[bn0 + r16], W2[bn0 + 16 + r16]};
#pragma unroll
    for (int fm = 0; fm < 2; ++fm)
#pragma unroll
        for (int r = 0; r < 4; ++r) {
            float h10 = acc[fm][0][r] + b1c[0]; h10 = h10 > 0.f ? h10 : 0.f;
            float h11 = acc[fm][1][r] + b1c[1]; h11 = h11 > 0.f ? h11 : 0.f;
            float s = h10 * w2c[0] + h11 * w2c[1];
#pragma unroll
            for (int st = 1; st < 16; st <<= 1) s += __shfl_xor(s, st);
            if (r16 == 0) pa[wc][wr * 32 + fm * 16 + g * 4 + r] = s;
        }
    __syncthreads();
    if (t < 64) {
        int row = blockIdx.x * 64 + t;
        if (row < N_NODES) {
            float pre = pa[0][t] + pa[1][t] + b2[0];
            out[row] = 1.f / (1.f + __expf(-pre));
        }
    }
    // vuln: 16 rows per wave, 4 lanes per row (32 dims each), f32 x
    int vrow = blockIdx.x * 64 + w * 16 + (lane >> 2);
    int q = lane & 3;
    if (vrow < N_NODES) {
        const float* xr = x + (size_t)vrow * 128 + q * 32;
        float s = 0.f;
#pragma unroll
        for (int j = 0; j < 32; ++j) s = fmaf(xr[j], vW[q * 32 + j], s);
        s += __shfl_xor(s, 1);
        s += __shfl_xor(s, 2);
        if (q == 0)
            out[N_NODES + vrow] = 1.f / (1.f + __expf(-(s + vb[0])));
    }
}

// ---------------------------------------------------------------------------
extern "C" void kernel_launch(void* const* d_in, const int* in_sizes, int n_in,
                              void* d_out, int out_size, void* d_ws, size_t ws_size,
                              hipStream_t stream) {
    const float* nf    = (const float*)d_in[0];
    const int*   ei    = (const int*)d_in[1];
    const float* encW  = (const float*)d_in[2];
    const float* encb  = (const float*)d_in[3];
    const float* lin   = (const float*)d_in[4];
    const float* attS  = (const float*)d_in[5];
    const float* attD  = (const float*)d_in[6];
    const float* gbias = (const float*)d_in[7];
    const float* W1    = (const float*)d_in[8];
    const float* b1    = (const float*)d_in[9];
    const float* W2    = (const float*)d_in[10];
    const float* b2    = (const float*)d_in[11];
    const float* vW    = (const float*)d_in[12];
    const float* vb    = (const float*)d_in[13];
    float* out = (float*)d_out;

    char* ws = (char*)d_ws;
    size_t o = 0;
    auto alloc = [&](size_t bytes) {
        void* p = ws + o;
        o += (bytes + 255) & ~(size_t)255;
        return p;
    };
    float* x      = (float*)alloc((size_t)N_NODES * 128 * 4);
    ushort_t* xb  = (ushort_t*)alloc((size_t)N_PAD * 128 * 2);
    ushort_t* Ub  = (ushort_t*)alloc((size_t)N_PAD * 512 * 2);
    ushort_t* Bp  = (ushort_t*)alloc((size_t)3 * 128 * 512 * 2);
    ushort_t* W1p = (ushort_t*)alloc((size_t)64 * 128 * 2);
    float* wtS    = (float*)alloc((size_t)3 * 512 * 4);
    float* wtD    = (float*)alloc((size_t)3 * 512 * 4);
    float* aS     = (float*)alloc((size_t)N_NODES * 4 * 4);
    float* aD     = (float*)alloc((size_t)N_NODES * 4 * 4);
    int* deg      = (int*)alloc((size_t)N_NODES * 4);
    int* cursor   = (int*)alloc((size_t)N_NODES * 4);
    int* offs     = (int*)alloc((size_t)(N_NODES + 1) * 4);
    int* csr      = (int*)alloc((size_t)ET * 4);

    hipMemsetAsync(deg, 0, (size_t)N_NODES * 4, stream);
    hipMemsetAsync(cursor, 0, (size_t)N_NODES * 4, stream);
    hipMemsetAsync(xb + (size_t)N_NODES * 128, 0, (size_t)(N_PAD - N_NODES) * 128 * 2, stream);
    hipMemsetAsync(Ub + (size_t)N_NODES * 512, 0, (size_t)(N_PAD - N_NODES) * 512 * 2, stream);

    pack_bw<<<96, 256, 0, stream>>>(lin, Bp);
    pack_wt<<<6, 256, 0, stream>>>(lin, attS, attD, wtS, wtD);
    pack_w1<<<4, 256, 0, stream>>>(W1, W1p);
    enc_gemm<<<N_NODES / 8, 128, 0, stream>>>(nf, encW, encb, x, xb);
    hist_kernel<<<(ET + 255) / 256, 256, 0, stream>>>(ei, deg);
    scan_kernel<<<1, 1024, 0, stream>>>(deg, offs);
    scatter_kernel<<<(ET + 255) / 256, 256, 0, stream>>>(ei, offs, cursor, csr);

    dim3 ugrid(N_PAD / 64, 2);
    for (int l = 0; l < 3; ++l) {
        dots_kernel<<<N_NODES / 32, 256, 0, stream>>>(xb, wtS + (size_t)l * 512,
                                                      wtD + (size_t)l * 512, aS, aD);
        gat_agg<<<N_NODES / 4, 256, 0, stream>>>((const uint_t*)xb, aS, aD, offs, csr,
                                                 (uint_t*)Ub);
        ugemm<<<ugrid, 256, 0, stream>>>(Ub, Bp + (size_t)l * 128 * 512,
                                         gbias + (size_t)l * 128, x, xb);
    }
    pred_kernel<<<N_PAD / 64, 256, 0, stream>>>(x, xb, W1p, b1, W2, b2, vW, vb, out);
}

// Round 6
// 305.395 us; speedup vs baseline: 1.9901x; 1.0031x over previous
//
#include <hip/hip_runtime.h>

#define N_NODES 20000
#define N_PAD 20032            // padded to multiple of 64 for MFMA tiles
#define F_IN 64
#define HID 128
#define HEADS 4
#define E_EDGES 320000
#define ET (E_EDGES + N_NODES)   // + self loops
#define NEG_SLOPE 0.2f

typedef unsigned short ushort_t;
typedef unsigned int uint_t;

using bf16x8 = __attribute__((ext_vector_type(8))) short;
using f32x4  = __attribute__((ext_vector_type(4))) float;

__device__ __forceinline__ ushort_t f2bf(float f) {
    union { float f; uint_t u; } v; v.f = f;
    uint_t r = v.u + 0x7fffu + ((v.u >> 16) & 1u);   // round-to-nearest-even
    return (ushort_t)(r >> 16);
}
__device__ __forceinline__ float bflo(uint_t w) {
    union { uint_t u; float f; } v; v.u = w << 16; return v.f;
}
__device__ __forceinline__ float bfhi(uint_t w) {
    union { uint_t u; float f; } v; v.u = w & 0xffff0000u; return v.f;
}
__device__ __forceinline__ float rdlane_f(float v, int j) {
    return __uint_as_float(__builtin_amdgcn_readlane(__float_as_uint(v), j));
}

// ---------------------------------------------------------------------------
// Encoder: x = relu(nf @ encW + encb); writes f32 x and bf16 xb
__global__ __launch_bounds__(128) void enc_gemm(const float* __restrict__ nf,
                                                const float* __restrict__ W,
                                                const float* __restrict__ b,
                                                float* __restrict__ x,
                                                ushort_t* __restrict__ xb) {
    __shared__ float xs[8][64];
    int t = threadIdx.x;
    int n0 = blockIdx.x * 8;
    for (int i = t; i < 8 * 64; i += 128)
        xs[i >> 6][i & 63] = nf[(size_t)n0 * 64 + i];
    __syncthreads();
    float acc[8];
#pragma unroll
    for (int i = 0; i < 8; ++i) acc[i] = 0.f;
    for (int k = 0; k < 64; ++k) {
        float w = W[k * 128 + t];
#pragma unroll
        for (int i = 0; i < 8; ++i) acc[i] = fmaf(xs[i][k], w, acc[i]);
    }
    float bias = b[t];
#pragma unroll
    for (int i = 0; i < 8; ++i) {
        float v = acc[i] + bias;
        v = v > 0.f ? v : 0.f;
        x[(size_t)(n0 + i) * 128 + t] = v;
        xb[(size_t)(n0 + i) * 128 + t] = f2bf(v);
    }
}

// ---------------------------------------------------------------------------
// Pack W-bar: Bp[l][col][kk] = lin[l][ kk&127 ][ (kk>>7)*128 + col ], bf16.
// ALSO clears deg[] (side job; runs before hist_kernel on the same stream,
// replacing a 41us single-WG rocclr fill).
__global__ __launch_bounds__(256) void pack_bw(const float* __restrict__ lin,
                                               ushort_t* __restrict__ Bp,
                                               int* __restrict__ deg) {
    int idx = blockIdx.x * 256 + threadIdx.x;   // 3*128*64 = 24576
    if (idx < N_NODES) deg[idx] = 0;
    int l = idx / 8192;
    int rem = idx % 8192;
    int col = rem / 64, kg = rem % 64;
    const float* W = lin + (size_t)l * 128 * 512;
    int h = kg >> 4;
    int kbase = (kg & 15) * 8;
    ushort_t tmp[8];
#pragma unroll
    for (int j = 0; j < 8; ++j)
        tmp[j] = f2bf(W[(size_t)(kbase + j) * 512 + h * 128 + col]);
    *(uint4*)(Bp + ((size_t)(l * 128 + col)) * 512 + kg * 8) = *(const uint4*)tmp;
}

// w-tilde: wtS[l][h][k] = sum_d lin[l][k][h*128+d] * attS[l][h][d] (f32)
__global__ __launch_bounds__(256) void pack_wt(const float* __restrict__ lin,
                                               const float* __restrict__ attS,
                                               const float* __restrict__ attD,
                                               float* __restrict__ wtS,
                                               float* __restrict__ wtD) {
    int idx = blockIdx.x * 256 + threadIdx.x;   // 3*4*128 = 1536
    if (idx >= 1536) return;
    int l = idx / 512;
    int rem = idx % 512;
    int h = rem >> 7, k = rem & 127;
    const float* W = lin + (size_t)l * 128 * 512 + (size_t)k * 512 + h * 128;
    const float* as = attS + (size_t)l * 512 + h * 128;
    const float* ad = attD + (size_t)l * 512 + h * 128;
    float ss = 0.f, sd = 0.f;
    for (int d = 0; d < 128; ++d) {
        float w = W[d];
        ss = fmaf(w, as[d], ss);
        sd = fmaf(w, ad[d], sd);
    }
    wtS[idx] = ss;
    wtD[idx] = sd;
}

// W1 pack: W1p[col][k] = W1[k*64+col] bf16  (64 cols, 128 k)
__global__ __launch_bounds__(256) void pack_w1(const float* __restrict__ W1,
                                               ushort_t* __restrict__ W1p) {
    int idx = blockIdx.x * 256 + threadIdx.x;   // 64*16 = 1024
    if (idx >= 1024) return;
    int col = idx >> 4, kg = idx & 15;
    ushort_t tmp[8];
#pragma unroll
    for (int j = 0; j < 8; ++j)
        tmp[j] = f2bf(W1[(size_t)(kg * 8 + j) * 64 + col]);
    *(uint4*)(W1p + (size_t)col * 128 + kg * 8) = *(const uint4*)tmp;
}

// ---------------------------------------------------------------------------
// CSR build (by destination), once per call
__global__ void hist_kernel(const int* __restrict__ ei, int* __restrict__ deg) {
    int e = blockIdx.x * 256 + threadIdx.x;
    if (e >= ET) return;
    int d = (e < E_EDGES) ? ei[E_EDGES + e] : (e - E_EDGES);
    atomicAdd(&deg[d], 1);
}

// writes exclusive-scan offsets into BOTH off[] and cursor[] (cursor is the
// mutable copy consumed by scatter's atomicAdd -> no memset needed)
__global__ __launch_bounds__(1024) void scan_kernel(const int* __restrict__ deg,
                                                    int* __restrict__ off,
                                                    int* __restrict__ cursor) {
    __shared__ int sums[1024];
    int t = threadIdx.x;
    int base = t * 20;
    int tmp[20];
    int s = 0;
#pragma unroll
    for (int i = 0; i < 20; ++i) {
        int idx = base + i;
        int v = (idx < N_NODES) ? deg[idx] : 0;
        tmp[i] = s;
        s += v;
    }
    sums[t] = s;
    __syncthreads();
    for (int st = 1; st < 1024; st <<= 1) {
        int v = (t >= st) ? sums[t - st] : 0;
        __syncthreads();
        sums[t] += v;
        __syncthreads();
    }
    int bsum = (t == 0) ? 0 : sums[t - 1];
#pragma unroll
    for (int i = 0; i < 20; ++i) {
        int idx = base + i;
        if (idx < N_NODES) {
            int v = bsum + tmp[i];
            off[idx] = v;
            cursor[idx] = v;
        }
    }
    if (t == 1023) off[N_NODES] = sums[1023];
}

__global__ void scatter_kernel(const int* __restrict__ ei,
                               int* __restrict__ cursor, int* __restrict__ csr) {
    int e = blockIdx.x * 256 + threadIdx.x;
    if (e >= ET) return;
    int s, d;
    if (e < E_EDGES) { s = ei[e]; d = ei[E_EDGES + e]; }
    else             { s = d = e - E_EDGES; }
    int pos = atomicAdd(&cursor[d], 1);
    csr[pos] = s;
}

// ---------------------------------------------------------------------------
// dots: aS[n][h] = xb[n] . wtS[l][h], aD similarly. 32 nodes/block,
// 8 threads per node (16 dims each), w-tilde staged in LDS.
__global__ __launch_bounds__(256) void dots_kernel(const ushort_t* __restrict__ xb,
                                                   const float* __restrict__ wtS,
                                                   const float* __restrict__ wtD,
                                                   float* __restrict__ aS,
                                                   float* __restrict__ aD) {
    __shared__ float ls[4][128], ld_[4][128];
    int t = threadIdx.x;
    for (int i = t; i < 512; i += 256) {
        ls[i >> 7][i & 127] = wtS[i];
        ld_[i >> 7][i & 127] = wtD[i];
    }
    __syncthreads();
    int n = blockIdx.x * 32 + (t >> 3);
    int p = t & 7;
    const uint_t* xr = (const uint_t*)xb + (size_t)n * 64 + p * 8;
    float pS[4] = {0.f, 0.f, 0.f, 0.f}, pD[4] = {0.f, 0.f, 0.f, 0.f};
#pragma unroll
    for (int j = 0; j < 8; ++j) {
        uint_t u = xr[j];
        float f0 = bflo(u), f1 = bfhi(u);
        int d = p * 16 + j * 2;
#pragma unroll
        for (int h = 0; h < 4; ++h) {
            pS[h] = fmaf(f0, ls[h][d], fmaf(f1, ls[h][d + 1], pS[h]));
            pD[h] = fmaf(f0, ld_[h][d], fmaf(f1, ld_[h][d + 1], pD[h]));
        }
    }
#pragma unroll
    for (int st = 1; st < 8; st <<= 1) {
#pragma unroll
        for (int h = 0; h < 4; ++h) {
            pS[h] += __shfl_xor(pS[h], st);
            pD[h] += __shfl_xor(pD[h], st);
        }
    }
    if (p == 0) {
        *(float4*)(aS + (size_t)n * 4) = make_float4(pS[0], pS[1], pS[2], pS[3]);
        *(float4*)(aD + (size_t)n * 4) = make_float4(pD[0], pD[1], pD[2], pD[3]);
    }
}

// ---------------------------------------------------------------------------
// Aggregation in x-space: ONE WAVE per dst node. Lane l owns dims (2l,2l+1).
// Gathers x[src] (256B/edge), accumulates 4 head-weighted sums, normalizes,
// writes Ubar[n][h*128 + 2l .. +1] bf16.
__global__ __launch_bounds__(256) void gat_agg(const uint_t* __restrict__ xb2,
                                               const float* __restrict__ aS,
                                               const float* __restrict__ aD,
                                               const int* __restrict__ off,
                                               const int* __restrict__ csr,
                                               uint_t* __restrict__ Ub2) {
    int t = threadIdx.x;
    int w = t >> 6, l = t & 63;
    int n = blockIdx.x * 4 + w;
    int beg = off[n];
    int deg = off[n + 1] - beg;

    float4 adv = *(const float4*)(aD + (size_t)n * 4);

    // phase 1: per-head max of aS over neighbors (leaky_relu monotone)
    float4 smax = make_float4(-1e30f, -1e30f, -1e30f, -1e30f);
    for (int i = l; i < deg; i += 64) {
        int s = csr[beg + i];
        float4 a = *(const float4*)(aS + (size_t)s * 4);
        smax.x = fmaxf(smax.x, a.x);
        smax.y = fmaxf(smax.y, a.y);
        smax.z = fmaxf(smax.z, a.z);
        smax.w = fmaxf(smax.w, a.w);
    }
#pragma unroll
    for (int st = 1; st < 64; st <<= 1) {
        smax.x = fmaxf(smax.x, __shfl_xor(smax.x, st));
        smax.y = fmaxf(smax.y, __shfl_xor(smax.y, st));
        smax.z = fmaxf(smax.z, __shfl_xor(smax.z, st));
        smax.w = fmaxf(smax.w, __shfl_xor(smax.w, st));
    }
    float e;
    e = smax.x + adv.x; float m0 = e > 0.f ? e : NEG_SLOPE * e;
    e = smax.y + adv.y; float m1 = e > 0.f ? e : NEG_SLOPE * e;
    e = smax.z + adv.z; float m2 = e > 0.f ? e : NEG_SLOPE * e;
    e = smax.w + adv.w; float m3 = e > 0.f ? e : NEG_SLOPE * e;

    // phase 2: chunked gather of x[src] with per-head weights
    float acc[8];
#pragma unroll
    for (int i = 0; i < 8; ++i) acc[i] = 0.f;
    float4 zac = make_float4(0.f, 0.f, 0.f, 0.f);
    for (int c0 = 0; c0 < deg; c0 += 64) {
        int ce = min(64, deg - c0);
        int sl = 0;
        float4 wv = make_float4(0.f, 0.f, 0.f, 0.f);
        if (l < ce) {
            sl = csr[beg + c0 + l];
            float4 a = *(const float4*)(aS + (size_t)sl * 4);
            e = a.x + adv.x; e = e > 0.f ? e : NEG_SLOPE * e; wv.x = __expf(e - m0);
            e = a.y + adv.y; e = e > 0.f ? e : NEG_SLOPE * e; wv.y = __expf(e - m1);
            e = a.z + adv.z; e = e > 0.f ? e : NEG_SLOPE * e; wv.z = __expf(e - m2);
            e = a.w + adv.w; e = e > 0.f ? e : NEG_SLOPE * e; wv.w = __expf(e - m3);
            zac.x += wv.x; zac.y += wv.y; zac.z += wv.z; zac.w += wv.w;
        }
#pragma unroll 2
        for (int j = 0; j < ce; ++j) {
            int s = __builtin_amdgcn_readlane(sl, j);
            float w0 = rdlane_f(wv.x, j);
            float w1 = rdlane_f(wv.y, j);
            float w2 = rdlane_f(wv.z, j);
            float w3 = rdlane_f(wv.w, j);
            uint_t xv = xb2[(size_t)s * 64 + l];
            float f0 = bflo(xv), f1 = bfhi(xv);
            acc[0] = fmaf(w0, f0, acc[0]); acc[1] = fmaf(w0, f1, acc[1]);
            acc[2] = fmaf(w1, f0, acc[2]); acc[3] = fmaf(w1, f1, acc[3]);
            acc[4] = fmaf(w2, f0, acc[4]); acc[5] = fmaf(w2, f1, acc[5]);
            acc[6] = fmaf(w3, f0, acc[6]); acc[7] = fmaf(w3, f1, acc[7]);
        }
    }

    // z: wave-sum of per-lane weight sums
#pragma unroll
    for (int st = 1; st < 64; st <<= 1) {
        zac.x += __shfl_xor(zac.x, st);
        zac.y += __shfl_xor(zac.y, st);
        zac.z += __shfl_xor(zac.z, st);
        zac.w += __shfl_xor(zac.w, st);
    }
    float iz0 = 1.f / zac.x, iz1 = 1.f / zac.y, iz2 = 1.f / zac.z, iz3 = 1.f / zac.w;
    uint_t o0 = (uint_t)f2bf(acc[0] * iz0) | ((uint_t)f2bf(acc[1] * iz0) << 16);
    uint_t o1 = (uint_t)f2bf(acc[2] * iz1) | ((uint_t)f2bf(acc[3] * iz1) << 16);
    uint_t o2 = (uint_t)f2bf(acc[4] * iz2) | ((uint_t)f2bf(acc[5] * iz2) << 16);
    uint_t o3 = (uint_t)f2bf(acc[6] * iz3) | ((uint_t)f2bf(acc[7] * iz3) << 16);
    size_t base = (size_t)n * 256;
    Ub2[base + l]       = o0;
    Ub2[base + 64 + l]  = o1;
    Ub2[base + 128 + l] = o2;
    Ub2[base + 192 + l] = o3;
}

// ---------------------------------------------------------------------------
// ugemm: x += relu(0.25 * Ubar @ Wbar + bias); update x (f32) and xb (bf16).
// [20032,512]@[512,128]; grid (313,2); 4 waves (2x2), wave = 32x32 tile.
// Pad rows of Ub are garbage but only affect pad-row outputs (masked).
__global__ __launch_bounds__(256) void ugemm(const ushort_t* __restrict__ Ub,
                                             const ushort_t* __restrict__ Bp,
                                             const float* __restrict__ bias,
                                             float* __restrict__ x,
                                             ushort_t* __restrict__ xb) {
    int t = threadIdx.x;
    int lane = t & 63, w = t >> 6;
    int wr = w >> 1, wc = w & 1;
    int bm0 = blockIdx.x * 64 + wr * 32;
    int bn0 = blockIdx.y * 64 + wc * 32;
    int r16 = lane & 15, g = lane >> 4;

    const ushort_t* arow = Ub + (size_t)(bm0 + r16) * 512 + g * 8;
    const ushort_t* bcol = Bp + (size_t)(bn0 + r16) * 512 + g * 8;

    f32x4 acc[2][2] = {};
#pragma unroll 4
    for (int k0 = 0; k0 < 512; k0 += 32) {
        bf16x8 a0 = *(const bf16x8*)(arow + k0);
        bf16x8 a1 = *(const bf16x8*)(arow + 16 * 512 + k0);
        bf16x8 b0 = *(const bf16x8*)(bcol + k0);
        bf16x8 b1 = *(const bf16x8*)(bcol + 16 * 512 + k0);
        acc[0][0] = __builtin_amdgcn_mfma_f32_16x16x32_bf16(a0, b0, acc[0][0], 0, 0, 0);
        acc[0][1] = __builtin_amdgcn_mfma_f32_16x16x32_bf16(a0, b1, acc[0][1], 0, 0, 0);
        acc[1][0] = __builtin_amdgcn_mfma_f32_16x16x32_bf16(a1, b0, acc[1][0], 0, 0, 0);
        acc[1][1] = __builtin_amdgcn_mfma_f32_16x16x32_bf16(a1, b1, acc[1][1], 0, 0, 0);
    }

    float bia[2] = {bias[bn0 + r16], bias[bn0 + 16 + r16]};
#pragma unroll
    for (int fm = 0; fm < 2; ++fm)
#pragma unroll
        for (int fn = 0; fn < 2; ++fn) {
            int col = bn0 + fn * 16 + r16;
#pragma unroll
            for (int r = 0; r < 4; ++r) {
                int row = bm0 + fm * 16 + g * 4 + r;
                if (row < N_NODES) {
                    float v = 0.25f * acc[fm][fn][r] + bia[fn];
                    v = v > 0.f ? v : 0.f;
                    float nx = x[(size_t)row * 128 + col] + v;
                    x[(size_t)row * 128 + col] = nx;
                    xb[(size_t)row * 128 + col] = f2bf(nx);
                }
            }
        }
}

// ---------------------------------------------------------------------------
// Prediction: MFMA for h1 = relu(xb@W1p + b1); attack = sigmoid(h1.W2 + b2);
// vuln = sigmoid(x.vW + vb). Block = 64 rows, 4 waves (2x2), cols 64.
__global__ __launch_bounds__(256) void pred_kernel(const float* __restrict__ x,
                                                   const ushort_t* __restrict__ xb,
                                                   const ushort_t* __restrict__ W1p,
                                                   const float* __restrict__ b1,
                                                   const float* __restrict__ W2,
                                                   const float* __restrict__ b2,
                                                   const float* __restrict__ vW,
                                                   const float* __restrict__ vb,
                                                   float* __restrict__ out) {
    int t = threadIdx.x;
    int lane = t & 63, w = t >> 6;
    int wr = w >> 1, wc = w & 1;
    int bm0 = blockIdx.x * 64 + wr * 32;
    int bn0 = wc * 32;
    int r16 = lane & 15, g = lane >> 4;

    const ushort_t* arow = xb + (size_t)(bm0 + r16) * 128 + g * 8;
    const ushort_t* bcol = W1p + (size_t)(bn0 + r16) * 128 + g * 8;

    f32x4 acc[2][2] = {};
#pragma unroll
    for (int k0 = 0; k0 < 128; k0 += 32) {
        bf16x8 a0 = *(const bf16x8*)(arow + k0);
        bf16x8 a1 = *(const bf16x8*)(arow + 16 * 128 + k0);
        bf16x8 b0 = *(const bf16x8*)(bcol + k0);
        bf16x8 b1 = *(const bf16x8*)(bcol + 16 * 128 + k0);
        acc[0][0] = __builtin_amdgcn_mfma_f32_16x16x32_bf16(a0, b0, acc[0][0], 0, 0, 0);
        acc[0][1] = __builtin_amdgcn_mfma_f32_16x16x32_bf16(a0, b1, acc[0][1], 0, 0, 0);
        acc[1][0] = __builtin_amdgcn_mfma_f32_16x16x32_bf16(a1, b0, acc[1][0], 0, 0, 0);
        acc[1][1] = __builtin_amdgcn_mfma_f32_16x16x32_bf16(a1, b1, acc[1][1], 0, 0, 0);
    }

    __shared__ float pa[2][64];
    float b1c[2] = {b1[bn0 + r16], b1[bn0 + 16 + r16]};
    float w2c[2] = {W2[bn0 + r16], W2[bn0 + 16 + r16]};
#pragma unroll
    for (int fm = 0; fm < 2; ++fm)
#pragma unroll
        for (int r = 0; r < 4; ++r) {
            float h10 = acc[fm][0][r] + b1c[0]; h10 = h10 > 0.f ? h10 : 0.f;
            float h11 = acc[fm][1][r] + b1c[1]; h11 = h11 > 0.f ? h11 : 0.f;
            float s = h10 * w2c[0] + h11 * w2c[1];
#pragma unroll
            for (int st = 1; st < 16; st <<= 1) s += __shfl_xor(s, st);
            if (r16 == 0) pa[wc][wr * 32 + fm * 16 + g * 4 + r] = s;
        }
    __syncthreads();
    if (t < 64) {
        int row = blockIdx.x * 64 + t;
        if (row < N_NODES) {
            float pre = pa[0][t] + pa[1][t] + b2[0];
            out[row] = 1.f / (1.f + __expf(-pre));
        }
    }
    // vuln: 16 rows per wave, 4 lanes per row (32 dims each), f32 x
    int vrow = blockIdx.x * 64 + w * 16 + (lane >> 2);
    int q = lane & 3;
    if (vrow < N_NODES) {
        const float* xr = x + (size_t)vrow * 128 + q * 32;
        float s = 0.f;
#pragma unroll
        for (int j = 0; j < 32; ++j) s = fmaf(xr[j], vW[q * 32 + j], s);
        s += __shfl_xor(s, 1);
        s += __shfl_xor(s, 2);
        if (q == 0)
            out[N_NODES + vrow] = 1.f / (1.f + __expf(-(s + vb[0])));
    }
}

// ---------------------------------------------------------------------------
extern "C" void kernel_launch(void* const* d_in, const int* in_sizes, int n_in,
                              void* d_out, int out_size, void* d_ws, size_t ws_size,
                              hipStream_t stream) {
    const float* nf    = (const float*)d_in[0];
    const int*   ei    = (const int*)d_in[1];
    const float* encW  = (const float*)d_in[2];
    const float* encb  = (const float*)d_in[3];
    const float* lin   = (const float*)d_in[4];
    const float* attS  = (const float*)d_in[5];
    const float* attD  = (const float*)d_in[6];
    const float* gbias = (const float*)d_in[7];
    const float* W1    = (const float*)d_in[8];
    const float* b1    = (const float*)d_in[9];
    const float* W2    = (const float*)d_in[10];
    const float* b2    = (const float*)d_in[11];
    const float* vW    = (const float*)d_in[12];
    const float* vb    = (const float*)d_in[13];
    float* out = (float*)d_out;

    char* ws = (char*)d_ws;
    size_t o = 0;
    auto alloc = [&](size_t bytes) {
        void* p = ws + o;
        o += (bytes + 255) & ~(size_t)255;
        return p;
    };
    float* x      = (float*)alloc((size_t)N_NODES * 128 * 4);
    ushort_t* xb  = (ushort_t*)alloc((size_t)N_PAD * 128 * 2);
    ushort_t* Ub  = (ushort_t*)alloc((size_t)N_PAD * 512 * 2);
    ushort_t* Bp  = (ushort_t*)alloc((size_t)3 * 128 * 512 * 2);
    ushort_t* W1p = (ushort_t*)alloc((size_t)64 * 128 * 2);
    float* wtS    = (float*)alloc((size_t)3 * 512 * 4);
    float* wtD    = (float*)alloc((size_t)3 * 512 * 4);
    float* aS     = (float*)alloc((size_t)N_NODES * 4 * 4);
    float* aD     = (float*)alloc((size_t)N_NODES * 4 * 4);
    int* deg      = (int*)alloc((size_t)N_NODES * 4);
    int* cursor   = (int*)alloc((size_t)N_NODES * 4);
    int* offs     = (int*)alloc((size_t)(N_NODES + 1) * 4);
    int* csr      = (int*)alloc((size_t)ET * 4);

    // NO hipMemsetAsync anywhere: deg is cleared by pack_bw (stream-ordered
    // before hist), cursor is initialized by scan_kernel, and the xb/Ub pad
    // rows never need zeroing (MFMA row i of C depends only on row i of A;
    // all pad-row outputs are masked by row<N_NODES at the stores).
    pack_bw<<<96, 256, 0, stream>>>(lin, Bp, deg);
    pack_wt<<<6, 256, 0, stream>>>(lin, attS, attD, wtS, wtD);
    pack_w1<<<4, 256, 0, stream>>>(W1, W1p);
    enc_gemm<<<N_NODES / 8, 128, 0, stream>>>(nf, encW, encb, x, xb);
    hist_kernel<<<(ET + 255) / 256, 256, 0, stream>>>(ei, deg);
    scan_kernel<<<1, 1024, 0, stream>>>(deg, offs, cursor);
    scatter_kernel<<<(ET + 255) / 256, 256, 0, stream>>>(ei, cursor, csr);

    dim3 ugrid(N_PAD / 64, 2);
    for (int l = 0; l < 3; ++l) {
        dots_kernel<<<N_NODES / 32, 256, 0, stream>>>(xb, wtS + (size_t)l * 512,
                                                      wtD + (size_t)l * 512, aS, aD);
        gat_agg<<<N_NODES / 4, 256, 0, stream>>>((const uint_t*)xb, aS, aD, offs, csr,
                                                 (uint_t*)Ub);
        ugemm<<<ugrid, 256, 0, stream>>>(Ub, Bp + (size_t)l * 128 * 512,
                                         gbias + (size_t)l * 128, x, xb);
    }
    pred_kernel<<<N_PAD / 64, 256, 0, stream>>>(x, xb, W1p, b1, W2, b2, vW, vb, out);
}

// Round 7
// 296.498 us; speedup vs baseline: 2.0499x; 1.0300x over previous
//
#include <hip/hip_runtime.h>

#define N_NODES 20000
#define N_PAD 20032            // padded to multiple of 64 for MFMA tiles
#define F_IN 64
#define HID 128
#define HEADS 4
#define E_EDGES 320000
#define ET (E_EDGES + N_NODES)   // + self loops
#define NEG_SLOPE 0.2f

typedef unsigned short ushort_t;
typedef unsigned int uint_t;

using bf16x8 = __attribute__((ext_vector_type(8))) short;
using f32x4  = __attribute__((ext_vector_type(4))) float;

__device__ __forceinline__ ushort_t f2bf(float f) {
    union { float f; uint_t u; } v; v.f = f;
    uint_t r = v.u + 0x7fffu + ((v.u >> 16) & 1u);   // round-to-nearest-even
    return (ushort_t)(r >> 16);
}
__device__ __forceinline__ float bflo(uint_t w) {
    union { uint_t u; float f; } v; v.u = w << 16; return v.f;
}
__device__ __forceinline__ float bfhi(uint_t w) {
    union { uint_t u; float f; } v; v.u = w & 0xffff0000u; return v.f;
}
__device__ __forceinline__ float rdlane_f(float v, int j) {
    return __uint_as_float(__builtin_amdgcn_readlane(__float_as_uint(v), j));
}

// ---------------------------------------------------------------------------
// ONE pack kernel: Bp (W-bar bf16), wtS/wtD (f32), W1p (bf16), deg clear.
// grid 96 x 256 = 24576 threads.
__global__ __launch_bounds__(256) void pack_all(const float* __restrict__ lin,
                                                const float* __restrict__ attS,
                                                const float* __restrict__ attD,
                                                const float* __restrict__ W1,
                                                ushort_t* __restrict__ Bp,
                                                float* __restrict__ wtS,
                                                float* __restrict__ wtD,
                                                ushort_t* __restrict__ W1p,
                                                int* __restrict__ deg) {
    int idx = blockIdx.x * 256 + threadIdx.x;
    if (idx < N_NODES) deg[idx] = 0;

    // job A: Bp[l][col][kk] = lin[l][kk&127][(kk>>7)*128 + col], all 24576
    {
        int l = idx / 8192;
        int rem = idx % 8192;
        int col = rem / 64, kg = rem % 64;
        const float* W = lin + (size_t)l * 128 * 512;
        int h = kg >> 4;
        int kbase = (kg & 15) * 8;
        ushort_t tmp[8];
#pragma unroll
        for (int j = 0; j < 8; ++j)
            tmp[j] = f2bf(W[(size_t)(kbase + j) * 512 + h * 128 + col]);
        *(uint4*)(Bp + ((size_t)(l * 128 + col)) * 512 + kg * 8) = *(const uint4*)tmp;
    }

    // job B: w-tilde (1536 items)
    if (idx < 1536) {
        int l = idx / 512;
        int rem = idx % 512;
        int h = rem >> 7, k = rem & 127;
        const float* W = lin + (size_t)l * 128 * 512 + (size_t)k * 512 + h * 128;
        const float* as = attS + (size_t)l * 512 + h * 128;
        const float* ad = attD + (size_t)l * 512 + h * 128;
        float ss = 0.f, sd = 0.f;
        for (int d = 0; d < 128; ++d) {
            float w = W[d];
            ss = fmaf(w, as[d], ss);
            sd = fmaf(w, ad[d], sd);
        }
        wtS[idx] = ss;
        wtD[idx] = sd;
    }

    // job C: W1p (1024 items)
    if (idx < 1024) {
        int col = idx >> 4, kg = idx & 15;
        ushort_t tmp[8];
#pragma unroll
        for (int j = 0; j < 8; ++j)
            tmp[j] = f2bf(W1[(size_t)(kg * 8 + j) * 64 + col]);
        *(uint4*)(W1p + (size_t)col * 128 + kg * 8) = *(const uint4*)tmp;
    }
}

// ---------------------------------------------------------------------------
// Fused encoder + degree histogram. Blocks 0..1249: enc (16 nodes each);
// blocks 1250+: hist atomics (deg cleared by pack_all earlier in stream).
#define ENC_BLOCKS 1250
__global__ __launch_bounds__(256) void enc_hist(const float* __restrict__ nf,
                                                const float* __restrict__ W,
                                                const float* __restrict__ b,
                                                const int* __restrict__ ei,
                                                float* __restrict__ x,
                                                ushort_t* __restrict__ xb,
                                                int* __restrict__ deg) {
    int t = threadIdx.x;
    if (blockIdx.x < ENC_BLOCKS) {
        __shared__ float xs[16][64];
        int n0 = blockIdx.x * 16;
        ((float4*)&xs[0][0])[t] = ((const float4*)(nf + (size_t)n0 * 64))[t];
        __syncthreads();
        int c = t & 127, ng = t >> 7;
        float acc[8];
#pragma unroll
        for (int i = 0; i < 8; ++i) acc[i] = 0.f;
        for (int k = 0; k < 64; ++k) {
            float wv = W[k * 128 + c];
#pragma unroll
            for (int i = 0; i < 8; ++i) acc[i] = fmaf(xs[ng * 8 + i][k], wv, acc[i]);
        }
        float bias = b[c];
#pragma unroll
        for (int i = 0; i < 8; ++i) {
            float v = acc[i] + bias;
            v = v > 0.f ? v : 0.f;
            int row = n0 + ng * 8 + i;
            x[(size_t)row * 128 + c] = v;
            xb[(size_t)row * 128 + c] = f2bf(v);
        }
    } else {
        int e = (blockIdx.x - ENC_BLOCKS) * 256 + t;
        if (e < ET) {
            int d = (e < E_EDGES) ? ei[E_EDGES + e] : (e - E_EDGES);
            atomicAdd(&deg[d], 1);
        }
    }
}

// ---------------------------------------------------------------------------
// scan: exclusive offsets into off[] AND cursor[] (no memset needed)
__global__ __launch_bounds__(1024) void scan_kernel(const int* __restrict__ deg,
                                                    int* __restrict__ off,
                                                    int* __restrict__ cursor) {
    __shared__ int sums[1024];
    int t = threadIdx.x;
    int base = t * 20;
    int tmp[20];
    int s = 0;
#pragma unroll
    for (int i = 0; i < 20; ++i) {
        int idx = base + i;
        int v = (idx < N_NODES) ? deg[idx] : 0;
        tmp[i] = s;
        s += v;
    }
    sums[t] = s;
    __syncthreads();
    for (int st = 1; st < 1024; st <<= 1) {
        int v = (t >= st) ? sums[t - st] : 0;
        __syncthreads();
        sums[t] += v;
        __syncthreads();
    }
    int bsum = (t == 0) ? 0 : sums[t - 1];
#pragma unroll
    for (int i = 0; i < 20; ++i) {
        int idx = base + i;
        if (idx < N_NODES) {
            int v = bsum + tmp[i];
            off[idx] = v;
            cursor[idx] = v;
        }
    }
    if (t == 1023) off[N_NODES] = sums[1023];
}

__global__ void scatter_kernel(const int* __restrict__ ei,
                               int* __restrict__ cursor, int* __restrict__ csr) {
    int e = blockIdx.x * 256 + threadIdx.x;
    if (e >= ET) return;
    int s, d;
    if (e < E_EDGES) { s = ei[e]; d = ei[E_EDGES + e]; }
    else             { s = d = e - E_EDGES; }
    int pos = atomicAdd(&cursor[d], 1);
    csr[pos] = s;
}

// ---------------------------------------------------------------------------
// dots for layer 0 (from bf16 xb). 32 nodes/block, 8 threads per node.
__global__ __launch_bounds__(256) void dots_kernel(const ushort_t* __restrict__ xb,
                                                   const float* __restrict__ wtS,
                                                   const float* __restrict__ wtD,
                                                   float* __restrict__ aS,
                                                   float* __restrict__ aD) {
    __shared__ float ls[4][128], ld_[4][128];
    int t = threadIdx.x;
    for (int i = t; i < 512; i += 256) {
        ls[i >> 7][i & 127] = wtS[i];
        ld_[i >> 7][i & 127] = wtD[i];
    }
    __syncthreads();
    int n = blockIdx.x * 32 + (t >> 3);
    int p = t & 7;
    const uint_t* xr = (const uint_t*)xb + (size_t)n * 64 + p * 8;
    float pS[4] = {0.f, 0.f, 0.f, 0.f}, pD[4] = {0.f, 0.f, 0.f, 0.f};
#pragma unroll
    for (int j = 0; j < 8; ++j) {
        uint_t u = xr[j];
        float f0 = bflo(u), f1 = bfhi(u);
        int d = p * 16 + j * 2;
#pragma unroll
        for (int h = 0; h < 4; ++h) {
            pS[h] = fmaf(f0, ls[h][d], fmaf(f1, ls[h][d + 1], pS[h]));
            pD[h] = fmaf(f0, ld_[h][d], fmaf(f1, ld_[h][d + 1], pD[h]));
        }
    }
#pragma unroll
    for (int st = 1; st < 8; st <<= 1) {
#pragma unroll
        for (int h = 0; h < 4; ++h) {
            pS[h] += __shfl_xor(pS[h], st);
            pD[h] += __shfl_xor(pD[h], st);
        }
    }
    if (p == 0) {
        *(float4*)(aS + (size_t)n * 4) = make_float4(pS[0], pS[1], pS[2], pS[3]);
        *(float4*)(aD + (size_t)n * 4) = make_float4(pD[0], pD[1], pD[2], pD[3]);
    }
}

// ---------------------------------------------------------------------------
// Aggregation: ONE WAVE per dst node, single pass over edges (chunk-0 csr/aS
// cached in registers during the max pass; deg<=64 covers ~all nodes).
__global__ __launch_bounds__(256) void gat_agg(const uint_t* __restrict__ xb2,
                                               const float* __restrict__ aS,
                                               const float* __restrict__ aD,
                                               const int* __restrict__ off,
                                               const int* __restrict__ csr,
                                               uint_t* __restrict__ Ub2) {
    int t = threadIdx.x;
    int w = t >> 6, l = t & 63;
    int n = blockIdx.x * 4 + w;
    int beg = off[n];
    int deg = off[n + 1] - beg;

    float4 adv = *(const float4*)(aD + (size_t)n * 4);

    // chunk-0 load (cached in regs) + max pass over remaining chunks
    int sl = 0;
    float4 av = make_float4(-1e30f, -1e30f, -1e30f, -1e30f);
    if (l < deg) {
        sl = csr[beg + l];
        av = *(const float4*)(aS + (size_t)sl * 4);
    }
    float4 smax = av;
    for (int i = l + 64; i < deg; i += 64) {
        int s = csr[beg + i];
        float4 a = *(const float4*)(aS + (size_t)s * 4);
        smax.x = fmaxf(smax.x, a.x);
        smax.y = fmaxf(smax.y, a.y);
        smax.z = fmaxf(smax.z, a.z);
        smax.w = fmaxf(smax.w, a.w);
    }
#pragma unroll
    for (int st = 1; st < 64; st <<= 1) {
        smax.x = fmaxf(smax.x, __shfl_xor(smax.x, st));
        smax.y = fmaxf(smax.y, __shfl_xor(smax.y, st));
        smax.z = fmaxf(smax.z, __shfl_xor(smax.z, st));
        smax.w = fmaxf(smax.w, __shfl_xor(smax.w, st));
    }
    float e;
    e = smax.x + adv.x; float m0 = e > 0.f ? e : NEG_SLOPE * e;
    e = smax.y + adv.y; float m1 = e > 0.f ? e : NEG_SLOPE * e;
    e = smax.z + adv.z; float m2 = e > 0.f ? e : NEG_SLOPE * e;
    e = smax.w + adv.w; float m3 = e > 0.f ? e : NEG_SLOPE * e;

    float acc[8];
#pragma unroll
    for (int i = 0; i < 8; ++i) acc[i] = 0.f;
    float4 zac = make_float4(0.f, 0.f, 0.f, 0.f);

    // chunk 0: weights from registers (no csr/aS re-read)
    int ce = min(64, deg);
    float4 wv = make_float4(0.f, 0.f, 0.f, 0.f);
    if (l < ce) {
        e = av.x + adv.x; e = e > 0.f ? e : NEG_SLOPE * e; wv.x = __expf(e - m0);
        e = av.y + adv.y; e = e > 0.f ? e : NEG_SLOPE * e; wv.y = __expf(e - m1);
        e = av.z + adv.z; e = e > 0.f ? e : NEG_SLOPE * e; wv.z = __expf(e - m2);
        e = av.w + adv.w; e = e > 0.f ? e : NEG_SLOPE * e; wv.w = __expf(e - m3);
        zac.x += wv.x; zac.y += wv.y; zac.z += wv.z; zac.w += wv.w;
    }
#pragma unroll 2
    for (int j = 0; j < ce; ++j) {
        int s = __builtin_amdgcn_readlane(sl, j);
        float w0 = rdlane_f(wv.x, j);
        float w1 = rdlane_f(wv.y, j);
        float w2 = rdlane_f(wv.z, j);
        float w3 = rdlane_f(wv.w, j);
        uint_t xv = xb2[(size_t)s * 64 + l];
        float f0 = bflo(xv), f1 = bfhi(xv);
        acc[0] = fmaf(w0, f0, acc[0]); acc[1] = fmaf(w0, f1, acc[1]);
        acc[2] = fmaf(w1, f0, acc[2]); acc[3] = fmaf(w1, f1, acc[3]);
        acc[4] = fmaf(w2, f0, acc[4]); acc[5] = fmaf(w2, f1, acc[5]);
        acc[6] = fmaf(w3, f0, acc[6]); acc[7] = fmaf(w3, f1, acc[7]);
    }

    // rare: remaining chunks (deg > 64)
    for (int c0 = 64; c0 < deg; c0 += 64) {
        ce = min(64, deg - c0);
        wv = make_float4(0.f, 0.f, 0.f, 0.f);
        if (l < ce) {
            sl = csr[beg + c0 + l];
            float4 a = *(const float4*)(aS + (size_t)sl * 4);
            e = a.x + adv.x; e = e > 0.f ? e : NEG_SLOPE * e; wv.x = __expf(e - m0);
            e = a.y + adv.y; e = e > 0.f ? e : NEG_SLOPE * e; wv.y = __expf(e - m1);
            e = a.z + adv.z; e = e > 0.f ? e : NEG_SLOPE * e; wv.z = __expf(e - m2);
            e = a.w + adv.w; e = e > 0.f ? e : NEG_SLOPE * e; wv.w = __expf(e - m3);
            zac.x += wv.x; zac.y += wv.y; zac.z += wv.z; zac.w += wv.w;
        }
#pragma unroll 2
        for (int j = 0; j < ce; ++j) {
            int s = __builtin_amdgcn_readlane(sl, j);
            float w0 = rdlane_f(wv.x, j);
            float w1 = rdlane_f(wv.y, j);
            float w2 = rdlane_f(wv.z, j);
            float w3 = rdlane_f(wv.w, j);
            uint_t xv = xb2[(size_t)s * 64 + l];
            float f0 = bflo(xv), f1 = bfhi(xv);
            acc[0] = fmaf(w0, f0, acc[0]); acc[1] = fmaf(w0, f1, acc[1]);
            acc[2] = fmaf(w1, f0, acc[2]); acc[3] = fmaf(w1, f1, acc[3]);
            acc[4] = fmaf(w2, f0, acc[4]); acc[5] = fmaf(w2, f1, acc[5]);
            acc[6] = fmaf(w3, f0, acc[6]); acc[7] = fmaf(w3, f1, acc[7]);
        }
    }

#pragma unroll
    for (int st = 1; st < 64; st <<= 1) {
        zac.x += __shfl_xor(zac.x, st);
        zac.y += __shfl_xor(zac.y, st);
        zac.z += __shfl_xor(zac.z, st);
        zac.w += __shfl_xor(zac.w, st);
    }
    float iz0 = 1.f / zac.x, iz1 = 1.f / zac.y, iz2 = 1.f / zac.z, iz3 = 1.f / zac.w;
    uint_t o0 = (uint_t)f2bf(acc[0] * iz0) | ((uint_t)f2bf(acc[1] * iz0) << 16);
    uint_t o1 = (uint_t)f2bf(acc[2] * iz1) | ((uint_t)f2bf(acc[3] * iz1) << 16);
    uint_t o2 = (uint_t)f2bf(acc[4] * iz2) | ((uint_t)f2bf(acc[5] * iz2) << 16);
    uint_t o3 = (uint_t)f2bf(acc[6] * iz3) | ((uint_t)f2bf(acc[7] * iz3) << 16);
    size_t base = (size_t)n * 256;
    Ub2[base + l]       = o0;
    Ub2[base + 64 + l]  = o1;
    Ub2[base + 128 + l] = o2;
    Ub2[base + 192 + l] = o3;
}

// ---------------------------------------------------------------------------
// ugemm: x += relu(0.25*Ubar@Wbar + bias); updates x/xb AND (fused) computes
// next layer's aS/aD dots from the fresh f32 rows.
// grid 625: block = 32 rows x 128 cols; 4 waves, wave = 32x32 tile.
__global__ __launch_bounds__(256) void ugemm(const ushort_t* __restrict__ Ub,
                                             const ushort_t* __restrict__ Bp,
                                             const float* __restrict__ bias,
                                             const float* __restrict__ wtS,
                                             const float* __restrict__ wtD,
                                             float* __restrict__ x,
                                             ushort_t* __restrict__ xb,
                                             float* __restrict__ aS,
                                             float* __restrict__ aD,
                                             int do_dots) {
    __shared__ float lwS[4][128], lwD[4][128];
    __shared__ float pS[4][32][4], pD[4][32][4];
    int t = threadIdx.x, lane = t & 63, w = t >> 6;
    if (do_dots) {
        for (int i = t; i < 512; i += 256) {
            lwS[i >> 7][i & 127] = wtS[i];
            lwD[i >> 7][i & 127] = wtD[i];
        }
        __syncthreads();
    }
    int bm0 = blockIdx.x * 32;
    int bn0 = w * 32;
    int r16 = lane & 15, g = lane >> 4;

    const ushort_t* arow = Ub + (size_t)(bm0 + r16) * 512 + g * 8;
    const ushort_t* bcol = Bp + (size_t)(bn0 + r16) * 512 + g * 8;

    f32x4 acc[2][2] = {};
#pragma unroll 4
    for (int k0 = 0; k0 < 512; k0 += 32) {
        bf16x8 a0 = *(const bf16x8*)(arow + k0);
        bf16x8 a1 = *(const bf16x8*)(arow + 16 * 512 + k0);
        bf16x8 b0 = *(const bf16x8*)(bcol + k0);
        bf16x8 b1 = *(const bf16x8*)(bcol + 16 * 512 + k0);
        acc[0][0] = __builtin_amdgcn_mfma_f32_16x16x32_bf16(a0, b0, acc[0][0], 0, 0, 0);
        acc[0][1] = __builtin_amdgcn_mfma_f32_16x16x32_bf16(a0, b1, acc[0][1], 0, 0, 0);
        acc[1][0] = __builtin_amdgcn_mfma_f32_16x16x32_bf16(a1, b0, acc[1][0], 0, 0, 0);
        acc[1][1] = __builtin_amdgcn_mfma_f32_16x16x32_bf16(a1, b1, acc[1][1], 0, 0, 0);
    }

    // epilogue: residual update (all rows valid: grid is exactly 20000/32)
    float bia[2] = {bias[bn0 + r16], bias[bn0 + 16 + r16]};
    float nx[2][2][4];
#pragma unroll
    for (int fm = 0; fm < 2; ++fm)
#pragma unroll
        for (int fn = 0; fn < 2; ++fn) {
            int col = bn0 + fn * 16 + r16;
#pragma unroll
            for (int r = 0; r < 4; ++r) {
                int row = bm0 + fm * 16 + g * 4 + r;
                float v = 0.25f * acc[fm][fn][r] + bia[fn];
                v = v > 0.f ? v : 0.f;
                float nv = x[(size_t)row * 128 + col] + v;
                x[(size_t)row * 128 + col] = nv;
                xb[(size_t)row * 128 + col] = f2bf(nv);
                nx[fm][fn][r] = nv;
            }
        }

    // fused dots for next layer (f32 precision)
    if (do_dots) {
        int c0 = bn0 + r16, c1 = bn0 + 16 + r16;
#pragma unroll
        for (int fm = 0; fm < 2; ++fm)
#pragma unroll
            for (int r = 0; r < 4; ++r) {
                float sS[4], sD[4];
#pragma unroll
                for (int h = 0; h < 4; ++h) {
                    sS[h] = nx[fm][0][r] * lwS[h][c0] + nx[fm][1][r] * lwS[h][c1];
                    sD[h] = nx[fm][0][r] * lwD[h][c0] + nx[fm][1][r] * lwD[h][c1];
                }
#pragma unroll
                for (int st = 1; st < 16; st <<= 1)
#pragma unroll
                    for (int h = 0; h < 4; ++h) {
                        sS[h] += __shfl_xor(sS[h], st);
                        sD[h] += __shfl_xor(sD[h], st);
                    }
                if (r16 == 0) {
                    int lr = fm * 16 + g * 4 + r;
#pragma unroll
                    for (int h = 0; h < 4; ++h) {
                        pS[w][lr][h] = sS[h];
                        pD[w][lr][h] = sD[h];
                    }
                }
            }
        __syncthreads();
        if (t < 128) {
            int lr = t >> 2, h = t & 3;
            int row = bm0 + lr;
            aS[(size_t)row * 4 + h] = pS[0][lr][h] + pS[1][lr][h] + pS[2][lr][h] + pS[3][lr][h];
            aD[(size_t)row * 4 + h] = pD[0][lr][h] + pD[1][lr][h] + pD[2][lr][h] + pD[3][lr][h];
        }
    }
}

// ---------------------------------------------------------------------------
// Prediction heads (MFMA attack head + strided vuln dot)
__global__ __launch_bounds__(256) void pred_kernel(const float* __restrict__ x,
                                                   const ushort_t* __restrict__ xb,
                                                   const ushort_t* __restrict__ W1p,
                                                   const float* __restrict__ b1,
                                                   const float* __restrict__ W2,
                                                   const float* __restrict__ b2,
                                                   const float* __restrict__ vW,
                                                   const float* __restrict__ vb,
                                                   float* __restrict__ out) {
    int t = threadIdx.x;
    int lane = t & 63, w = t >> 6;
    int wr = w >> 1, wc = w & 1;
    int bm0 = blockIdx.x * 64 + wr * 32;
    int bn0 = wc * 32;
    int r16 = lane & 15, g = lane >> 4;

    const ushort_t* arow = xb + (size_t)(bm0 + r16) * 128 + g * 8;
    const ushort_t* bcol = W1p + (size_t)(bn0 + r16) * 128 + g * 8;

    f32x4 acc[2][2] = {};
#pragma unroll
    for (int k0 = 0; k0 < 128; k0 += 32) {
        bf16x8 a0 = *(const bf16x8*)(arow + k0);
        bf16x8 a1 = *(const bf16x8*)(arow + 16 * 128 + k0);
        bf16x8 b0 = *(const bf16x8*)(bcol + k0);
        bf16x8 b1 = *(const bf16x8*)(bcol + 16 * 128 + k0);
        acc[0][0] = __builtin_amdgcn_mfma_f32_16x16x32_bf16(a0, b0, acc[0][0], 0, 0, 0);
        acc[0][1] = __builtin_amdgcn_mfma_f32_16x16x32_bf16(a0, b1, acc[0][1], 0, 0, 0);
        acc[1][0] = __builtin_amdgcn_mfma_f32_16x16x32_bf16(a1, b0, acc[1][0], 0, 0, 0);
        acc[1][1] = __builtin_amdgcn_mfma_f32_16x16x32_bf16(a1, b1, acc[1][1], 0, 0, 0);
    }

    __shared__ float pa[2][64];
    float b1c[2] = {b1[bn0 + r16], b1[bn0 + 16 + r16]};
    float w2c[2] = {W2[bn0 + r16], W2[bn0 + 16 + r16]};
#pragma unroll
    for (int fm = 0; fm < 2; ++fm)
#pragma unroll
        for (int r = 0; r < 4; ++r) {
            float h10 = acc[fm][0][r] + b1c[0]; h10 = h10 > 0.f ? h10 : 0.f;
            float h11 = acc[fm][1][r] + b1c[1]; h11 = h11 > 0.f ? h11 : 0.f;
            float s = h10 * w2c[0] + h11 * w2c[1];
#pragma unroll
            for (int st = 1; st < 16; st <<= 1) s += __shfl_xor(s, st);
            if (r16 == 0) pa[wc][wr * 32 + fm * 16 + g * 4 + r] = s;
        }
    __syncthreads();
    if (t < 64) {
        int row = blockIdx.x * 64 + t;
        if (row < N_NODES) {
            float pre = pa[0][t] + pa[1][t] + b2[0];
            out[row] = 1.f / (1.f + __expf(-pre));
        }
    }
    int vrow = blockIdx.x * 64 + w * 16 + (lane >> 2);
    int q = lane & 3;
    if (vrow < N_NODES) {
        const float* xr = x + (size_t)vrow * 128 + q * 32;
        float s = 0.f;
#pragma unroll
        for (int j = 0; j < 32; ++j) s = fmaf(xr[j], vW[q * 32 + j], s);
        s += __shfl_xor(s, 1);
        s += __shfl_xor(s, 2);
        if (q == 0)
            out[N_NODES + vrow] = 1.f / (1.f + __expf(-(s + vb[0])));
    }
}

// ---------------------------------------------------------------------------
extern "C" void kernel_launch(void* const* d_in, const int* in_sizes, int n_in,
                              void* d_out, int out_size, void* d_ws, size_t ws_size,
                              hipStream_t stream) {
    const float* nf    = (const float*)d_in[0];
    const int*   ei    = (const int*)d_in[1];
    const float* encW  = (const float*)d_in[2];
    const float* encb  = (const float*)d_in[3];
    const float* lin   = (const float*)d_in[4];
    const float* attS  = (const float*)d_in[5];
    const float* attD  = (const float*)d_in[6];
    const float* gbias = (const float*)d_in[7];
    const float* W1    = (const float*)d_in[8];
    const float* b1    = (const float*)d_in[9];
    const float* W2    = (const float*)d_in[10];
    const float* b2    = (const float*)d_in[11];
    const float* vW    = (const float*)d_in[12];
    const float* vb    = (const float*)d_in[13];
    float* out = (float*)d_out;

    char* ws = (char*)d_ws;
    size_t o = 0;
    auto alloc = [&](size_t bytes) {
        void* p = ws + o;
        o += (bytes + 255) & ~(size_t)255;
        return p;
    };
    float* x      = (float*)alloc((size_t)N_NODES * 128 * 4);
    ushort_t* xb  = (ushort_t*)alloc((size_t)N_PAD * 128 * 2);
    ushort_t* Ub  = (ushort_t*)alloc((size_t)N_NODES * 512 * 2);
    ushort_t* Bp  = (ushort_t*)alloc((size_t)3 * 128 * 512 * 2);
    ushort_t* W1p = (ushort_t*)alloc((size_t)64 * 128 * 2);
    float* wtS    = (float*)alloc((size_t)3 * 512 * 4);
    float* wtD    = (float*)alloc((size_t)3 * 512 * 4);
    float* aS     = (float*)alloc((size_t)N_NODES * 4 * 4);
    float* aD     = (float*)alloc((size_t)N_NODES * 4 * 4);
    int* deg      = (int*)alloc((size_t)N_NODES * 4);
    int* cursor   = (int*)alloc((size_t)N_NODES * 4);
    int* offs     = (int*)alloc((size_t)(N_NODES + 1) * 4);
    int* csr      = (int*)alloc((size_t)ET * 4);

    const int HIST_BLOCKS = (ET + 255) / 256;

    pack_all<<<96, 256, 0, stream>>>(lin, attS, attD, W1, Bp, wtS, wtD, W1p, deg);
    enc_hist<<<ENC_BLOCKS + HIST_BLOCKS, 256, 0, stream>>>(nf, encW, encb, ei, x, xb, deg);
    scan_kernel<<<1, 1024, 0, stream>>>(deg, offs, cursor);
    scatter_kernel<<<HIST_BLOCKS, 256, 0, stream>>>(ei, cursor, csr);
    dots_kernel<<<N_NODES / 32, 256, 0, stream>>>(xb, wtS, wtD, aS, aD);

    for (int l = 0; l < 3; ++l) {
        gat_agg<<<N_NODES / 4, 256, 0, stream>>>((const uint_t*)xb, aS, aD, offs, csr,
                                                 (uint_t*)Ub);
        int dd = (l < 2) ? 1 : 0;
        const float* nwtS = wtS + (size_t)(dd ? (l + 1) : 0) * 512;
        const float* nwtD = wtD + (size_t)(dd ? (l + 1) : 0) * 512;
        ugemm<<<N_NODES / 32, 256, 0, stream>>>(Ub, Bp + (size_t)l * 128 * 512,
                                                gbias + (size_t)l * 128,
                                                nwtS, nwtD, x, xb, aS, aD, dd);
    }
    pred_kernel<<<N_PAD / 64, 256, 0, stream>>>(x, xb, W1p, b1, W2, b2, vW, vb, out);
}

// Round 8
// 292.496 us; speedup vs baseline: 2.0779x; 1.0137x over previous
//
#include <hip/hip_runtime.h>

#define N_NODES 20000
#define N_PAD 20032
#define F_IN 64
#define HID 128
#define HEADS 4
#define E_EDGES 320000
#define ET (E_EDGES + N_NODES)   // + self loops
#define NEG_SLOPE 0.2f
#define LNODES 16                // nodes per gat_layer block

typedef unsigned short ushort_t;
typedef unsigned int uint_t;

using bf16x8 = __attribute__((ext_vector_type(8))) short;
using f32x4  = __attribute__((ext_vector_type(4))) float;

__device__ __forceinline__ ushort_t f2bf(float f) {
    union { float f; uint_t u; } v; v.f = f;
    uint_t r = v.u + 0x7fffu + ((v.u >> 16) & 1u);   // round-to-nearest-even
    return (ushort_t)(r >> 16);
}
__device__ __forceinline__ float bflo(uint_t w) {
    union { uint_t u; float f; } v; v.u = w << 16; return v.f;
}
__device__ __forceinline__ float bfhi(uint_t w) {
    union { uint_t u; float f; } v; v.u = w & 0xffff0000u; return v.f;
}
__device__ __forceinline__ float rdlane_f(float v, int j) {
    return __uint_as_float(__builtin_amdgcn_readlane(__float_as_uint(v), j));
}

// ---------------------------------------------------------------------------
// ONE pack kernel: Bp (W-bar bf16), wtS/wtD (f32), W1p (bf16), deg clear.
__global__ __launch_bounds__(256) void pack_all(const float* __restrict__ lin,
                                                const float* __restrict__ attS,
                                                const float* __restrict__ attD,
                                                const float* __restrict__ W1,
                                                ushort_t* __restrict__ Bp,
                                                float* __restrict__ wtS,
                                                float* __restrict__ wtD,
                                                ushort_t* __restrict__ W1p,
                                                int* __restrict__ deg) {
    int idx = blockIdx.x * 256 + threadIdx.x;
    if (idx < N_NODES) deg[idx] = 0;

    {   // job A: Bp[l][col][kk] = lin[l][kk&127][(kk>>7)*128 + col]
        int l = idx / 8192;
        int rem = idx % 8192;
        int col = rem / 64, kg = rem % 64;
        const float* W = lin + (size_t)l * 128 * 512;
        int h = kg >> 4;
        int kbase = (kg & 15) * 8;
        ushort_t tmp[8];
#pragma unroll
        for (int j = 0; j < 8; ++j)
            tmp[j] = f2bf(W[(size_t)(kbase + j) * 512 + h * 128 + col]);
        *(uint4*)(Bp + ((size_t)(l * 128 + col)) * 512 + kg * 8) = *(const uint4*)tmp;
    }

    if (idx < 1536) {   // job B: w-tilde
        int l = idx / 512;
        int rem = idx % 512;
        int h = rem >> 7, k = rem & 127;
        const float* W = lin + (size_t)l * 128 * 512 + (size_t)k * 512 + h * 128;
        const float* as = attS + (size_t)l * 512 + h * 128;
        const float* ad = attD + (size_t)l * 512 + h * 128;
        float ss = 0.f, sd = 0.f;
        for (int d = 0; d < 128; ++d) {
            float w = W[d];
            ss = fmaf(w, as[d], ss);
            sd = fmaf(w, ad[d], sd);
        }
        wtS[idx] = ss;
        wtD[idx] = sd;
    }

    if (idx < 1024) {   // job C: W1p
        int col = idx >> 4, kg = idx & 15;
        ushort_t tmp[8];
#pragma unroll
        for (int j = 0; j < 8; ++j)
            tmp[j] = f2bf(W1[(size_t)(kg * 8 + j) * 64 + col]);
        *(uint4*)(W1p + (size_t)col * 128 + kg * 8) = *(const uint4*)tmp;
    }
}

// ---------------------------------------------------------------------------
// Fused encoder + degree histogram.
#define ENC_BLOCKS 1250
__global__ __launch_bounds__(256) void enc_hist(const float* __restrict__ nf,
                                                const float* __restrict__ W,
                                                const float* __restrict__ b,
                                                const int* __restrict__ ei,
                                                float* __restrict__ x,
                                                ushort_t* __restrict__ xb,
                                                int* __restrict__ deg) {
    int t = threadIdx.x;
    if (blockIdx.x < ENC_BLOCKS) {
        __shared__ float xs[16][64];
        int n0 = blockIdx.x * 16;
        ((float4*)&xs[0][0])[t] = ((const float4*)(nf + (size_t)n0 * 64))[t];
        __syncthreads();
        int c = t & 127, ng = t >> 7;
        float acc[8];
#pragma unroll
        for (int i = 0; i < 8; ++i) acc[i] = 0.f;
        for (int k = 0; k < 64; ++k) {
            float wv = W[k * 128 + c];
#pragma unroll
            for (int i = 0; i < 8; ++i) acc[i] = fmaf(xs[ng * 8 + i][k], wv, acc[i]);
        }
        float bias = b[c];
#pragma unroll
        for (int i = 0; i < 8; ++i) {
            float v = acc[i] + bias;
            v = v > 0.f ? v : 0.f;
            int row = n0 + ng * 8 + i;
            x[(size_t)row * 128 + c] = v;
            xb[(size_t)row * 128 + c] = f2bf(v);
        }
    } else {
        int e = (blockIdx.x - ENC_BLOCKS) * 256 + t;
        if (e < ET) {
            int d = (e < E_EDGES) ? ei[E_EDGES + e] : (e - E_EDGES);
            atomicAdd(&deg[d], 1);
        }
    }
}

// ---------------------------------------------------------------------------
__global__ __launch_bounds__(1024) void scan_kernel(const int* __restrict__ deg,
                                                    int* __restrict__ off,
                                                    int* __restrict__ cursor) {
    __shared__ int sums[1024];
    int t = threadIdx.x;
    int base = t * 20;
    int tmp[20];
    int s = 0;
#pragma unroll
    for (int i = 0; i < 20; ++i) {
        int idx = base + i;
        int v = (idx < N_NODES) ? deg[idx] : 0;
        tmp[i] = s;
        s += v;
    }
    sums[t] = s;
    __syncthreads();
    for (int st = 1; st < 1024; st <<= 1) {
        int v = (t >= st) ? sums[t - st] : 0;
        __syncthreads();
        sums[t] += v;
        __syncthreads();
    }
    int bsum = (t == 0) ? 0 : sums[t - 1];
#pragma unroll
    for (int i = 0; i < 20; ++i) {
        int idx = base + i;
        if (idx < N_NODES) {
            int v = bsum + tmp[i];
            off[idx] = v;
            cursor[idx] = v;
        }
    }
    if (t == 1023) off[N_NODES] = sums[1023];
}

__global__ void scatter_kernel(const int* __restrict__ ei,
                               int* __restrict__ cursor, int* __restrict__ csr) {
    int e = blockIdx.x * 256 + threadIdx.x;
    if (e >= ET) return;
    int s, d;
    if (e < E_EDGES) { s = ei[e]; d = ei[E_EDGES + e]; }
    else             { s = d = e - E_EDGES; }
    int pos = atomicAdd(&cursor[d], 1);
    csr[pos] = s;
}

// ---------------------------------------------------------------------------
// dots for layer 0 (from bf16 xb0). 32 nodes/block, 8 threads per node.
__global__ __launch_bounds__(256) void dots_kernel(const ushort_t* __restrict__ xb,
                                                   const float* __restrict__ wtS,
                                                   const float* __restrict__ wtD,
                                                   float* __restrict__ aS,
                                                   float* __restrict__ aD) {
    __shared__ float ls[4][128], ld_[4][128];
    int t = threadIdx.x;
    for (int i = t; i < 512; i += 256) {
        ls[i >> 7][i & 127] = wtS[i];
        ld_[i >> 7][i & 127] = wtD[i];
    }
    __syncthreads();
    int n = blockIdx.x * 32 + (t >> 3);
    int p = t & 7;
    const uint_t* xr = (const uint_t*)xb + (size_t)n * 64 + p * 8;
    float pS[4] = {0.f, 0.f, 0.f, 0.f}, pD[4] = {0.f, 0.f, 0.f, 0.f};
#pragma unroll
    for (int j = 0; j < 8; ++j) {
        uint_t u = xr[j];
        float f0 = bflo(u), f1 = bfhi(u);
        int d = p * 16 + j * 2;
#pragma unroll
        for (int h = 0; h < 4; ++h) {
            pS[h] = fmaf(f0, ls[h][d], fmaf(f1, ls[h][d + 1], pS[h]));
            pD[h] = fmaf(f0, ld_[h][d], fmaf(f1, ld_[h][d + 1], pD[h]));
        }
    }
#pragma unroll
    for (int st = 1; st < 8; st <<= 1) {
#pragma unroll
        for (int h = 0; h < 4; ++h) {
            pS[h] += __shfl_xor(pS[h], st);
            pD[h] += __shfl_xor(pD[h], st);
        }
    }
    if (p == 0) {
        *(float4*)(aS + (size_t)n * 4) = make_float4(pS[0], pS[1], pS[2], pS[3]);
        *(float4*)(aD + (size_t)n * 4) = make_float4(pD[0], pD[1], pD[2], pD[3]);
    }
}

// ---------------------------------------------------------------------------
// FUSED LAYER: phase A = wave-per-node softmax-gather into LDS (U, bf16,
// XOR-swizzled); phase B = 8-wave MFMA GEMM 16x512 @ 512x128 + residual +
// relu + (optional) next-layer dots. Double-buffered x/xb and aS/aD:
// reads *_cur, writes *_next (no intra-dispatch races).
__global__ __launch_bounds__(512) void gat_layer(const uint_t* __restrict__ xb2_cur,
                                                 const float* __restrict__ aS_cur,
                                                 const float* __restrict__ aD_cur,
                                                 const int* __restrict__ off,
                                                 const int* __restrict__ csr,
                                                 const ushort_t* __restrict__ Bp,
                                                 const float* __restrict__ bias,
                                                 const float* __restrict__ x_cur,
                                                 float* __restrict__ x_next,
                                                 ushort_t* __restrict__ xb_next,
                                                 const float* __restrict__ wtS,
                                                 const float* __restrict__ wtD,
                                                 float* __restrict__ aS_next,
                                                 float* __restrict__ aD_next,
                                                 int do_dots) {
    __shared__ ushort_t U_lds[LNODES][512];
    __shared__ float lwS[4][128], lwD[4][128];
    __shared__ float pS[8][LNODES][4], pD[8][LNODES][4];

    int t = threadIdx.x;
    int w = t >> 6, l = t & 63;
    int n0 = blockIdx.x * LNODES;

    if (do_dots) {
        for (int i = t; i < 512; i += 512) { /* one pass: 512 threads, 512 items */
            lwS[i >> 7][i & 127] = wtS[i];
            lwD[i >> 7][i & 127] = wtD[i];
        }
    }

    // ---------------- phase A: aggregation, 2 nodes per wave ----------------
    for (int it = 0; it < 2; ++it) {
        int row = w * 2 + it;
        int n = n0 + row;
        int beg = off[n];
        int deg = off[n + 1] - beg;

        float4 adv = *(const float4*)(aD_cur + (size_t)n * 4);

        int sl = 0;
        float4 av = make_float4(-1e30f, -1e30f, -1e30f, -1e30f);
        if (l < deg) {
            sl = csr[beg + l];
            av = *(const float4*)(aS_cur + (size_t)sl * 4);
        }
        float4 smax = av;
        for (int i = l + 64; i < deg; i += 64) {
            int s = csr[beg + i];
            float4 a = *(const float4*)(aS_cur + (size_t)s * 4);
            smax.x = fmaxf(smax.x, a.x);
            smax.y = fmaxf(smax.y, a.y);
            smax.z = fmaxf(smax.z, a.z);
            smax.w = fmaxf(smax.w, a.w);
        }
#pragma unroll
        for (int st = 1; st < 64; st <<= 1) {
            smax.x = fmaxf(smax.x, __shfl_xor(smax.x, st));
            smax.y = fmaxf(smax.y, __shfl_xor(smax.y, st));
            smax.z = fmaxf(smax.z, __shfl_xor(smax.z, st));
            smax.w = fmaxf(smax.w, __shfl_xor(smax.w, st));
        }
        float e;
        e = smax.x + adv.x; float m0 = e > 0.f ? e : NEG_SLOPE * e;
        e = smax.y + adv.y; float m1 = e > 0.f ? e : NEG_SLOPE * e;
        e = smax.z + adv.z; float m2 = e > 0.f ? e : NEG_SLOPE * e;
        e = smax.w + adv.w; float m3 = e > 0.f ? e : NEG_SLOPE * e;

        float acc[8];
#pragma unroll
        for (int i = 0; i < 8; ++i) acc[i] = 0.f;
        float4 zac = make_float4(0.f, 0.f, 0.f, 0.f);

        // chunk 0 from registers
        int ce = min(64, deg);
        float4 wv = make_float4(0.f, 0.f, 0.f, 0.f);
        if (l < ce) {
            e = av.x + adv.x; e = e > 0.f ? e : NEG_SLOPE * e; wv.x = __expf(e - m0);
            e = av.y + adv.y; e = e > 0.f ? e : NEG_SLOPE * e; wv.y = __expf(e - m1);
            e = av.z + adv.z; e = e > 0.f ? e : NEG_SLOPE * e; wv.z = __expf(e - m2);
            e = av.w + adv.w; e = e > 0.f ? e : NEG_SLOPE * e; wv.w = __expf(e - m3);
            zac.x += wv.x; zac.y += wv.y; zac.z += wv.z; zac.w += wv.w;
        }
#pragma unroll 4
        for (int j = 0; j < ce; ++j) {
            int s = __builtin_amdgcn_readlane(sl, j);
            float w0 = rdlane_f(wv.x, j);
            float w1 = rdlane_f(wv.y, j);
            float w2 = rdlane_f(wv.z, j);
            float w3 = rdlane_f(wv.w, j);
            uint_t xv = xb2_cur[(size_t)s * 64 + l];
            float f0 = bflo(xv), f1 = bfhi(xv);
            acc[0] = fmaf(w0, f0, acc[0]); acc[1] = fmaf(w0, f1, acc[1]);
            acc[2] = fmaf(w1, f0, acc[2]); acc[3] = fmaf(w1, f1, acc[3]);
            acc[4] = fmaf(w2, f0, acc[4]); acc[5] = fmaf(w2, f1, acc[5]);
            acc[6] = fmaf(w3, f0, acc[6]); acc[7] = fmaf(w3, f1, acc[7]);
        }
        for (int c0 = 64; c0 < deg; c0 += 64) {
            ce = min(64, deg - c0);
            wv = make_float4(0.f, 0.f, 0.f, 0.f);
            if (l < ce) {
                sl = csr[beg + c0 + l];
                float4 a = *(const float4*)(aS_cur + (size_t)sl * 4);
                e = a.x + adv.x; e = e > 0.f ? e : NEG_SLOPE * e; wv.x = __expf(e - m0);
                e = a.y + adv.y; e = e > 0.f ? e : NEG_SLOPE * e; wv.y = __expf(e - m1);
                e = a.z + adv.z; e = e > 0.f ? e : NEG_SLOPE * e; wv.z = __expf(e - m2);
                e = a.w + adv.w; e = e > 0.f ? e : NEG_SLOPE * e; wv.w = __expf(e - m3);
                zac.x += wv.x; zac.y += wv.y; zac.z += wv.z; zac.w += wv.w;
            }
#pragma unroll 4
            for (int j = 0; j < ce; ++j) {
                int s = __builtin_amdgcn_readlane(sl, j);
                float w0 = rdlane_f(wv.x, j);
                float w1 = rdlane_f(wv.y, j);
                float w2 = rdlane_f(wv.z, j);
                float w3 = rdlane_f(wv.w, j);
                uint_t xv = xb2_cur[(size_t)s * 64 + l];
                float f0 = bflo(xv), f1 = bfhi(xv);
                acc[0] = fmaf(w0, f0, acc[0]); acc[1] = fmaf(w0, f1, acc[1]);
                acc[2] = fmaf(w1, f0, acc[2]); acc[3] = fmaf(w1, f1, acc[3]);
                acc[4] = fmaf(w2, f0, acc[4]); acc[5] = fmaf(w2, f1, acc[5]);
                acc[6] = fmaf(w3, f0, acc[6]); acc[7] = fmaf(w3, f1, acc[7]);
            }
        }

#pragma unroll
        for (int st = 1; st < 64; st <<= 1) {
            zac.x += __shfl_xor(zac.x, st);
            zac.y += __shfl_xor(zac.y, st);
            zac.z += __shfl_xor(zac.z, st);
            zac.w += __shfl_xor(zac.w, st);
        }
        float iz0 = 1.f / zac.x, iz1 = 1.f / zac.y, iz2 = 1.f / zac.z, iz3 = 1.f / zac.w;
        // U row -> LDS, XOR-swizzled (uint idx ^= (row&7)<<2 within h-block)
        uint_t* U32 = (uint_t*)&U_lds[row][0];
        int swz = (row & 7) << 2;
        int li = l ^ swz;
        U32[li]        = (uint_t)f2bf(acc[0] * iz0) | ((uint_t)f2bf(acc[1] * iz0) << 16);
        U32[64 + li]   = (uint_t)f2bf(acc[2] * iz1) | ((uint_t)f2bf(acc[3] * iz1) << 16);
        U32[128 + li]  = (uint_t)f2bf(acc[4] * iz2) | ((uint_t)f2bf(acc[5] * iz2) << 16);
        U32[192 + li]  = (uint_t)f2bf(acc[6] * iz3) | ((uint_t)f2bf(acc[7] * iz3) << 16);
    }

    __syncthreads();

    // ---------------- phase B: GEMM 16x512 @ 512x128 ----------------
    int r16 = l & 15, g = l >> 4;
    int bn0 = w * 16;
    const ushort_t* bcol = Bp + (size_t)(bn0 + r16) * 512 + g * 8;
    int arow_sw = (r16 & 7) << 3;   // element-index XOR for ds reads

    f32x4 cacc = {};
#pragma unroll 4
    for (int k0 = 0; k0 < 512; k0 += 32) {
        bf16x8 a = *(const bf16x8*)&U_lds[r16][(k0 + g * 8) ^ arow_sw];
        bf16x8 bb = *(const bf16x8*)(bcol + k0);
        cacc = __builtin_amdgcn_mfma_f32_16x16x32_bf16(a, bb, cacc, 0, 0, 0);
    }

    // epilogue: residual + relu + store; optional fused dots
    int col = bn0 + r16;
    float bia = bias[col];
    float nx[4];
#pragma unroll
    for (int r = 0; r < 4; ++r) {
        int rl = g * 4 + r;
        int row = n0 + rl;
        float v = 0.25f * cacc[r] + bia;
        v = v > 0.f ? v : 0.f;
        float nv = x_cur[(size_t)row * 128 + col] + v;
        x_next[(size_t)row * 128 + col] = nv;
        xb_next[(size_t)row * 128 + col] = f2bf(nv);
        nx[r] = nv;
    }

    if (do_dots) {
#pragma unroll
        for (int r = 0; r < 4; ++r) {
            float sS[4], sD[4];
#pragma unroll
            for (int h = 0; h < 4; ++h) {
                sS[h] = nx[r] * lwS[h][col];
                sD[h] = nx[r] * lwD[h][col];
            }
#pragma unroll
            for (int st = 1; st < 16; st <<= 1)
#pragma unroll
                for (int h = 0; h < 4; ++h) {
                    sS[h] += __shfl_xor(sS[h], st);
                    sD[h] += __shfl_xor(sD[h], st);
                }
            if (r16 == 0) {
                int rl = g * 4 + r;
#pragma unroll
                for (int h = 0; h < 4; ++h) {
                    pS[w][rl][h] = sS[h];
                    pD[w][rl][h] = sD[h];
                }
            }
        }
        __syncthreads();
        if (t < LNODES * 4) {
            int rl = t >> 2, h = t & 3;
            int row = n0 + rl;
            float ssum = 0.f, dsum = 0.f;
#pragma unroll
            for (int ww = 0; ww < 8; ++ww) {
                ssum += pS[ww][rl][h];
                dsum += pD[ww][rl][h];
            }
            aS_next[(size_t)row * 4 + h] = ssum;
            aD_next[(size_t)row * 4 + h] = dsum;
        }
    }
}

// ---------------------------------------------------------------------------
// Prediction heads (MFMA attack head + strided vuln dot)
__global__ __launch_bounds__(256) void pred_kernel(const float* __restrict__ x,
                                                   const ushort_t* __restrict__ xb,
                                                   const ushort_t* __restrict__ W1p,
                                                   const float* __restrict__ b1,
                                                   const float* __restrict__ W2,
                                                   const float* __restrict__ b2,
                                                   const float* __restrict__ vW,
                                                   const float* __restrict__ vb,
                                                   float* __restrict__ out) {
    int t = threadIdx.x;
    int lane = t & 63, w = t >> 6;
    int wr = w >> 1, wc = w & 1;
    int bm0 = blockIdx.x * 64 + wr * 32;
    int bn0 = wc * 32;
    int r16 = lane & 15, g = lane >> 4;

    const ushort_t* arow = xb + (size_t)(bm0 + r16) * 128 + g * 8;
    const ushort_t* bcol = W1p + (size_t)(bn0 + r16) * 128 + g * 8;

    f32x4 acc[2][2] = {};
#pragma unroll
    for (int k0 = 0; k0 < 128; k0 += 32) {
        bf16x8 a0 = *(const bf16x8*)(arow + k0);
        bf16x8 a1 = *(const bf16x8*)(arow + 16 * 128 + k0);
        bf16x8 b0 = *(const bf16x8*)(bcol + k0);
        bf16x8 b1 = *(const bf16x8*)(bcol + 16 * 128 + k0);
        acc[0][0] = __builtin_amdgcn_mfma_f32_16x16x32_bf16(a0, b0, acc[0][0], 0, 0, 0);
        acc[0][1] = __builtin_amdgcn_mfma_f32_16x16x32_bf16(a0, b1, acc[0][1], 0, 0, 0);
        acc[1][0] = __builtin_amdgcn_mfma_f32_16x16x32_bf16(a1, b0, acc[1][0], 0, 0, 0);
        acc[1][1] = __builtin_amdgcn_mfma_f32_16x16x32_bf16(a1, b1, acc[1][1], 0, 0, 0);
    }

    __shared__ float pa[2][64];
    float b1c[2] = {b1[bn0 + r16], b1[bn0 + 16 + r16]};
    float w2c[2] = {W2[bn0 + r16], W2[bn0 + 16 + r16]};
#pragma unroll
    for (int fm = 0; fm < 2; ++fm)
#pragma unroll
        for (int r = 0; r < 4; ++r) {
            float h10 = acc[fm][0][r] + b1c[0]; h10 = h10 > 0.f ? h10 : 0.f;
            float h11 = acc[fm][1][r] + b1c[1]; h11 = h11 > 0.f ? h11 : 0.f;
            float s = h10 * w2c[0] + h11 * w2c[1];
#pragma unroll
            for (int st = 1; st < 16; st <<= 1) s += __shfl_xor(s, st);
            if (r16 == 0) pa[wc][wr * 32 + fm * 16 + g * 4 + r] = s;
        }
    __syncthreads();
    if (t < 64) {
        int row = blockIdx.x * 64 + t;
        if (row < N_NODES) {
            float pre = pa[0][t] + pa[1][t] + b2[0];
            out[row] = 1.f / (1.f + __expf(-pre));
        }
    }
    int vrow = blockIdx.x * 64 + w * 16 + (lane >> 2);
    int q = lane & 3;
    if (vrow < N_NODES) {
        const float* xr = x + (size_t)vrow * 128 + q * 32;
        float s = 0.f;
#pragma unroll
        for (int j = 0; j < 32; ++j) s = fmaf(xr[j], vW[q * 32 + j], s);
        s += __shfl_xor(s, 1);
        s += __shfl_xor(s, 2);
        if (q == 0)
            out[N_NODES + vrow] = 1.f / (1.f + __expf(-(s + vb[0])));
    }
}

// ---------------------------------------------------------------------------
extern "C" void kernel_launch(void* const* d_in, const int* in_sizes, int n_in,
                              void* d_out, int out_size, void* d_ws, size_t ws_size,
                              hipStream_t stream) {
    const float* nf    = (const float*)d_in[0];
    const int*   ei    = (const int*)d_in[1];
    const float* encW  = (const float*)d_in[2];
    const float* encb  = (const float*)d_in[3];
    const float* lin   = (const float*)d_in[4];
    const float* attS  = (const float*)d_in[5];
    const float* attD  = (const float*)d_in[6];
    const float* gbias = (const float*)d_in[7];
    const float* W1    = (const float*)d_in[8];
    const float* b1    = (const float*)d_in[9];
    const float* W2    = (const float*)d_in[10];
    const float* b2    = (const float*)d_in[11];
    const float* vW    = (const float*)d_in[12];
    const float* vb    = (const float*)d_in[13];
    float* out = (float*)d_out;

    char* ws = (char*)d_ws;
    size_t o = 0;
    auto alloc = [&](size_t bytes) {
        void* p = ws + o;
        o += (bytes + 255) & ~(size_t)255;
        return p;
    };
    float* x0     = (float*)alloc((size_t)N_PAD * 128 * 4);
    float* x1     = (float*)alloc((size_t)N_PAD * 128 * 4);
    ushort_t* xb0 = (ushort_t*)alloc((size_t)N_PAD * 128 * 2);
    ushort_t* xb1 = (ushort_t*)alloc((size_t)N_PAD * 128 * 2);
    ushort_t* Bp  = (ushort_t*)alloc((size_t)3 * 128 * 512 * 2);
    ushort_t* W1p = (ushort_t*)alloc((size_t)64 * 128 * 2);
    float* wtS    = (float*)alloc((size_t)3 * 512 * 4);
    float* wtD    = (float*)alloc((size_t)3 * 512 * 4);
    float* aS0    = (float*)alloc((size_t)N_NODES * 4 * 4);
    float* aD0    = (float*)alloc((size_t)N_NODES * 4 * 4);
    float* aS1    = (float*)alloc((size_t)N_NODES * 4 * 4);
    float* aD1    = (float*)alloc((size_t)N_NODES * 4 * 4);
    int* deg      = (int*)alloc((size_t)N_NODES * 4);
    int* cursor   = (int*)alloc((size_t)N_NODES * 4);
    int* offs     = (int*)alloc((size_t)(N_NODES + 1) * 4);
    int* csr      = (int*)alloc((size_t)ET * 4);

    const int HIST_BLOCKS = (ET + 255) / 256;

    pack_all<<<96, 256, 0, stream>>>(lin, attS, attD, W1, Bp, wtS, wtD, W1p, deg);
    enc_hist<<<ENC_BLOCKS + HIST_BLOCKS, 256, 0, stream>>>(nf, encW, encb, ei, x0, xb0, deg);
    scan_kernel<<<1, 1024, 0, stream>>>(deg, offs, cursor);
    scatter_kernel<<<HIST_BLOCKS, 256, 0, stream>>>(ei, cursor, csr);
    dots_kernel<<<N_NODES / 32, 256, 0, stream>>>(xb0, wtS, wtD, aS0, aD0);

    float*    xc[2]  = {x0, x1};
    ushort_t* xbc[2] = {xb0, xb1};
    float*    aSc[2] = {aS0, aS1};
    float*    aDc[2] = {aD0, aD1};
    for (int l = 0; l < 3; ++l) {
        int ci = l & 1, ni = ci ^ 1;
        int dd = (l < 2) ? 1 : 0;
        gat_layer<<<N_NODES / LNODES, 512, 0, stream>>>(
            (const uint_t*)xbc[ci], aSc[ci], aDc[ci], offs, csr,
            Bp + (size_t)l * 128 * 512, gbias + (size_t)l * 128,
            xc[ci], xc[ni], xbc[ni],
            wtS + (size_t)(l + 1 < 3 ? l + 1 : 0) * 512,
            wtD + (size_t)(l + 1 < 3 ? l + 1 : 0) * 512,
            aSc[ni], aDc[ni], dd);
    }
    pred_kernel<<<N_PAD / 64, 256, 0, stream>>>(x1, xb1, W1p, b1, W2, b2, vW, vb, out);
}

// Round 9
// 290.685 us; speedup vs baseline: 2.0908x; 1.0062x over previous
//
#include <hip/hip_runtime.h>

#define N_NODES 20000
#define N_PAD 20032
#define F_IN 64
#define HID 128
#define HEADS 4
#define E_EDGES 320000
#define ET (E_EDGES + N_NODES)   // + self loops
#define NEG_SLOPE 0.2f
#define LNODES 16                // nodes per gat_layer block

typedef unsigned short ushort_t;
typedef unsigned int uint_t;

using bf16x8 = __attribute__((ext_vector_type(8))) short;
using f32x4  = __attribute__((ext_vector_type(4))) float;

__device__ __forceinline__ ushort_t f2bf(float f) {
    union { float f; uint_t u; } v; v.f = f;
    uint_t r = v.u + 0x7fffu + ((v.u >> 16) & 1u);   // round-to-nearest-even
    return (ushort_t)(r >> 16);
}
__device__ __forceinline__ float bflo(uint_t w) {
    union { uint_t u; float f; } v; v.u = w << 16; return v.f;
}
__device__ __forceinline__ float bfhi(uint_t w) {
    union { uint_t u; float f; } v; v.u = w & 0xffff0000u; return v.f;
}
__device__ __forceinline__ float rdlane_f(float v, int j) {
    return __uint_as_float(__builtin_amdgcn_readlane(__float_as_uint(v), j));
}

// ---------------------------------------------------------------------------
// ONE pack kernel: Bp (W-bar bf16), wtS/wtD (f32), W1p (bf16), deg clear.
__global__ __launch_bounds__(256) void pack_all(const float* __restrict__ lin,
                                                const float* __restrict__ attS,
                                                const float* __restrict__ attD,
                                                const float* __restrict__ W1,
                                                ushort_t* __restrict__ Bp,
                                                float* __restrict__ wtS,
                                                float* __restrict__ wtD,
                                                ushort_t* __restrict__ W1p,
                                                int* __restrict__ deg) {
    int idx = blockIdx.x * 256 + threadIdx.x;
    if (idx < N_NODES) deg[idx] = 0;

    {   // job A: Bp[l][col][kk] = lin[l][kk&127][(kk>>7)*128 + col]
        int l = idx / 8192;
        int rem = idx % 8192;
        int col = rem / 64, kg = rem % 64;
        const float* W = lin + (size_t)l * 128 * 512;
        int h = kg >> 4;
        int kbase = (kg & 15) * 8;
        ushort_t tmp[8];
#pragma unroll
        for (int j = 0; j < 8; ++j)
            tmp[j] = f2bf(W[(size_t)(kbase + j) * 512 + h * 128 + col]);
        *(uint4*)(Bp + ((size_t)(l * 128 + col)) * 512 + kg * 8) = *(const uint4*)tmp;
    }

    if (idx < 1536) {   // job B: w-tilde
        int l = idx / 512;
        int rem = idx % 512;
        int h = rem >> 7, k = rem & 127;
        const float* W = lin + (size_t)l * 128 * 512 + (size_t)k * 512 + h * 128;
        const float* as = attS + (size_t)l * 512 + h * 128;
        const float* ad = attD + (size_t)l * 512 + h * 128;
        float ss = 0.f, sd = 0.f;
        for (int d = 0; d < 128; ++d) {
            float w = W[d];
            ss = fmaf(w, as[d], ss);
            sd = fmaf(w, ad[d], sd);
        }
        wtS[idx] = ss;
        wtD[idx] = sd;
    }

    if (idx < 1024) {   // job C: W1p
        int col = idx >> 4, kg = idx & 15;
        ushort_t tmp[8];
#pragma unroll
        for (int j = 0; j < 8; ++j)
            tmp[j] = f2bf(W1[(size_t)(kg * 8 + j) * 64 + col]);
        *(uint4*)(W1p + (size_t)col * 128 + kg * 8) = *(const uint4*)tmp;
    }
}

// ---------------------------------------------------------------------------
// Fused encoder + degree histogram.
#define ENC_BLOCKS 1250
__global__ __launch_bounds__(256) void enc_hist(const float* __restrict__ nf,
                                                const float* __restrict__ W,
                                                const float* __restrict__ b,
                                                const int* __restrict__ ei,
                                                float* __restrict__ x,
                                                ushort_t* __restrict__ xb,
                                                int* __restrict__ deg) {
    int t = threadIdx.x;
    if (blockIdx.x < ENC_BLOCKS) {
        __shared__ float xs[16][64];
        int n0 = blockIdx.x * 16;
        ((float4*)&xs[0][0])[t] = ((const float4*)(nf + (size_t)n0 * 64))[t];
        __syncthreads();
        int c = t & 127, ng = t >> 7;
        float acc[8];
#pragma unroll
        for (int i = 0; i < 8; ++i) acc[i] = 0.f;
        for (int k = 0; k < 64; ++k) {
            float wv = W[k * 128 + c];
#pragma unroll
            for (int i = 0; i < 8; ++i) acc[i] = fmaf(xs[ng * 8 + i][k], wv, acc[i]);
        }
        float bias = b[c];
#pragma unroll
        for (int i = 0; i < 8; ++i) {
            float v = acc[i] + bias;
            v = v > 0.f ? v : 0.f;
            int row = n0 + ng * 8 + i;
            x[(size_t)row * 128 + c] = v;
            xb[(size_t)row * 128 + c] = f2bf(v);
        }
    } else {
        int e = (blockIdx.x - ENC_BLOCKS) * 256 + t;
        if (e < ET) {
            int d = (e < E_EDGES) ? ei[E_EDGES + e] : (e - E_EDGES);
            atomicAdd(&deg[d], 1);
        }
    }
}

// ---------------------------------------------------------------------------
__global__ __launch_bounds__(1024) void scan_kernel(const int* __restrict__ deg,
                                                    int* __restrict__ off,
                                                    int* __restrict__ cursor) {
    __shared__ int sums[1024];
    int t = threadIdx.x;
    int base = t * 20;
    int tmp[20];
    int s = 0;
#pragma unroll
    for (int i = 0; i < 20; ++i) {
        int idx = base + i;
        int v = (idx < N_NODES) ? deg[idx] : 0;
        tmp[i] = s;
        s += v;
    }
    sums[t] = s;
    __syncthreads();
    for (int st = 1; st < 1024; st <<= 1) {
        int v = (t >= st) ? sums[t - st] : 0;
        __syncthreads();
        sums[t] += v;
        __syncthreads();
    }
    int bsum = (t == 0) ? 0 : sums[t - 1];
#pragma unroll
    for (int i = 0; i < 20; ++i) {
        int idx = base + i;
        if (idx < N_NODES) {
            int v = bsum + tmp[i];
            off[idx] = v;
            cursor[idx] = v;
        }
    }
    if (t == 1023) off[N_NODES] = sums[1023];
}

__global__ void scatter_kernel(const int* __restrict__ ei,
                               int* __restrict__ cursor, int* __restrict__ csr) {
    int e = blockIdx.x * 256 + threadIdx.x;
    if (e >= ET) return;
    int s, d;
    if (e < E_EDGES) { s = ei[e]; d = ei[E_EDGES + e]; }
    else             { s = d = e - E_EDGES; }
    int pos = atomicAdd(&cursor[d], 1);
    csr[pos] = s;
}

// ---------------------------------------------------------------------------
// dots for layer 0 (from bf16 xb0). 32 nodes/block, 8 threads per node.
__global__ __launch_bounds__(256) void dots_kernel(const ushort_t* __restrict__ xb,
                                                   const float* __restrict__ wtS,
                                                   const float* __restrict__ wtD,
                                                   float* __restrict__ aS,
                                                   float* __restrict__ aD) {
    __shared__ float ls[4][128], ld_[4][128];
    int t = threadIdx.x;
    for (int i = t; i < 512; i += 256) {
        ls[i >> 7][i & 127] = wtS[i];
        ld_[i >> 7][i & 127] = wtD[i];
    }
    __syncthreads();
    int n = blockIdx.x * 32 + (t >> 3);
    int p = t & 7;
    const uint_t* xr = (const uint_t*)xb + (size_t)n * 64 + p * 8;
    float pS[4] = {0.f, 0.f, 0.f, 0.f}, pD[4] = {0.f, 0.f, 0.f, 0.f};
#pragma unroll
    for (int j = 0; j < 8; ++j) {
        uint_t u = xr[j];
        float f0 = bflo(u), f1 = bfhi(u);
        int d = p * 16 + j * 2;
#pragma unroll
        for (int h = 0; h < 4; ++h) {
            pS[h] = fmaf(f0, ls[h][d], fmaf(f1, ls[h][d + 1], pS[h]));
            pD[h] = fmaf(f0, ld_[h][d], fmaf(f1, ld_[h][d + 1], pD[h]));
        }
    }
#pragma unroll
    for (int st = 1; st < 8; st <<= 1) {
#pragma unroll
        for (int h = 0; h < 4; ++h) {
            pS[h] += __shfl_xor(pS[h], st);
            pD[h] += __shfl_xor(pD[h], st);
        }
    }
    if (p == 0) {
        *(float4*)(aS + (size_t)n * 4) = make_float4(pS[0], pS[1], pS[2], pS[3]);
        *(float4*)(aD + (size_t)n * 4) = make_float4(pD[0], pD[1], pD[2], pD[3]);
    }
}

// ---------------------------------------------------------------------------
// FUSED LAYER, 16 KB LDS (U_lds only -> 4 blocks/CU in a 64KB pool).
// phase A: wave-per-node softmax-gather into LDS (bf16, XOR-swizzled);
// phase B: 8-wave MFMA GEMM 16x512 @ 512x128 + residual + relu + fused dots
// (dots scratch OVERLAYS U_lds after the k-loop; wtS/wtD read from L2).
__global__ __launch_bounds__(512) void gat_layer(const uint_t* __restrict__ xb2_cur,
                                                 const float* __restrict__ aS_cur,
                                                 const float* __restrict__ aD_cur,
                                                 const int* __restrict__ off,
                                                 const int* __restrict__ csr,
                                                 const ushort_t* __restrict__ Bp,
                                                 const float* __restrict__ bias,
                                                 const float* __restrict__ x_cur,
                                                 float* __restrict__ x_next,
                                                 ushort_t* __restrict__ xb_next,
                                                 const float* __restrict__ wtS,
                                                 const float* __restrict__ wtD,
                                                 float* __restrict__ aS_next,
                                                 float* __restrict__ aD_next,
                                                 int do_dots) {
    __shared__ ushort_t U_lds[LNODES][512];   // 16384 B total static LDS

    int t = threadIdx.x;
    int w = t >> 6, l = t & 63;
    int n0 = blockIdx.x * LNODES;

    // ---------------- phase A: aggregation, 2 nodes per wave ----------------
    for (int it = 0; it < 2; ++it) {
        int row = w * 2 + it;
        int n = n0 + row;
        int beg = off[n];
        int deg = off[n + 1] - beg;

        float4 adv = *(const float4*)(aD_cur + (size_t)n * 4);

        int sl = 0;
        float4 av = make_float4(-1e30f, -1e30f, -1e30f, -1e30f);
        if (l < deg) {
            sl = csr[beg + l];
            av = *(const float4*)(aS_cur + (size_t)sl * 4);
        }
        float4 smax = av;
        for (int i = l + 64; i < deg; i += 64) {
            int s = csr[beg + i];
            float4 a = *(const float4*)(aS_cur + (size_t)s * 4);
            smax.x = fmaxf(smax.x, a.x);
            smax.y = fmaxf(smax.y, a.y);
            smax.z = fmaxf(smax.z, a.z);
            smax.w = fmaxf(smax.w, a.w);
        }
#pragma unroll
        for (int st = 1; st < 64; st <<= 1) {
            smax.x = fmaxf(smax.x, __shfl_xor(smax.x, st));
            smax.y = fmaxf(smax.y, __shfl_xor(smax.y, st));
            smax.z = fmaxf(smax.z, __shfl_xor(smax.z, st));
            smax.w = fmaxf(smax.w, __shfl_xor(smax.w, st));
        }
        float e;
        e = smax.x + adv.x; float m0 = e > 0.f ? e : NEG_SLOPE * e;
        e = smax.y + adv.y; float m1 = e > 0.f ? e : NEG_SLOPE * e;
        e = smax.z + adv.z; float m2 = e > 0.f ? e : NEG_SLOPE * e;
        e = smax.w + adv.w; float m3 = e > 0.f ? e : NEG_SLOPE * e;

        float acc[8];
#pragma unroll
        for (int i = 0; i < 8; ++i) acc[i] = 0.f;
        float4 zac = make_float4(0.f, 0.f, 0.f, 0.f);

        // chunk 0 from registers
        int ce = min(64, deg);
        float4 wv = make_float4(0.f, 0.f, 0.f, 0.f);
        if (l < ce) {
            e = av.x + adv.x; e = e > 0.f ? e : NEG_SLOPE * e; wv.x = __expf(e - m0);
            e = av.y + adv.y; e = e > 0.f ? e : NEG_SLOPE * e; wv.y = __expf(e - m1);
            e = av.z + adv.z; e = e > 0.f ? e : NEG_SLOPE * e; wv.z = __expf(e - m2);
            e = av.w + adv.w; e = e > 0.f ? e : NEG_SLOPE * e; wv.w = __expf(e - m3);
            zac.x += wv.x; zac.y += wv.y; zac.z += wv.z; zac.w += wv.w;
        }
#pragma unroll 4
        for (int j = 0; j < ce; ++j) {
            int s = __builtin_amdgcn_readlane(sl, j);
            float w0 = rdlane_f(wv.x, j);
            float w1 = rdlane_f(wv.y, j);
            float w2 = rdlane_f(wv.z, j);
            float w3 = rdlane_f(wv.w, j);
            uint_t xv = xb2_cur[(size_t)s * 64 + l];
            float f0 = bflo(xv), f1 = bfhi(xv);
            acc[0] = fmaf(w0, f0, acc[0]); acc[1] = fmaf(w0, f1, acc[1]);
            acc[2] = fmaf(w1, f0, acc[2]); acc[3] = fmaf(w1, f1, acc[3]);
            acc[4] = fmaf(w2, f0, acc[4]); acc[5] = fmaf(w2, f1, acc[5]);
            acc[6] = fmaf(w3, f0, acc[6]); acc[7] = fmaf(w3, f1, acc[7]);
        }
        for (int c0 = 64; c0 < deg; c0 += 64) {
            ce = min(64, deg - c0);
            wv = make_float4(0.f, 0.f, 0.f, 0.f);
            if (l < ce) {
                sl = csr[beg + c0 + l];
                float4 a = *(const float4*)(aS_cur + (size_t)sl * 4);
                e = a.x + adv.x; e = e > 0.f ? e : NEG_SLOPE * e; wv.x = __expf(e - m0);
                e = a.y + adv.y; e = e > 0.f ? e : NEG_SLOPE * e; wv.y = __expf(e - m1);
                e = a.z + adv.z; e = e > 0.f ? e : NEG_SLOPE * e; wv.z = __expf(e - m2);
                e = a.w + adv.w; e = e > 0.f ? e : NEG_SLOPE * e; wv.w = __expf(e - m3);
                zac.x += wv.x; zac.y += wv.y; zac.z += wv.z; zac.w += wv.w;
            }
#pragma unroll 4
            for (int j = 0; j < ce; ++j) {
                int s = __builtin_amdgcn_readlane(sl, j);
                float w0 = rdlane_f(wv.x, j);
                float w1 = rdlane_f(wv.y, j);
                float w2 = rdlane_f(wv.z, j);
                float w3 = rdlane_f(wv.w, j);
                uint_t xv = xb2_cur[(size_t)s * 64 + l];
                float f0 = bflo(xv), f1 = bfhi(xv);
                acc[0] = fmaf(w0, f0, acc[0]); acc[1] = fmaf(w0, f1, acc[1]);
                acc[2] = fmaf(w1, f0, acc[2]); acc[3] = fmaf(w1, f1, acc[3]);
                acc[4] = fmaf(w2, f0, acc[4]); acc[5] = fmaf(w2, f1, acc[5]);
                acc[6] = fmaf(w3, f0, acc[6]); acc[7] = fmaf(w3, f1, acc[7]);
            }
        }

#pragma unroll
        for (int st = 1; st < 64; st <<= 1) {
            zac.x += __shfl_xor(zac.x, st);
            zac.y += __shfl_xor(zac.y, st);
            zac.z += __shfl_xor(zac.z, st);
            zac.w += __shfl_xor(zac.w, st);
        }
        float iz0 = 1.f / zac.x, iz1 = 1.f / zac.y, iz2 = 1.f / zac.z, iz3 = 1.f / zac.w;
        // U row -> LDS, XOR-swizzled (uint idx ^= (row&7)<<2 within h-block)
        uint_t* U32 = (uint_t*)&U_lds[row][0];
        int swz = (row & 7) << 2;
        int li = l ^ swz;
        U32[li]        = (uint_t)f2bf(acc[0] * iz0) | ((uint_t)f2bf(acc[1] * iz0) << 16);
        U32[64 + li]   = (uint_t)f2bf(acc[2] * iz1) | ((uint_t)f2bf(acc[3] * iz1) << 16);
        U32[128 + li]  = (uint_t)f2bf(acc[4] * iz2) | ((uint_t)f2bf(acc[5] * iz2) << 16);
        U32[192 + li]  = (uint_t)f2bf(acc[6] * iz3) | ((uint_t)f2bf(acc[7] * iz3) << 16);
    }

    __syncthreads();

    // ---------------- phase B: GEMM 16x512 @ 512x128 ----------------
    int r16 = l & 15, g = l >> 4;
    int bn0 = w * 16;
    const ushort_t* bcol = Bp + (size_t)(bn0 + r16) * 512 + g * 8;
    int arow_sw = (r16 & 7) << 3;   // element-index XOR for ds reads

    f32x4 cacc = {};
#pragma unroll 4
    for (int k0 = 0; k0 < 512; k0 += 32) {
        bf16x8 a = *(const bf16x8*)&U_lds[r16][(k0 + g * 8) ^ arow_sw];
        bf16x8 bb = *(const bf16x8*)(bcol + k0);
        cacc = __builtin_amdgcn_mfma_f32_16x16x32_bf16(a, bb, cacc, 0, 0, 0);
    }

    // epilogue: residual + relu + store
    int col = bn0 + r16;
    float bia = bias[col];
    float nx[4];
#pragma unroll
    for (int r = 0; r < 4; ++r) {
        int rl = g * 4 + r;
        int row = n0 + rl;
        float v = 0.25f * cacc[r] + bia;
        v = v > 0.f ? v : 0.f;
        float nv = x_cur[(size_t)row * 128 + col] + v;
        x_next[(size_t)row * 128 + col] = nv;
        xb_next[(size_t)row * 128 + col] = f2bf(nv);
        nx[r] = nv;
    }

    // fused dots for next layer; scratch overlays U_lds (dead after k-loop)
    if (do_dots) {
        __syncthreads();   // ensure ALL waves finished reading U_lds
        float* ov = (float*)&U_lds[0][0];   // [0..511]=pS, [512..1023]=pD
        float wS[4], wD[4];
#pragma unroll
        for (int h = 0; h < 4; ++h) {
            wS[h] = wtS[h * 128 + col];
            wD[h] = wtD[h * 128 + col];
        }
#pragma unroll
        for (int r = 0; r < 4; ++r) {
            float sS[4], sD[4];
#pragma unroll
            for (int h = 0; h < 4; ++h) {
                sS[h] = nx[r] * wS[h];
                sD[h] = nx[r] * wD[h];
            }
#pragma unroll
            for (int st = 1; st < 16; st <<= 1)
#pragma unroll
                for (int h = 0; h < 4; ++h) {
                    sS[h] += __shfl_xor(sS[h], st);
                    sD[h] += __shfl_xor(sD[h], st);
                }
            if (r16 == 0) {
                int rl = g * 4 + r;
#pragma unroll
                for (int h = 0; h < 4; ++h) {
                    ov[(w * 16 + rl) * 4 + h] = sS[h];
                    ov[512 + (w * 16 + rl) * 4 + h] = sD[h];
                }
            }
        }
        __syncthreads();
        if (t < 64) {
            int rl = t >> 2, h = t & 3;
            int row = n0 + rl;
            float ssum = 0.f, dsum = 0.f;
#pragma unroll
            for (int ww = 0; ww < 8; ++ww) {
                ssum += ov[(ww * 16 + rl) * 4 + h];
                dsum += ov[512 + (ww * 16 + rl) * 4 + h];
            }
            aS_next[(size_t)row * 4 + h] = ssum;
            aD_next[(size_t)row * 4 + h] = dsum;
        }
    }
}

// ---------------------------------------------------------------------------
// Prediction heads (MFMA attack head + strided vuln dot)
__global__ __launch_bounds__(256) void pred_kernel(const float* __restrict__ x,
                                                   const ushort_t* __restrict__ xb,
                                                   const ushort_t* __restrict__ W1p,
                                                   const float* __restrict__ b1,
                                                   const float* __restrict__ W2,
                                                   const float* __restrict__ b2,
                                                   const float* __restrict__ vW,
                                                   const float* __restrict__ vb,
                                                   float* __restrict__ out) {
    int t = threadIdx.x;
    int lane = t & 63, w = t >> 6;
    int wr = w >> 1, wc = w & 1;
    int bm0 = blockIdx.x * 64 + wr * 32;
    int bn0 = wc * 32;
    int r16 = lane & 15, g = lane >> 4;

    const ushort_t* arow = xb + (size_t)(bm0 + r16) * 128 + g * 8;
    const ushort_t* bcol = W1p + (size_t)(bn0 + r16) * 128 + g * 8;

    f32x4 acc[2][2] = {};
#pragma unroll
    for (int k0 = 0; k0 < 128; k0 += 32) {
        bf16x8 a0 = *(const bf16x8*)(arow + k0);
        bf16x8 a1 = *(const bf16x8*)(arow + 16 * 128 + k0);
        bf16x8 b0 = *(const bf16x8*)(bcol + k0);
        bf16x8 b1 = *(const bf16x8*)(bcol + 16 * 128 + k0);
        acc[0][0] = __builtin_amdgcn_mfma_f32_16x16x32_bf16(a0, b0, acc[0][0], 0, 0, 0);
        acc[0][1] = __builtin_amdgcn_mfma_f32_16x16x32_bf16(a0, b1, acc[0][1], 0, 0, 0);
        acc[1][0] = __builtin_amdgcn_mfma_f32_16x16x32_bf16(a1, b0, acc[1][0], 0, 0, 0);
        acc[1][1] = __builtin_amdgcn_mfma_f32_16x16x32_bf16(a1, b1, acc[1][1], 0, 0, 0);
    }

    __shared__ float pa[2][64];
    float b1c[2] = {b1[bn0 + r16], b1[bn0 + 16 + r16]};
    float w2c[2] = {W2[bn0 + r16], W2[bn0 + 16 + r16]};
#pragma unroll
    for (int fm = 0; fm < 2; ++fm)
#pragma unroll
        for (int r = 0; r < 4; ++r) {
            float h10 = acc[fm][0][r] + b1c[0]; h10 = h10 > 0.f ? h10 : 0.f;
            float h11 = acc[fm][1][r] + b1c[1]; h11 = h11 > 0.f ? h11 : 0.f;
            float s = h10 * w2c[0] + h11 * w2c[1];
#pragma unroll
            for (int st = 1; st < 16; st <<= 1) s += __shfl_xor(s, st);
            if (r16 == 0) pa[wc][wr * 32 + fm * 16 + g * 4 + r] = s;
        }
    __syncthreads();
    if (t < 64) {
        int row = blockIdx.x * 64 + t;
        if (row < N_NODES) {
            float pre = pa[0][t] + pa[1][t] + b2[0];
            out[row] = 1.f / (1.f + __expf(-pre));
        }
    }
    int vrow = blockIdx.x * 64 + w * 16 + (lane >> 2);
    int q = lane & 3;
    if (vrow < N_NODES) {
        const float* xr = x + (size_t)vrow * 128 + q * 32;
        float s = 0.f;
#pragma unroll
        for (int j = 0; j < 32; ++j) s = fmaf(xr[j], vW[q * 32 + j], s);
        s += __shfl_xor(s, 1);
        s += __shfl_xor(s, 2);
        if (q == 0)
            out[N_NODES + vrow] = 1.f / (1.f + __expf(-(s + vb[0])));
    }
}

// ---------------------------------------------------------------------------
extern "C" void kernel_launch(void* const* d_in, const int* in_sizes, int n_in,
                              void* d_out, int out_size, void* d_ws, size_t ws_size,
                              hipStream_t stream) {
    const float* nf    = (const float*)d_in[0];
    const int*   ei    = (const int*)d_in[1];
    const float* encW  = (const float*)d_in[2];
    const float* encb  = (const float*)d_in[3];
    const float* lin   = (const float*)d_in[4];
    const float* attS  = (const float*)d_in[5];
    const float* attD  = (const float*)d_in[6];
    const float* gbias = (const float*)d_in[7];
    const float* W1    = (const float*)d_in[8];
    const float* b1    = (const float*)d_in[9];
    const float* W2    = (const float*)d_in[10];
    const float* b2    = (const float*)d_in[11];
    const float* vW    = (const float*)d_in[12];
    const float* vb    = (const float*)d_in[13];
    float* out = (float*)d_out;

    char* ws = (char*)d_ws;
    size_t o = 0;
    auto alloc = [&](size_t bytes) {
        void* p = ws + o;
        o += (bytes + 255) & ~(size_t)255;
        return p;
    };
    float* x0     = (float*)alloc((size_t)N_PAD * 128 * 4);
    float* x1     = (float*)alloc((size_t)N_PAD * 128 * 4);
    ushort_t* xb0 = (ushort_t*)alloc((size_t)N_PAD * 128 * 2);
    ushort_t* xb1 = (ushort_t*)alloc((size_t)N_PAD * 128 * 2);
    ushort_t* Bp  = (ushort_t*)alloc((size_t)3 * 128 * 512 * 2);
    ushort_t* W1p = (ushort_t*)alloc((size_t)64 * 128 * 2);
    float* wtS    = (float*)alloc((size_t)3 * 512 * 4);
    float* wtD    = (float*)alloc((size_t)3 * 512 * 4);
    float* aS0    = (float*)alloc((size_t)N_NODES * 4 * 4);
    float* aD0    = (float*)alloc((size_t)N_NODES * 4 * 4);
    float* aS1    = (float*)alloc((size_t)N_NODES * 4 * 4);
    float* aD1    = (float*)alloc((size_t)N_NODES * 4 * 4);
    int* deg      = (int*)alloc((size_t)N_NODES * 4);
    int* cursor   = (int*)alloc((size_t)N_NODES * 4);
    int* offs     = (int*)alloc((size_t)(N_NODES + 1) * 4);
    int* csr      = (int*)alloc((size_t)ET * 4);

    const int HIST_BLOCKS = (ET + 255) / 256;

    pack_all<<<96, 256, 0, stream>>>(lin, attS, attD, W1, Bp, wtS, wtD, W1p, deg);
    enc_hist<<<ENC_BLOCKS + HIST_BLOCKS, 256, 0, stream>>>(nf, encW, encb, ei, x0, xb0, deg);
    scan_kernel<<<1, 1024, 0, stream>>>(deg, offs, cursor);
    scatter_kernel<<<HIST_BLOCKS, 256, 0, stream>>>(ei, cursor, csr);
    dots_kernel<<<N_NODES / 32, 256, 0, stream>>>(xb0, wtS, wtD, aS0, aD0);

    float*    xc[2]  = {x0, x1};
    ushort_t* xbc[2] = {xb0, xb1};
    float*    aSc[2] = {aS0, aS1};
    float*    aDc[2] = {aD0, aD1};
    for (int l = 0; l < 3; ++l) {
        int ci = l & 1, ni = ci ^ 1;
        int dd = (l < 2) ? 1 : 0;
        gat_layer<<<N_NODES / LNODES, 512, 0, stream>>>(
            (const uint_t*)xbc[ci], aSc[ci], aDc[ci], offs, csr,
            Bp + (size_t)l * 128 * 512, gbias + (size_t)l * 128,
            xc[ci], xc[ni], xbc[ni],
            wtS + (size_t)(l + 1 < 3 ? l + 1 : 0) * 512,
            wtD + (size_t)(l + 1 < 3 ? l + 1 : 0) * 512,
            aSc[ni], aDc[ni], dd);
    }
    pred_kernel<<<N_PAD / 64, 256, 0, stream>>>(x1, xb1, W1p, b1, W2, b2, vW, vb, out);
}